// Round 9
// baseline (401.387 us; speedup 1.0000x reference)
//
#include <hip/hip_runtime.h>
#include <math.h>

#define TOK    8192
#define DMODEL 512
#define FDIM   2048
#define NH     8
#define DKH    64
#define SEQ    1024
#define BATCH  8
#define KCONV  31
#define LN_EPS 1e-5f

typedef __attribute__((ext_vector_type(8))) short bf16x8;
typedef __attribute__((ext_vector_type(4))) float f32x4;
typedef unsigned short ushort_t;

#define AS1 __attribute__((address_space(1)))
#define AS3 __attribute__((address_space(3)))

// 0.125 (1/sqrt(64)) * log2(e): QK scores land in base-2 domain
#define QSCALE 0.1803368801111204f

__device__ __forceinline__ float sigf(float x) { return 1.0f / (1.0f + __expf(-x)); }

__device__ __forceinline__ unsigned short f2bf(float f) {
  unsigned u = __float_as_uint(f);
  u = u + 0x7fffu + ((u >> 16) & 1u);   // RNE
  return (unsigned short)(u >> 16);
}
__device__ __forceinline__ unsigned pk2(float a, float b) {
  return (unsigned)f2bf(a) | ((unsigned)f2bf(b) << 16);
}
__device__ __forceinline__ float bf2f(ushort_t u) {
  return __uint_as_float((unsigned)u << 16);
}

// XCD-aware bijective block swizzle (grids here are multiples of 8).
__device__ __forceinline__ void xcd_swizzle(int gx, int* bx, int* by) {
  const int nwg = gx * (int)gridDim.y;
  const int cpx = nwg >> 3;
  const int bid = (*by) * gx + (*bx);
  const int wg = (bid & 7) * cpx + (bid >> 3);
  *bx = wg % gx;
  *by = wg / gx;
}

// ---------------- all weight prep in ONE dispatch ---------------------------
struct WJob { const float* src; ushort_t* dst; int K, N, t0; };
struct WJobs {
  WJob j[10];
  int misc_t0;
  const float* dww; const float* bq; const float* bk; const float* bv;
  float* wTc; float* bcat;
};

__global__ __launch_bounds__(256) void wcast_all(WJobs jobs) {
  __shared__ float tile[32][33];
  const int t = blockIdx.x;
  const int tx = threadIdx.x, ty = threadIdx.y;  // 32 x 8
  if (t >= jobs.misc_t0) {
    const int idx = (t - jobs.misc_t0) * 256 + ty * 32 + tx;
    if (idx < DMODEL * KCONV) {
      const int d = idx / KCONV, k = idx % KCONV;
      jobs.wTc[k * DMODEL + d] = jobs.dww[idx];
    } else if (idx < DMODEL * KCONV + 3 * DMODEL) {
      const int c = idx - DMODEL * KCONV;
      jobs.bcat[c] = (c < DMODEL) ? jobs.bq[c]
                    : (c < 2 * DMODEL ? jobs.bk[c - DMODEL] : jobs.bv[c - 2 * DMODEL]);
    }
    return;
  }
  int i = 0;
#pragma unroll
  for (int k = 1; k < 10; ++k) if (t >= jobs.j[k].t0) i = k;
  const WJob jb = jobs.j[i];
  const int local = t - jb.t0;
  const int ntx = jb.N >> 5;
  const int bx = (local % ntx) * 32, by = (local / ntx) * 32;
#pragma unroll
  for (int r = 0; r < 32; r += 8)
    tile[ty + r][tx] = jb.src[(size_t)(by + ty + r) * jb.N + bx + tx];
  __syncthreads();
#pragma unroll
  for (int r = 0; r < 32; r += 8)
    jb.dst[(size_t)(bx + ty + r) * jb.K + by + tx] = f2bf(tile[tx][ty + r]);
}

// ---------------- LayerNorm: one wave per 512-wide row ----------------------
template <bool OBF>
__global__ __launch_bounds__(256) void ln_kernel(const float* __restrict__ in,
                                                 const float* __restrict__ g,
                                                 const float* __restrict__ b,
                                                 void* __restrict__ outp) {
  const int wave = threadIdx.x >> 6, lane = threadIdx.x & 63;
  const size_t row = (size_t)blockIdx.x * 4 + wave;
  const float* p = in + row * DMODEL + lane * 8;
  const float4 v0 = *(const float4*)p;
  const float4 v1 = *(const float4*)(p + 4);
  float s  = v0.x + v0.y + v0.z + v0.w + v1.x + v1.y + v1.z + v1.w;
  float ss = v0.x*v0.x + v0.y*v0.y + v0.z*v0.z + v0.w*v0.w
           + v1.x*v1.x + v1.y*v1.y + v1.z*v1.z + v1.w*v1.w;
#pragma unroll
  for (int m = 1; m < 64; m <<= 1) { s += __shfl_xor(s, m); ss += __shfl_xor(ss, m); }
  const float mean = s * (1.0f / DMODEL);
  const float var  = ss * (1.0f / DMODEL) - mean * mean;
  const float rstd = rsqrtf(var + LN_EPS);
  const float4 g0 = *(const float4*)(g + lane * 8);
  const float4 g1 = *(const float4*)(g + lane * 8 + 4);
  const float4 bb0 = *(const float4*)(b + lane * 8);
  const float4 bb1 = *(const float4*)(b + lane * 8 + 4);
  float o[8];
  o[0] = (v0.x - mean) * rstd * g0.x + bb0.x;
  o[1] = (v0.y - mean) * rstd * g0.y + bb0.y;
  o[2] = (v0.z - mean) * rstd * g0.z + bb0.z;
  o[3] = (v0.w - mean) * rstd * g0.w + bb0.w;
  o[4] = (v1.x - mean) * rstd * g1.x + bb1.x;
  o[5] = (v1.y - mean) * rstd * g1.y + bb1.y;
  o[6] = (v1.z - mean) * rstd * g1.z + bb1.z;
  o[7] = (v1.w - mean) * rstd * g1.w + bb1.w;
  if (OBF) {
    uint4 pkv;
    pkv.x = pk2(o[0], o[1]); pkv.y = pk2(o[2], o[3]);
    pkv.z = pk2(o[4], o[5]); pkv.w = pk2(o[6], o[7]);
    *(uint4*)((ushort_t*)outp + row * DMODEL + lane * 8) = pkv;
  } else {
    float4 a, c;
    a.x = o[0]; a.y = o[1]; a.z = o[2]; a.w = o[3];
    c.x = o[4]; c.y = o[5]; c.z = o[6]; c.w = o[7];
    float* q = (float*)outp + row * DMODEL + lane * 8;
    *(float4*)q = a;
    *(float4*)(q + 4) = c;
  }
}

// ---------------- fused double LayerNorm (norm3 then conv_ln), bf16 out -----
__global__ __launch_bounds__(256) void ln2_kernel(const float* __restrict__ in,
                                                  const float* __restrict__ g1,
                                                  const float* __restrict__ b1,
                                                  const float* __restrict__ g2,
                                                  const float* __restrict__ b2,
                                                  ushort_t* __restrict__ outp) {
  const int wave = threadIdx.x >> 6, lane = threadIdx.x & 63;
  const size_t row = (size_t)blockIdx.x * 4 + wave;
  const float* p = in + row * DMODEL + lane * 8;
  float v[8];
  {
    const float4 v0 = *(const float4*)p;
    const float4 v1 = *(const float4*)(p + 4);
    v[0]=v0.x; v[1]=v0.y; v[2]=v0.z; v[3]=v0.w;
    v[4]=v1.x; v[5]=v1.y; v[6]=v1.z; v[7]=v1.w;
  }
  float s = 0.f, ss = 0.f;
#pragma unroll
  for (int e = 0; e < 8; ++e) { s += v[e]; ss += v[e]*v[e]; }
#pragma unroll
  for (int m = 1; m < 64; m <<= 1) { s += __shfl_xor(s, m); ss += __shfl_xor(ss, m); }
  float mean = s * (1.0f / DMODEL);
  float rstd = rsqrtf(ss * (1.0f / DMODEL) - mean * mean + LN_EPS);
  const float4 ga = *(const float4*)(g1 + lane * 8);
  const float4 gb = *(const float4*)(g1 + lane * 8 + 4);
  const float4 ba = *(const float4*)(b1 + lane * 8);
  const float4 bb = *(const float4*)(b1 + lane * 8 + 4);
  const float gg1[8] = {ga.x,ga.y,ga.z,ga.w,gb.x,gb.y,gb.z,gb.w};
  const float bb1[8] = {ba.x,ba.y,ba.z,ba.w,bb.x,bb.y,bb.z,bb.w};
#pragma unroll
  for (int e = 0; e < 8; ++e) v[e] = (v[e] - mean) * rstd * gg1[e] + bb1[e];
  s = 0.f; ss = 0.f;
#pragma unroll
  for (int e = 0; e < 8; ++e) { s += v[e]; ss += v[e]*v[e]; }
#pragma unroll
  for (int m = 1; m < 64; m <<= 1) { s += __shfl_xor(s, m); ss += __shfl_xor(ss, m); }
  mean = s * (1.0f / DMODEL);
  rstd = rsqrtf(ss * (1.0f / DMODEL) - mean * mean + LN_EPS);
  const float4 gc = *(const float4*)(g2 + lane * 8);
  const float4 gd = *(const float4*)(g2 + lane * 8 + 4);
  const float4 bc = *(const float4*)(b2 + lane * 8);
  const float4 bd = *(const float4*)(b2 + lane * 8 + 4);
  const float gg2[8] = {gc.x,gc.y,gc.z,gc.w,gd.x,gd.y,gd.z,gd.w};
  const float bb2[8] = {bc.x,bc.y,bc.z,bc.w,bd.x,bd.y,bd.z,bd.w};
  float o[8];
#pragma unroll
  for (int e = 0; e < 8; ++e) o[e] = (v[e] - mean) * rstd * gg2[e] + bb2[e];
  uint4 pkv;
  pkv.x = pk2(o[0], o[1]); pkv.y = pk2(o[2], o[3]);
  pkv.z = pk2(o[4], o[5]); pkv.w = pk2(o[6], o[7]);
  *(uint4*)(outp + row * DMODEL + lane * 8) = pkv;
}

// ================= 8-phase 256x256 GEMM (T2+T3+T4+T5), K=512 ================
template <int ACT, bool QSC>
__global__ __launch_bounds__(512, 2) void gemm256(const ushort_t* __restrict__ A,
                                                  const ushort_t* __restrict__ Bt,
                                                  const float* __restrict__ bias,
                                                  ushort_t* __restrict__ Cout,
                                                  int N) {
  __shared__ ushort_t lds[65536];   // 128 KB
  const int t = threadIdx.x;
  const int l = t & 63;
  const int wid = t >> 6;
  const int wm = wid >> 2, wn = wid & 3;
  int bx = blockIdx.x, by = blockIdx.y;
  xcd_swizzle(gridDim.x, &bx, &by);
  const int m0 = by * 256, n0 = bx * 256;
  const int K = 512;

  f32x4 acc[8][4];
#pragma unroll
  for (int m = 0; m < 8; ++m)
#pragma unroll
    for (int n = 0; n < 4; ++n) acc[m][n] = (f32x4){0.f, 0.f, 0.f, 0.f};

  const int srow = t >> 3;
  const int schunk = (t & 7) ^ ((t >> 3) & 7);

#define STAGE_A(TAU, C_, I_)                                                    \
  __builtin_amdgcn_global_load_lds(                                             \
      (const AS1 unsigned*)(A + (size_t)(m0 + (I_) * 64 + srow) * K +           \
                            (TAU) * 64 + schunk * 8),                           \
      (AS3 unsigned*)(lds + (C_) * 16384 + ((I_) * 512 + t) * 8), 16, 0, 0)
#define STAGE_B(TAU, C_, I_)                                                    \
  __builtin_amdgcn_global_load_lds(                                             \
      (const AS1 unsigned*)(Bt + (size_t)(n0 + (I_) * 64 + srow) * K +          \
                            (TAU) * 64 + schunk * 8),                           \
      (AS3 unsigned*)(lds + 32768 + (C_) * 16384 + ((I_) * 512 + t) * 8), 16, 0, 0)

#pragma unroll
  for (int i = 0; i < 4; ++i) STAGE_B(0, 0, i);
#pragma unroll
  for (int i = 0; i < 4; ++i) STAGE_A(0, 0, i);
#pragma unroll
  for (int i = 0; i < 4; ++i) STAGE_B(1, 1, i);
  STAGE_A(1, 1, 0);
  STAGE_A(1, 1, 2);
  asm volatile("s_waitcnt vmcnt(6)" ::: "memory");
  __builtin_amdgcn_s_barrier();

  const int arow = (l & 15);
  const int kch0 = (l >> 4);
  bf16x8 bfr[2][4];

  for (int it = 0; it < 4; ++it) {
    const bool stg = (it < 3);
#pragma unroll
    for (int h = 0; h < 2; ++h) {
      const int c = h;
#pragma unroll
      for (int p = 0; p < 4; ++p) {
        bf16x8 afr[2][2];
#pragma unroll
        for (int m2 = 0; m2 < 2; ++m2)
#pragma unroll
          for (int ks = 0; ks < 2; ++ks) {
            const int row = wm * 128 + (2 * p + m2) * 16 + arow;
            const int ch = (ks * 4 + kch0) ^ (row & 7);
            afr[m2][ks] = *(const bf16x8*)(lds + c * 16384 + row * 64 + ch * 8);
          }
        if (p == 0) {
#pragma unroll
          for (int nr = 0; nr < 4; ++nr)
#pragma unroll
            for (int ks = 0; ks < 2; ++ks) {
              const int row = wn * 64 + nr * 16 + arow;
              const int ch = (ks * 4 + kch0) ^ (row & 7);
              bfr[ks][nr] = *(const bf16x8*)(lds + 32768 + c * 16384 + row * 64 + ch * 8);
            }
        }
        if (p == 0) {
          if (h == 0 || stg) {
            STAGE_A(2 * it + h + 1, c ^ 1, 1);
            STAGE_A(2 * it + h + 1, c ^ 1, 3);
          }
        } else if (p == 1) {
          if (stg) {
#pragma unroll
            for (int i = 0; i < 4; ++i) STAGE_B(2 * it + h + 2, c, i);
          }
        } else if (p == 2) {
          if (stg) {
            STAGE_A(2 * it + h + 2, c, 0);
            STAGE_A(2 * it + h + 2, c, 2);
          }
        }
        __builtin_amdgcn_s_barrier();
        __builtin_amdgcn_s_setprio(1);
#pragma unroll
        for (int ks = 0; ks < 2; ++ks)
#pragma unroll
          for (int m2 = 0; m2 < 2; ++m2)
#pragma unroll
            for (int nr = 0; nr < 4; ++nr)
              acc[2 * p + m2][nr] = __builtin_amdgcn_mfma_f32_16x16x32_bf16(
                  afr[m2][ks], bfr[ks][nr], acc[2 * p + m2][nr], 0, 0, 0);
        __builtin_amdgcn_s_setprio(0);
        if (p == 3) {
          if (h == 0) {
            if (stg) asm volatile("s_waitcnt vmcnt(6)" ::: "memory");
            else     asm volatile("s_waitcnt vmcnt(0)" ::: "memory");
          } else if (stg) {
            asm volatile("s_waitcnt vmcnt(6)" ::: "memory");
          }
        }
        __builtin_amdgcn_s_barrier();
      }
    }
  }
#undef STAGE_A
#undef STAGE_B

#pragma unroll
  for (int m = 0; m < 8; ++m) {
    const int row_b = m0 + wm * 128 + m * 16 + (l >> 4) * 4;
#pragma unroll
    for (int n = 0; n < 4; ++n) {
      const int col = n0 + wn * 64 + n * 16 + (l & 15);
      const float bv = bias[col];
      const float sc = QSC ? (col < DMODEL ? QSCALE : 1.0f) : 1.0f;
#pragma unroll
      for (int j = 0; j < 4; ++j) {
        float v = acc[m][n][j] + bv;
        if (ACT == 1) v = fmaxf(v, 0.f);
        v *= sc;
        Cout[(size_t)(row_b + j) * N + col] = f2bf(v);
      }
    }
  }
}

// ---------------- bf16 MFMA GEMM (m97 structure), TN = 128 or 64 ------------
template <int TN, int ACT, bool RES, bool OBF, bool QSC>
__global__ __launch_bounds__(256) void gemm_bf16(const ushort_t* __restrict__ A,
                                                 const ushort_t* __restrict__ Bt,
                                                 const float* __restrict__ bias,
                                                 const float* __restrict__ Rp,
                                                 float alpha,
                                                 void* __restrict__ Cout,
                                                 int M, int N, int K) {
  constexpr int NF = TN / 32;
  constexpr int NB = TN / 32;
  __shared__ ushort_t Al[128 * 64];
  __shared__ ushort_t Bl[TN * 64];
  const int t = threadIdx.x;
  const int lane = t & 63;
  const int wid = t >> 6;
  const int wr = wid >> 1, wc = wid & 1;
  int bx = blockIdx.x, by = blockIdx.y;
  xcd_swizzle(gridDim.x, &bx, &by);
  const int m0 = by * 128, n0 = bx * TN;

  f32x4 acc[4][NF];
#pragma unroll
  for (int m = 0; m < 4; ++m)
#pragma unroll
    for (int n = 0; n < NF; ++n) acc[m][n] = (f32x4){0.f, 0.f, 0.f, 0.f};

  const int srow = t >> 3;
  const int scol = (t & 7) * 8;
  const ushort_t* Ag = A + (size_t)(m0 + srow) * K + scol;
  const ushort_t* Bg = Bt + (size_t)(n0 + srow) * K + scol;

  for (int k0 = 0; k0 < K; k0 += 64) {
    __syncthreads();
#pragma unroll
    for (int i = 0; i < 4; ++i) {
      __builtin_amdgcn_global_load_lds(
          (const AS1 unsigned*)(Ag + (size_t)i * 32 * K + k0),
          (AS3 unsigned*)(Al + ((size_t)i * 256 + t) * 8),
          16, 0, 0);
    }
#pragma unroll
    for (int i = 0; i < NB; ++i) {
      __builtin_amdgcn_global_load_lds(
          (const AS1 unsigned*)(Bg + (size_t)i * 32 * K + k0),
          (AS3 unsigned*)(Bl + ((size_t)i * 256 + t) * 8),
          16, 0, 0);
    }
    __syncthreads();

#pragma unroll
    for (int ks = 0; ks < 2; ++ks) {
      const int kk = ks * 32 + (lane >> 4) * 8;
      bf16x8 af[4], bfv[NF];
#pragma unroll
      for (int m = 0; m < 4; ++m)
        af[m] = *(const bf16x8*)(Al + (wr * 64 + m * 16 + (lane & 15)) * 64 + kk);
#pragma unroll
      for (int n = 0; n < NF; ++n)
        bfv[n] = *(const bf16x8*)(Bl + (wc * (TN / 2) + n * 16 + (lane & 15)) * 64 + kk);
#pragma unroll
      for (int m = 0; m < 4; ++m)
#pragma unroll
        for (int n = 0; n < NF; ++n)
          acc[m][n] = __builtin_amdgcn_mfma_f32_16x16x32_bf16(af[m], bfv[n], acc[m][n], 0, 0, 0);
    }
  }

#pragma unroll
  for (int m = 0; m < 4; ++m) {
    const int row_b = m0 + wr * 64 + m * 16 + (lane >> 4) * 4;
#pragma unroll
    for (int n = 0; n < NF; ++n) {
      const int col = n0 + wc * (TN / 2) + n * 16 + (lane & 15);
      const float bv = bias[col];
#pragma unroll
      for (int j = 0; j < 4; ++j) {
        float v = acc[m][n][j] + bv;
        if (ACT == 1) v = fmaxf(v, 0.f);
        if (QSC) v *= (col < DMODEL ? QSCALE : 1.0f);
        const size_t idx = (size_t)(row_b + j) * N + col;
        if (RES) v = Rp[idx] + alpha * v;
        if (OBF) ((ushort_t*)Cout)[idx] = f2bf(v);
        else     ((float*)Cout)[idx] = v;
      }
    }
  }
}

// ---------------- fused pw1 + GLU GEMM --------------------------------------
__global__ __launch_bounds__(256) void gemm_glu(const ushort_t* __restrict__ A,
                                                const ushort_t* __restrict__ Bt,
                                                const float* __restrict__ bias,
                                                ushort_t* __restrict__ Cout) {
  __shared__ ushort_t Al[128 * 64];
  __shared__ ushort_t Bl[128 * 64];
  const int t = threadIdx.x;
  const int lane = t & 63;
  const int wid = t >> 6;
  const int wr = wid >> 1, wc = wid & 1;
  int bx = blockIdx.x, by = blockIdx.y;
  xcd_swizzle(gridDim.x, &bx, &by);
  const int m0 = by * 128, n0 = bx * 64;
  const int K = DMODEL, N = DMODEL;

  f32x4 aa[4][2], ag[4][2];
#pragma unroll
  for (int m = 0; m < 4; ++m)
#pragma unroll
    for (int n = 0; n < 2; ++n) {
      aa[m][n] = (f32x4){0.f, 0.f, 0.f, 0.f};
      ag[m][n] = (f32x4){0.f, 0.f, 0.f, 0.f};
    }

  const int srow = t >> 3;
  const int scol = (t & 7) * 8;
  const ushort_t* Ag_ = A + (size_t)(m0 + srow) * K + scol;
  const ushort_t* Ba_ = Bt + (size_t)(n0 + srow) * K + scol;
  const ushort_t* Bg_ = Bt + (size_t)(512 + n0 + srow) * K + scol;

  for (int k0 = 0; k0 < K; k0 += 64) {
    __syncthreads();
#pragma unroll
    for (int i = 0; i < 4; ++i) {
      __builtin_amdgcn_global_load_lds(
          (const AS1 unsigned*)(Ag_ + (size_t)i * 32 * K + k0),
          (AS3 unsigned*)(Al + ((size_t)i * 256 + t) * 8),
          16, 0, 0);
    }
#pragma unroll
    for (int i = 0; i < 2; ++i) {
      __builtin_amdgcn_global_load_lds(
          (const AS1 unsigned*)(Ba_ + (size_t)i * 32 * K + k0),
          (AS3 unsigned*)(Bl + ((size_t)i * 256 + t) * 8),
          16, 0, 0);
      __builtin_amdgcn_global_load_lds(
          (const AS1 unsigned*)(Bg_ + (size_t)i * 32 * K + k0),
          (AS3 unsigned*)(Bl + 64 * 64 + ((size_t)i * 256 + t) * 8),
          16, 0, 0);
    }
    __syncthreads();

#pragma unroll
    for (int ks = 0; ks < 2; ++ks) {
      const int kk = ks * 32 + (lane >> 4) * 8;
      bf16x8 af[4], bfa[2], bfg[2];
#pragma unroll
      for (int m = 0; m < 4; ++m)
        af[m] = *(const bf16x8*)(Al + (wr * 64 + m * 16 + (lane & 15)) * 64 + kk);
#pragma unroll
      for (int n = 0; n < 2; ++n) {
        bfa[n] = *(const bf16x8*)(Bl + (wc * 32 + n * 16 + (lane & 15)) * 64 + kk);
        bfg[n] = *(const bf16x8*)(Bl + (64 + wc * 32 + n * 16 + (lane & 15)) * 64 + kk);
      }
#pragma unroll
      for (int m = 0; m < 4; ++m)
#pragma unroll
        for (int n = 0; n < 2; ++n) {
          aa[m][n] = __builtin_amdgcn_mfma_f32_16x16x32_bf16(af[m], bfa[n], aa[m][n], 0, 0, 0);
          ag[m][n] = __builtin_amdgcn_mfma_f32_16x16x32_bf16(af[m], bfg[n], ag[m][n], 0, 0, 0);
        }
    }
  }

#pragma unroll
  for (int m = 0; m < 4; ++m) {
    const int row_b = m0 + wr * 64 + m * 16 + (lane >> 4) * 4;
#pragma unroll
    for (int n = 0; n < 2; ++n) {
      const int col = n0 + wc * 32 + n * 16 + (lane & 15);
      const float ba_v = bias[col];
      const float bg_v = bias[col + DMODEL];
#pragma unroll
      for (int j = 0; j < 4; ++j) {
        const float av = aa[m][n][j] + ba_v;
        const float gv = ag[m][n][j] + bg_v;
        Cout[(size_t)(row_b + j) * N + col] = f2bf(av * sigf(gv));
      }
    }
  }
}

// ------- K pack + V transpose: QKV -> Kp[bh][s][64], Vt[bh][d][s] -----------
__global__ __launch_bounds__(256) void vtrans(const ushort_t* __restrict__ QKV,
                                              ushort_t* __restrict__ Kp,
                                              ushort_t* __restrict__ Vt) {
  __shared__ ushort_t tl[64][72];
  const int st = blockIdx.x;
  const int bh = blockIdx.y;
  const int b = bh >> 3, h = bh & 7;
  const int t = threadIdx.x;
#pragma unroll
  for (int i = 0; i < 2; ++i) {
    const int chunk = i * 256 + t;
    const int sr = chunk >> 3, c8 = (chunk & 7) * 8;
    const size_t src = (size_t)(b * SEQ + st * 64 + sr) * (3 * DMODEL) + h * DKH + c8;
    // V -> LDS for transpose
    *(uint4*)&tl[sr][c8] = *(const uint4*)(QKV + src + 2 * DMODEL);
    // K -> packed copy (no transpose)
    *(uint4*)(Kp + ((size_t)(bh * SEQ + st * 64 + sr)) * DKH + c8) =
        *(const uint4*)(QKV + src + DMODEL);
  }
  __syncthreads();
#pragma unroll
  for (int i = 0; i < 2; ++i) {
    const int chunk = i * 256 + t;
    const int dr = chunk >> 3, c8 = (chunk & 7) * 8;
    ushort_t tmp[8];
#pragma unroll
    for (int e = 0; e < 8; ++e) tmp[e] = tl[c8 + e][dr];
    *(uint4*)(Vt + ((size_t)(bh * DKH + dr) * SEQ) + st * 64 + c8) = *(uint4*)tmp;
  }
}

// ---------------- MFMA flash attention, NO K/V staging (L2-direct) ----------
// m169 lesson: at S=1024 K/V are L2-resident; LDS staging + barriers were the
// cost. 1D grid + chunked swizzle keeps one (b,h)'s 256KB on one XCD's L2.
// Only Ps (P/O repack) lives in LDS (16KB). Zero barriers in the main loop.
__global__ __launch_bounds__(256) void attn_mfma(const ushort_t* __restrict__ QKV,
                                                 const ushort_t* __restrict__ Kp,
                                                 const ushort_t* __restrict__ Vt,
                                                 ushort_t* __restrict__ Om) {
  __shared__ ushort_t Ps[64 * 128];   // [q][key] rows 256 B, swizzled
  const int t = threadIdx.x;
  const int l = t & 63;
  const int w = t >> 6;
  // chunked XCD swizzle over 1024 blocks: 16 q-blocks of one (b,h) contiguous
  const int bid = blockIdx.x;
  const int wg = (bid & 7) * 128 + (bid >> 3);
  const int qb = wg & 15;
  const int bh = wg >> 4;
  const size_t rowstr = 3 * DMODEL;
  const size_t baseQ  = (size_t)(bh >> 3) * SEQ * rowstr + (size_t)(bh & 7) * DKH;
  const size_t baseKp = (size_t)bh * SEQ * DKH;
  const size_t baseV  = (size_t)bh * DKH * SEQ;
  const size_t baseO  = (size_t)(bh >> 3) * SEQ * DMODEL + (size_t)(bh & 7) * DKH;

  bf16x8 qf[2];
  {
    const int qrow = qb * 64 + w * 16 + (l & 15);
    const ushort_t* qp = QKV + baseQ + (size_t)qrow * rowstr + ((l >> 4) * 8);
    qf[0] = *(const bf16x8*)(qp);
    qf[1] = *(const bf16x8*)(qp + 32);
  }

  float mrun[4], lrun[4];
  f32x4 o[4];
#pragma unroll
  for (int j = 0; j < 4; ++j) { mrun[j] = -1e30f; lrun[j] = 0.f; }
#pragma unroll
  for (int n = 0; n < 4; ++n) o[n] = (f32x4){0.f, 0.f, 0.f, 0.f};

  for (int kt = 0; kt < SEQ / 128; ++kt) {
    // S = Q K^T : K fragments direct from L2-resident Kp
    f32x4 s[8];
#pragma unroll
    for (int n = 0; n < 8; ++n) s[n] = (f32x4){0.f, 0.f, 0.f, 0.f};
    __builtin_amdgcn_s_setprio(1);
#pragma unroll
    for (int ks = 0; ks < 2; ++ks) {
      const int koff = ks * 32 + (l >> 4) * 8;
#pragma unroll
      for (int n = 0; n < 8; ++n) {
        const int krow = kt * 128 + n * 16 + (l & 15);
        const bf16x8 kf = *(const bf16x8*)(Kp + baseKp + (size_t)krow * DKH + koff);
        s[n] = __builtin_amdgcn_mfma_f32_16x16x32_bf16(qf[ks], kf, s[n], 0, 0, 0);
      }
    }
    __builtin_amdgcn_s_setprio(0);

    // online softmax (base-2; log2e pre-folded into Q); P -> bf16 via LDS
#pragma unroll
    for (int j = 0; j < 4; ++j) {
      float r0 = fmaxf(fmaxf(fmaxf(s[0][j], s[1][j]), fmaxf(s[2][j], s[3][j])),
                       fmaxf(fmaxf(s[4][j], s[5][j]), fmaxf(s[6][j], s[7][j])));
      r0 = fmaxf(r0, __shfl_xor(r0, 1));
      r0 = fmaxf(r0, __shfl_xor(r0, 2));
      r0 = fmaxf(r0, __shfl_xor(r0, 4));
      r0 = fmaxf(r0, __shfl_xor(r0, 8));
      const float mn = fmaxf(mrun[j], r0);
      const float cs = exp2f(mrun[j] - mn);
      const int prow = w * 16 + (l >> 4) * 4 + j;
      const int pswz = (prow & 15) << 4;
      float psum = 0.f;
#pragma unroll
      for (int n = 0; n < 8; ++n) {
        const float p = exp2f(s[n][j] - mn);
        psum += p;
        const int col2 = (n * 16 + (l & 15)) * 2;
        *(ushort_t*)((char*)Ps + prow * 256 + (col2 ^ pswz)) = f2bf(p);
      }
      psum += __shfl_xor(psum, 1);
      psum += __shfl_xor(psum, 2);
      psum += __shfl_xor(psum, 4);
      psum += __shfl_xor(psum, 8);
      lrun[j] = lrun[j] * cs + psum;
      mrun[j] = mn;
      o[0][j] *= cs; o[1][j] *= cs; o[2][j] *= cs; o[3][j] *= cs;
    }

    // O += P V : V fragments direct from L2-resident Vt
    __builtin_amdgcn_s_setprio(1);
#pragma unroll
    for (int ks = 0; ks < 4; ++ks) {
      const int kk = ks * 64 + (l >> 4) * 16;   // byte offset in P row
      const int arow = w * 16 + (l & 15);
      const bf16x8 pf = *(const bf16x8*)((char*)Ps + arow * 256 + (kk ^ ((arow & 15) << 4)));
      const int voff = kt * 128 + ks * 32 + (l >> 4) * 8;   // key elem offset
#pragma unroll
      for (int n = 0; n < 4; ++n) {
        const int vrow = n * 16 + (l & 15);
        const bf16x8 vf = *(const bf16x8*)(Vt + baseV + (size_t)vrow * SEQ + voff);
        o[n] = __builtin_amdgcn_mfma_f32_16x16x32_bf16(pf, vf, o[n], 0, 0, 0);
      }
    }
    __builtin_amdgcn_s_setprio(0);
  }

  // normalize, repack through LDS, coalesced bf16 store
  float inv[4];
#pragma unroll
  for (int j = 0; j < 4; ++j) inv[j] = 1.0f / lrun[j];
#pragma unroll
  for (int j = 0; j < 4; ++j) {
    const int prow = w * 16 + (l >> 4) * 4 + j;
    const int pswz = (prow & 15) << 4;
#pragma unroll
    for (int n = 0; n < 4; ++n) {
      const int col2 = (n * 16 + (l & 15)) * 2;
      *(ushort_t*)((char*)Ps + prow * 256 + (col2 ^ pswz)) = f2bf(o[n][j] * inv[j]);
    }
  }
  __syncthreads();
#pragma unroll
  for (int i = 0; i < 2; ++i) {
    const int chunk = i * 256 + t;
    const int qr = chunk >> 3, c8 = (chunk & 7) * 8;
    const uint4 ov = *(const uint4*)((char*)Ps + qr * 256 + ((c8 * 2) ^ ((qr & 15) << 4)));
    *(uint4*)(Om + baseO + (size_t)(qb * 64 + qr) * DMODEL + c8) = ov;
  }
}

// ---------------- depthwise conv + bias + BN + SiLU, bf16 in/out ------------
__global__ __launch_bounds__(256) void dwconv_bn_silu(const ushort_t* __restrict__ in,
                                                      const float* __restrict__ wT,
                                                      const float* __restrict__ dwb,
                                                      const float* __restrict__ bng,
                                                      const float* __restrict__ bnb,
                                                      const float* __restrict__ bnm,
                                                      const float* __restrict__ bnv,
                                                      ushort_t* __restrict__ out) {
  const size_t gid = (size_t)blockIdx.x * 256 + threadIdx.x;
  const int dc = (int)(gid & 127) * 4;
  const int s = (int)((gid >> 7) & (SEQ - 1));
  const int b = (int)(gid >> 17);
  const ushort_t* bp = in + (size_t)b * SEQ * DMODEL;
  float ax = 0.f, ay = 0.f, az = 0.f, aw = 0.f;
#pragma unroll
  for (int k = 0; k < KCONV; ++k) {
    const int ssi = s + k - (KCONV / 2);
    if (ssi < 0 || ssi >= SEQ) continue;
    ushort_t xv[4];
    *(uint2*)xv = *(const uint2*)(bp + (size_t)ssi * DMODEL + dc);
    const float4 w = *(const float4*)(wT + k * DMODEL + dc);
    ax = fmaf(bf2f(xv[0]), w.x, ax); ay = fmaf(bf2f(xv[1]), w.y, ay);
    az = fmaf(bf2f(xv[2]), w.z, az); aw = fmaf(bf2f(xv[3]), w.w, aw);
  }
  const float4 bi = *(const float4*)(dwb + dc);
  const float4 mm = *(const float4*)(bnm + dc);
  const float4 vv = *(const float4*)(bnv + dc);
  const float4 gg = *(const float4*)(bng + dc);
  const float4 b2 = *(const float4*)(bnb + dc);
  float v0 = ax + bi.x, v1 = ay + bi.y, v2 = az + bi.z, v3 = aw + bi.w;
  v0 = (v0 - mm.x) * rsqrtf(vv.x + LN_EPS) * gg.x + b2.x;
  v1 = (v1 - mm.y) * rsqrtf(vv.y + LN_EPS) * gg.y + b2.y;
  v2 = (v2 - mm.z) * rsqrtf(vv.z + LN_EPS) * gg.z + b2.z;
  v3 = (v3 - mm.w) * rsqrtf(vv.w + LN_EPS) * gg.w + b2.w;
  v0 = v0 * sigf(v0); v1 = v1 * sigf(v1); v2 = v2 * sigf(v2); v3 = v3 * sigf(v3);
  uint2 o;
  o.x = pk2(v0, v1); o.y = pk2(v2, v3);
  *(uint2*)&out[(((size_t)b * SEQ + s) * DMODEL) + dc] = o;
}

extern "C" void kernel_launch(void* const* d_in, const int* in_sizes, int n_in,
                              void* d_out, int out_size, void* d_ws, size_t ws_size,
                              hipStream_t stream) {
  const float* x    = (const float*)d_in[0];
  const float* n1g  = (const float*)d_in[1];
  const float* n1b  = (const float*)d_in[2];
  const float* n2g  = (const float*)d_in[3];
  const float* n2b  = (const float*)d_in[4];
  const float* n3g  = (const float*)d_in[5];
  const float* n3b  = (const float*)d_in[6];
  const float* n4g  = (const float*)d_in[7];
  const float* n4b  = (const float*)d_in[8];
  const float* clg  = (const float*)d_in[9];
  const float* clb  = (const float*)d_in[10];
  const float* f1w1 = (const float*)d_in[11];
  const float* f1b1 = (const float*)d_in[12];
  const float* f1w2 = (const float*)d_in[13];
  const float* f1b2 = (const float*)d_in[14];
  const float* f2w1 = (const float*)d_in[15];
  const float* f2b1 = (const float*)d_in[16];
  const float* f2w2 = (const float*)d_in[17];
  const float* f2b2 = (const float*)d_in[18];
  const float* wq   = (const float*)d_in[19];
  const float* bq   = (const float*)d_in[20];
  const float* wk   = (const float*)d_in[21];
  const float* bk   = (const float*)d_in[22];
  const float* wv   = (const float*)d_in[23];
  const float* bv   = (const float*)d_in[24];
  const float* wo   = (const float*)d_in[25];
  const float* bo   = (const float*)d_in[26];
  const float* pw1w = (const float*)d_in[27];
  const float* pw1b = (const float*)d_in[28];
  const float* dww  = (const float*)d_in[29];
  const float* dwb  = (const float*)d_in[30];
  const float* bng  = (const float*)d_in[31];
  const float* bnb  = (const float*)d_in[32];
  const float* bnm  = (const float*)d_in[33];
  const float* bnv  = (const float*)d_in[34];
  const float* pw2w = (const float*)d_in[35];
  const float* pw2b = (const float*)d_in[36];

  char* wsb = (char*)d_ws;
  const size_t MB = 1ull << 20;
  ushort_t* Wbf    = (ushort_t*)(wsb + 0);
  ushort_t* f1w1T  = Wbf + 0;
  ushort_t* f1w2T  = Wbf + (1ull << 20);
  ushort_t* f2w1T  = Wbf + (2ull << 20);
  ushort_t* f2w2T  = Wbf + (3ull << 20);
  ushort_t* wqkvT  = Wbf + (4ull << 20);
  ushort_t* wkT    = wqkvT + (256ull << 10);
  ushort_t* wvT    = wqkvT + (512ull << 10);
  ushort_t* woT    = wqkvT + (768ull << 10);
  ushort_t* pw1T   = Wbf + (5ull << 20);
  ushort_t* pw2T   = Wbf + (5ull << 20) + (512ull << 10);
  float*    WTc    = (float*)(wsb + 12 * MB);
  float*    bcat   = (float*)(wsb + 12 * MB + 128 * 1024);
  ushort_t* Lbf    = (ushort_t*)(wsb + 13 * MB);
  ushort_t* Hbf    = (ushort_t*)(wsb + 21 * MB);
  ushort_t* QKVb   = (ushort_t*)(wsb + 53 * MB);
  ushort_t* Vtb    = (ushort_t*)(wsb + 77 * MB);
  ushort_t* Gbf    = (ushort_t*)(wsb + 53 * MB);
  ushort_t* Obf    = (ushort_t*)(wsb + 85 * MB);
  ushort_t* Cbf    = Obf;
  ushort_t* Kpb    = (ushort_t*)(wsb + 93 * MB);   // packed K [bh][s][64], 8 MB
  float* out = (float*)d_out;

  const dim3 blk(256);
  const dim3 blk512(512);
  const dim3 blkT(32, 8);
  const dim3 gLN(TOK / 4);
  const dim3 gFFa256(FDIM / 256, TOK / 256);       // 256 blocks
  const dim3 gQKV256(3 * DMODEL / 256, TOK / 256); // 192 blocks
  const dim3 gFFb(DMODEL / 64, TOK / 128);         // 512 blocks
  const dim3 gGLU(DMODEL / 64, TOK / 128);         // 512 blocks
  const dim3 gAttn(BATCH * NH * (SEQ / 64));       // 1024 blocks, 1D
  const dim3 gVt(SEQ / 64, BATCH * NH);
  const dim3 gElem(TOK * 128 / 256);

  // ---- weight preprocessing (single dispatch) ----
  {
    WJobs jobs;
    const float* srcs[10] = {f1w1, f1w2, f2w1, f2w2, wq, wk, wv, wo, pw1w, pw2w};
    ushort_t* dsts[10] = {f1w1T, f1w2T, f2w1T, f2w2T, wqkvT, wkT, wvT, woT, pw1T, pw2T};
    const int Ks[10] = {512, 2048, 512, 2048, 512, 512, 512, 512, 512, 512};
    const int Ns[10] = {2048, 512, 2048, 512, 512, 512, 512, 512, 1024, 512};
    int t0 = 0;
    for (int i = 0; i < 10; ++i) {
      jobs.j[i].src = srcs[i]; jobs.j[i].dst = dsts[i];
      jobs.j[i].K = Ks[i]; jobs.j[i].N = Ns[i]; jobs.j[i].t0 = t0;
      t0 += (Ks[i] / 32) * (Ns[i] / 32);
    }
    jobs.misc_t0 = t0;
    jobs.dww = dww; jobs.bq = bq; jobs.bk = bk; jobs.bv = bv;
    jobs.wTc = WTc; jobs.bcat = bcat;
    const int nmisc = (DMODEL * KCONV + 3 * DMODEL + 255) / 256;
    wcast_all<<<t0 + nmisc, blkT, 0, stream>>>(jobs);
  }

  // ---- FF1 half-step ----
  ln_kernel<true><<<gLN, blk, 0, stream>>>(x, n1g, n1b, Lbf);
  gemm256<1, false><<<gFFa256, blk512, 0, stream>>>(Lbf, f1w1T, f1b1, Hbf, FDIM);
  gemm_bf16<64,  0, true,  false, false><<<gFFb, blk, 0, stream>>>(Hbf, f1w2T, f1b2, x, 0.5f, out, TOK, DMODEL, FDIM);

  // ---- MHSA ----
  ln_kernel<true><<<gLN, blk, 0, stream>>>(out, n2g, n2b, Lbf);
  gemm256<0, true><<<gQKV256, blk512, 0, stream>>>(Lbf, wqkvT, bcat, QKVb, 3 * DMODEL);
  vtrans<<<gVt, blk, 0, stream>>>(QKVb, Kpb, Vtb);
  attn_mfma<<<gAttn, blk, 0, stream>>>(QKVb, Kpb, Vtb, Obf);
  gemm_bf16<64,  0, true,  false, false><<<gFFb, blk, 0, stream>>>(Obf, woT, bo, out, 1.0f, out, TOK, DMODEL, DMODEL);

  // ---- conv module ----
  ln2_kernel<<<gLN, blk, 0, stream>>>(out, n3g, n3b, clg, clb, Lbf);
  gemm_glu<<<gGLU, blk, 0, stream>>>(Lbf, pw1T, pw1b, Gbf);
  dwconv_bn_silu<<<gElem, blk, 0, stream>>>(Gbf, WTc, dwb, bng, bnb, bnm, bnv, Cbf);
  gemm_bf16<64,  0, true,  false, false><<<gFFb, blk, 0, stream>>>(Cbf, pw2T, pw2b, out, 1.0f, out, TOK, DMODEL, DMODEL);

  // ---- FF2 half-step ----
  ln_kernel<true><<<gLN, blk, 0, stream>>>(out, n4g, n4b, Lbf);
  gemm256<1, false><<<gFFa256, blk512, 0, stream>>>(Lbf, f2w1T, f2b1, Hbf, FDIM);
  gemm_bf16<64,  0, true,  false, false><<<gFFb, blk, 0, stream>>>(Hbf, f2w2T, f2b2, out, 0.5f, out, TOK, DMODEL, FDIM);
}

// Round 10
// 311.046 us; speedup vs baseline: 1.2904x; 1.2904x over previous
//
#include <hip/hip_runtime.h>
#include <math.h>

#define TOK    8192
#define DMODEL 512
#define FDIM   2048
#define NH     8
#define DKH    64
#define SEQ    1024
#define BATCH  8
#define KCONV  31
#define LN_EPS 1e-5f

typedef __attribute__((ext_vector_type(8))) short bf16x8;
typedef __attribute__((ext_vector_type(4))) float f32x4;
typedef unsigned short ushort_t;

#define AS1 __attribute__((address_space(1)))
#define AS3 __attribute__((address_space(3)))

// 0.125 (1/sqrt(64)) * log2(e): QK scores land in base-2 domain
#define QSCALE 0.1803368801111204f

__device__ __forceinline__ float sigf(float x) { return 1.0f / (1.0f + __expf(-x)); }

__device__ __forceinline__ unsigned short f2bf(float f) {
  unsigned u = __float_as_uint(f);
  u = u + 0x7fffu + ((u >> 16) & 1u);   // RNE
  return (unsigned short)(u >> 16);
}
__device__ __forceinline__ unsigned pk2(float a, float b) {
  return (unsigned)f2bf(a) | ((unsigned)f2bf(b) << 16);
}
__device__ __forceinline__ float bf2f(ushort_t u) {
  return __uint_as_float((unsigned)u << 16);
}

// XCD-aware bijective block swizzle (grids here are multiples of 8).
__device__ __forceinline__ void xcd_swizzle(int gx, int* bx, int* by) {
  const int nwg = gx * (int)gridDim.y;
  const int cpx = nwg >> 3;
  const int bid = (*by) * gx + (*bx);
  const int wg = (bid & 7) * cpx + (bid >> 3);
  *bx = wg % gx;
  *by = wg / gx;
}

// ---------------- all weight prep in ONE dispatch ---------------------------
struct WJob { const float* src; ushort_t* dst; int K, N, t0; };
struct WJobs {
  WJob j[10];
  int misc_t0;
  const float* dww; const float* bq; const float* bk; const float* bv;
  float* wTc; float* bcat;
};

__global__ __launch_bounds__(256) void wcast_all(WJobs jobs) {
  __shared__ float tile[32][33];
  const int t = blockIdx.x;
  const int tx = threadIdx.x, ty = threadIdx.y;  // 32 x 8
  if (t >= jobs.misc_t0) {
    const int idx = (t - jobs.misc_t0) * 256 + ty * 32 + tx;
    if (idx < DMODEL * KCONV) {
      const int d = idx / KCONV, k = idx % KCONV;
      jobs.wTc[k * DMODEL + d] = jobs.dww[idx];
    } else if (idx < DMODEL * KCONV + 3 * DMODEL) {
      const int c = idx - DMODEL * KCONV;
      jobs.bcat[c] = (c < DMODEL) ? jobs.bq[c]
                    : (c < 2 * DMODEL ? jobs.bk[c - DMODEL] : jobs.bv[c - 2 * DMODEL]);
    }
    return;
  }
  int i = 0;
#pragma unroll
  for (int k = 1; k < 10; ++k) if (t >= jobs.j[k].t0) i = k;
  const WJob jb = jobs.j[i];
  const int local = t - jb.t0;
  const int ntx = jb.N >> 5;
  const int bx = (local % ntx) * 32, by = (local / ntx) * 32;
#pragma unroll
  for (int r = 0; r < 32; r += 8)
    tile[ty + r][tx] = jb.src[(size_t)(by + ty + r) * jb.N + bx + tx];
  __syncthreads();
#pragma unroll
  for (int r = 0; r < 32; r += 8)
    jb.dst[(size_t)(bx + ty + r) * jb.K + by + tx] = f2bf(tile[tx][ty + r]);
}

// ---------------- LayerNorm: one wave per 512-wide row ----------------------
template <bool OBF>
__global__ __launch_bounds__(256) void ln_kernel(const float* __restrict__ in,
                                                 const float* __restrict__ g,
                                                 const float* __restrict__ b,
                                                 void* __restrict__ outp) {
  const int wave = threadIdx.x >> 6, lane = threadIdx.x & 63;
  const size_t row = (size_t)blockIdx.x * 4 + wave;
  const float* p = in + row * DMODEL + lane * 8;
  const float4 v0 = *(const float4*)p;
  const float4 v1 = *(const float4*)(p + 4);
  float s  = v0.x + v0.y + v0.z + v0.w + v1.x + v1.y + v1.z + v1.w;
  float ss = v0.x*v0.x + v0.y*v0.y + v0.z*v0.z + v0.w*v0.w
           + v1.x*v1.x + v1.y*v1.y + v1.z*v1.z + v1.w*v1.w;
#pragma unroll
  for (int m = 1; m < 64; m <<= 1) { s += __shfl_xor(s, m); ss += __shfl_xor(ss, m); }
  const float mean = s * (1.0f / DMODEL);
  const float var  = ss * (1.0f / DMODEL) - mean * mean;
  const float rstd = rsqrtf(var + LN_EPS);
  const float4 g0 = *(const float4*)(g + lane * 8);
  const float4 g1 = *(const float4*)(g + lane * 8 + 4);
  const float4 bb0 = *(const float4*)(b + lane * 8);
  const float4 bb1 = *(const float4*)(b + lane * 8 + 4);
  float o[8];
  o[0] = (v0.x - mean) * rstd * g0.x + bb0.x;
  o[1] = (v0.y - mean) * rstd * g0.y + bb0.y;
  o[2] = (v0.z - mean) * rstd * g0.z + bb0.z;
  o[3] = (v0.w - mean) * rstd * g0.w + bb0.w;
  o[4] = (v1.x - mean) * rstd * g1.x + bb1.x;
  o[5] = (v1.y - mean) * rstd * g1.y + bb1.y;
  o[6] = (v1.z - mean) * rstd * g1.z + bb1.z;
  o[7] = (v1.w - mean) * rstd * g1.w + bb1.w;
  if (OBF) {
    uint4 pkv;
    pkv.x = pk2(o[0], o[1]); pkv.y = pk2(o[2], o[3]);
    pkv.z = pk2(o[4], o[5]); pkv.w = pk2(o[6], o[7]);
    *(uint4*)((ushort_t*)outp + row * DMODEL + lane * 8) = pkv;
  } else {
    float4 a, c;
    a.x = o[0]; a.y = o[1]; a.z = o[2]; a.w = o[3];
    c.x = o[4]; c.y = o[5]; c.z = o[6]; c.w = o[7];
    float* q = (float*)outp + row * DMODEL + lane * 8;
    *(float4*)q = a;
    *(float4*)(q + 4) = c;
  }
}

// ---------------- fused double LayerNorm (norm3 then conv_ln), bf16 out -----
__global__ __launch_bounds__(256) void ln2_kernel(const float* __restrict__ in,
                                                  const float* __restrict__ g1,
                                                  const float* __restrict__ b1,
                                                  const float* __restrict__ g2,
                                                  const float* __restrict__ b2,
                                                  ushort_t* __restrict__ outp) {
  const int wave = threadIdx.x >> 6, lane = threadIdx.x & 63;
  const size_t row = (size_t)blockIdx.x * 4 + wave;
  const float* p = in + row * DMODEL + lane * 8;
  float v[8];
  {
    const float4 v0 = *(const float4*)p;
    const float4 v1 = *(const float4*)(p + 4);
    v[0]=v0.x; v[1]=v0.y; v[2]=v0.z; v[3]=v0.w;
    v[4]=v1.x; v[5]=v1.y; v[6]=v1.z; v[7]=v1.w;
  }
  float s = 0.f, ss = 0.f;
#pragma unroll
  for (int e = 0; e < 8; ++e) { s += v[e]; ss += v[e]*v[e]; }
#pragma unroll
  for (int m = 1; m < 64; m <<= 1) { s += __shfl_xor(s, m); ss += __shfl_xor(ss, m); }
  float mean = s * (1.0f / DMODEL);
  float rstd = rsqrtf(ss * (1.0f / DMODEL) - mean * mean + LN_EPS);
  const float4 ga = *(const float4*)(g1 + lane * 8);
  const float4 gb = *(const float4*)(g1 + lane * 8 + 4);
  const float4 ba = *(const float4*)(b1 + lane * 8);
  const float4 bb = *(const float4*)(b1 + lane * 8 + 4);
  const float gg1[8] = {ga.x,ga.y,ga.z,ga.w,gb.x,gb.y,gb.z,gb.w};
  const float bb1[8] = {ba.x,ba.y,ba.z,ba.w,bb.x,bb.y,bb.z,bb.w};
#pragma unroll
  for (int e = 0; e < 8; ++e) v[e] = (v[e] - mean) * rstd * gg1[e] + bb1[e];
  s = 0.f; ss = 0.f;
#pragma unroll
  for (int e = 0; e < 8; ++e) { s += v[e]; ss += v[e]*v[e]; }
#pragma unroll
  for (int m = 1; m < 64; m <<= 1) { s += __shfl_xor(s, m); ss += __shfl_xor(ss, m); }
  mean = s * (1.0f / DMODEL);
  rstd = rsqrtf(ss * (1.0f / DMODEL) - mean * mean + LN_EPS);
  const float4 gc = *(const float4*)(g2 + lane * 8);
  const float4 gd = *(const float4*)(g2 + lane * 8 + 4);
  const float4 bc = *(const float4*)(b2 + lane * 8);
  const float4 bd = *(const float4*)(b2 + lane * 8 + 4);
  const float gg2[8] = {gc.x,gc.y,gc.z,gc.w,gd.x,gd.y,gd.z,gd.w};
  const float bb2[8] = {bc.x,bc.y,bc.z,bc.w,bd.x,bd.y,bd.z,bd.w};
  float o[8];
#pragma unroll
  for (int e = 0; e < 8; ++e) o[e] = (v[e] - mean) * rstd * gg2[e] + bb2[e];
  uint4 pkv;
  pkv.x = pk2(o[0], o[1]); pkv.y = pk2(o[2], o[3]);
  pkv.z = pk2(o[4], o[5]); pkv.w = pk2(o[6], o[7]);
  *(uint4*)(outp + row * DMODEL + lane * 8) = pkv;
}

// ================= 8-phase 256x256 GEMM (T2+T3+T4+T5), K=512 ================
template <int ACT, bool QSC>
__global__ __launch_bounds__(512, 2) void gemm256(const ushort_t* __restrict__ A,
                                                  const ushort_t* __restrict__ Bt,
                                                  const float* __restrict__ bias,
                                                  ushort_t* __restrict__ Cout,
                                                  int N) {
  __shared__ ushort_t lds[65536];   // 128 KB
  const int t = threadIdx.x;
  const int l = t & 63;
  const int wid = t >> 6;
  const int wm = wid >> 2, wn = wid & 3;
  int bx = blockIdx.x, by = blockIdx.y;
  xcd_swizzle(gridDim.x, &bx, &by);
  const int m0 = by * 256, n0 = bx * 256;
  const int K = 512;

  f32x4 acc[8][4];
#pragma unroll
  for (int m = 0; m < 8; ++m)
#pragma unroll
    for (int n = 0; n < 4; ++n) acc[m][n] = (f32x4){0.f, 0.f, 0.f, 0.f};

  const int srow = t >> 3;
  const int schunk = (t & 7) ^ ((t >> 3) & 7);

#define STAGE_A(TAU, C_, I_)                                                    \
  __builtin_amdgcn_global_load_lds(                                             \
      (const AS1 unsigned*)(A + (size_t)(m0 + (I_) * 64 + srow) * K +           \
                            (TAU) * 64 + schunk * 8),                           \
      (AS3 unsigned*)(lds + (C_) * 16384 + ((I_) * 512 + t) * 8), 16, 0, 0)
#define STAGE_B(TAU, C_, I_)                                                    \
  __builtin_amdgcn_global_load_lds(                                             \
      (const AS1 unsigned*)(Bt + (size_t)(n0 + (I_) * 64 + srow) * K +          \
                            (TAU) * 64 + schunk * 8),                           \
      (AS3 unsigned*)(lds + 32768 + (C_) * 16384 + ((I_) * 512 + t) * 8), 16, 0, 0)

#pragma unroll
  for (int i = 0; i < 4; ++i) STAGE_B(0, 0, i);
#pragma unroll
  for (int i = 0; i < 4; ++i) STAGE_A(0, 0, i);
#pragma unroll
  for (int i = 0; i < 4; ++i) STAGE_B(1, 1, i);
  STAGE_A(1, 1, 0);
  STAGE_A(1, 1, 2);
  asm volatile("s_waitcnt vmcnt(6)" ::: "memory");
  __builtin_amdgcn_s_barrier();

  const int arow = (l & 15);
  const int kch0 = (l >> 4);
  bf16x8 bfr[2][4];

  for (int it = 0; it < 4; ++it) {
    const bool stg = (it < 3);
#pragma unroll
    for (int h = 0; h < 2; ++h) {
      const int c = h;
#pragma unroll
      for (int p = 0; p < 4; ++p) {
        bf16x8 afr[2][2];
#pragma unroll
        for (int m2 = 0; m2 < 2; ++m2)
#pragma unroll
          for (int ks = 0; ks < 2; ++ks) {
            const int row = wm * 128 + (2 * p + m2) * 16 + arow;
            const int ch = (ks * 4 + kch0) ^ (row & 7);
            afr[m2][ks] = *(const bf16x8*)(lds + c * 16384 + row * 64 + ch * 8);
          }
        if (p == 0) {
#pragma unroll
          for (int nr = 0; nr < 4; ++nr)
#pragma unroll
            for (int ks = 0; ks < 2; ++ks) {
              const int row = wn * 64 + nr * 16 + arow;
              const int ch = (ks * 4 + kch0) ^ (row & 7);
              bfr[ks][nr] = *(const bf16x8*)(lds + 32768 + c * 16384 + row * 64 + ch * 8);
            }
        }
        if (p == 0) {
          if (h == 0 || stg) {
            STAGE_A(2 * it + h + 1, c ^ 1, 1);
            STAGE_A(2 * it + h + 1, c ^ 1, 3);
          }
        } else if (p == 1) {
          if (stg) {
#pragma unroll
            for (int i = 0; i < 4; ++i) STAGE_B(2 * it + h + 2, c, i);
          }
        } else if (p == 2) {
          if (stg) {
            STAGE_A(2 * it + h + 2, c, 0);
            STAGE_A(2 * it + h + 2, c, 2);
          }
        }
        __builtin_amdgcn_s_barrier();
        __builtin_amdgcn_s_setprio(1);
#pragma unroll
        for (int ks = 0; ks < 2; ++ks)
#pragma unroll
          for (int m2 = 0; m2 < 2; ++m2)
#pragma unroll
            for (int nr = 0; nr < 4; ++nr)
              acc[2 * p + m2][nr] = __builtin_amdgcn_mfma_f32_16x16x32_bf16(
                  afr[m2][ks], bfr[ks][nr], acc[2 * p + m2][nr], 0, 0, 0);
        __builtin_amdgcn_s_setprio(0);
        if (p == 3) {
          if (h == 0) {
            if (stg) asm volatile("s_waitcnt vmcnt(6)" ::: "memory");
            else     asm volatile("s_waitcnt vmcnt(0)" ::: "memory");
          } else if (stg) {
            asm volatile("s_waitcnt vmcnt(6)" ::: "memory");
          }
        }
        __builtin_amdgcn_s_barrier();
      }
    }
  }
#undef STAGE_A
#undef STAGE_B

#pragma unroll
  for (int m = 0; m < 8; ++m) {
    const int row_b = m0 + wm * 128 + m * 16 + (l >> 4) * 4;
#pragma unroll
    for (int n = 0; n < 4; ++n) {
      const int col = n0 + wn * 64 + n * 16 + (l & 15);
      const float bv = bias[col];
      const float sc = QSC ? (col < DMODEL ? QSCALE : 1.0f) : 1.0f;
#pragma unroll
      for (int j = 0; j < 4; ++j) {
        float v = acc[m][n][j] + bv;
        if (ACT == 1) v = fmaxf(v, 0.f);
        v *= sc;
        Cout[(size_t)(row_b + j) * N + col] = f2bf(v);
      }
    }
  }
}

// ---------------- bf16 MFMA GEMM (m97 structure), TN = 128 or 64 ------------
template <int TN, int ACT, bool RES, bool OBF, bool QSC>
__global__ __launch_bounds__(256) void gemm_bf16(const ushort_t* __restrict__ A,
                                                 const ushort_t* __restrict__ Bt,
                                                 const float* __restrict__ bias,
                                                 const float* __restrict__ Rp,
                                                 float alpha,
                                                 void* __restrict__ Cout,
                                                 int M, int N, int K) {
  constexpr int NF = TN / 32;
  constexpr int NB = TN / 32;
  __shared__ ushort_t Al[128 * 64];
  __shared__ ushort_t Bl[TN * 64];
  const int t = threadIdx.x;
  const int lane = t & 63;
  const int wid = t >> 6;
  const int wr = wid >> 1, wc = wid & 1;
  int bx = blockIdx.x, by = blockIdx.y;
  xcd_swizzle(gridDim.x, &bx, &by);
  const int m0 = by * 128, n0 = bx * TN;

  f32x4 acc[4][NF];
#pragma unroll
  for (int m = 0; m < 4; ++m)
#pragma unroll
    for (int n = 0; n < NF; ++n) acc[m][n] = (f32x4){0.f, 0.f, 0.f, 0.f};

  const int srow = t >> 3;
  const int scol = (t & 7) * 8;
  const ushort_t* Ag = A + (size_t)(m0 + srow) * K + scol;
  const ushort_t* Bg = Bt + (size_t)(n0 + srow) * K + scol;

  for (int k0 = 0; k0 < K; k0 += 64) {
    __syncthreads();
#pragma unroll
    for (int i = 0; i < 4; ++i) {
      __builtin_amdgcn_global_load_lds(
          (const AS1 unsigned*)(Ag + (size_t)i * 32 * K + k0),
          (AS3 unsigned*)(Al + ((size_t)i * 256 + t) * 8),
          16, 0, 0);
    }
#pragma unroll
    for (int i = 0; i < NB; ++i) {
      __builtin_amdgcn_global_load_lds(
          (const AS1 unsigned*)(Bg + (size_t)i * 32 * K + k0),
          (AS3 unsigned*)(Bl + ((size_t)i * 256 + t) * 8),
          16, 0, 0);
    }
    __syncthreads();

#pragma unroll
    for (int ks = 0; ks < 2; ++ks) {
      const int kk = ks * 32 + (lane >> 4) * 8;
      bf16x8 af[4], bfv[NF];
#pragma unroll
      for (int m = 0; m < 4; ++m)
        af[m] = *(const bf16x8*)(Al + (wr * 64 + m * 16 + (lane & 15)) * 64 + kk);
#pragma unroll
      for (int n = 0; n < NF; ++n)
        bfv[n] = *(const bf16x8*)(Bl + (wc * (TN / 2) + n * 16 + (lane & 15)) * 64 + kk);
#pragma unroll
      for (int m = 0; m < 4; ++m)
#pragma unroll
        for (int n = 0; n < NF; ++n)
          acc[m][n] = __builtin_amdgcn_mfma_f32_16x16x32_bf16(af[m], bfv[n], acc[m][n], 0, 0, 0);
    }
  }

#pragma unroll
  for (int m = 0; m < 4; ++m) {
    const int row_b = m0 + wr * 64 + m * 16 + (lane >> 4) * 4;
#pragma unroll
    for (int n = 0; n < NF; ++n) {
      const int col = n0 + wc * (TN / 2) + n * 16 + (lane & 15);
      const float bv = bias[col];
#pragma unroll
      for (int j = 0; j < 4; ++j) {
        float v = acc[m][n][j] + bv;
        if (ACT == 1) v = fmaxf(v, 0.f);
        if (QSC) v *= (col < DMODEL ? QSCALE : 1.0f);
        const size_t idx = (size_t)(row_b + j) * N + col;
        if (RES) v = Rp[idx] + alpha * v;
        if (OBF) ((ushort_t*)Cout)[idx] = f2bf(v);
        else     ((float*)Cout)[idx] = v;
      }
    }
  }
}

// ---------------- fused pw1 + GLU GEMM --------------------------------------
__global__ __launch_bounds__(256) void gemm_glu(const ushort_t* __restrict__ A,
                                                const ushort_t* __restrict__ Bt,
                                                const float* __restrict__ bias,
                                                ushort_t* __restrict__ Cout) {
  __shared__ ushort_t Al[128 * 64];
  __shared__ ushort_t Bl[128 * 64];
  const int t = threadIdx.x;
  const int lane = t & 63;
  const int wid = t >> 6;
  const int wr = wid >> 1, wc = wid & 1;
  int bx = blockIdx.x, by = blockIdx.y;
  xcd_swizzle(gridDim.x, &bx, &by);
  const int m0 = by * 128, n0 = bx * 64;
  const int K = DMODEL, N = DMODEL;

  f32x4 aa[4][2], ag[4][2];
#pragma unroll
  for (int m = 0; m < 4; ++m)
#pragma unroll
    for (int n = 0; n < 2; ++n) {
      aa[m][n] = (f32x4){0.f, 0.f, 0.f, 0.f};
      ag[m][n] = (f32x4){0.f, 0.f, 0.f, 0.f};
    }

  const int srow = t >> 3;
  const int scol = (t & 7) * 8;
  const ushort_t* Ag_ = A + (size_t)(m0 + srow) * K + scol;
  const ushort_t* Ba_ = Bt + (size_t)(n0 + srow) * K + scol;
  const ushort_t* Bg_ = Bt + (size_t)(512 + n0 + srow) * K + scol;

  for (int k0 = 0; k0 < K; k0 += 64) {
    __syncthreads();
#pragma unroll
    for (int i = 0; i < 4; ++i) {
      __builtin_amdgcn_global_load_lds(
          (const AS1 unsigned*)(Ag_ + (size_t)i * 32 * K + k0),
          (AS3 unsigned*)(Al + ((size_t)i * 256 + t) * 8),
          16, 0, 0);
    }
#pragma unroll
    for (int i = 0; i < 2; ++i) {
      __builtin_amdgcn_global_load_lds(
          (const AS1 unsigned*)(Ba_ + (size_t)i * 32 * K + k0),
          (AS3 unsigned*)(Bl + ((size_t)i * 256 + t) * 8),
          16, 0, 0);
      __builtin_amdgcn_global_load_lds(
          (const AS1 unsigned*)(Bg_ + (size_t)i * 32 * K + k0),
          (AS3 unsigned*)(Bl + 64 * 64 + ((size_t)i * 256 + t) * 8),
          16, 0, 0);
    }
    __syncthreads();

#pragma unroll
    for (int ks = 0; ks < 2; ++ks) {
      const int kk = ks * 32 + (lane >> 4) * 8;
      bf16x8 af[4], bfa[2], bfg[2];
#pragma unroll
      for (int m = 0; m < 4; ++m)
        af[m] = *(const bf16x8*)(Al + (wr * 64 + m * 16 + (lane & 15)) * 64 + kk);
#pragma unroll
      for (int n = 0; n < 2; ++n) {
        bfa[n] = *(const bf16x8*)(Bl + (wc * 32 + n * 16 + (lane & 15)) * 64 + kk);
        bfg[n] = *(const bf16x8*)(Bl + (64 + wc * 32 + n * 16 + (lane & 15)) * 64 + kk);
      }
#pragma unroll
      for (int m = 0; m < 4; ++m)
#pragma unroll
        for (int n = 0; n < 2; ++n) {
          aa[m][n] = __builtin_amdgcn_mfma_f32_16x16x32_bf16(af[m], bfa[n], aa[m][n], 0, 0, 0);
          ag[m][n] = __builtin_amdgcn_mfma_f32_16x16x32_bf16(af[m], bfg[n], ag[m][n], 0, 0, 0);
        }
    }
  }

#pragma unroll
  for (int m = 0; m < 4; ++m) {
    const int row_b = m0 + wr * 64 + m * 16 + (lane >> 4) * 4;
#pragma unroll
    for (int n = 0; n < 2; ++n) {
      const int col = n0 + wc * 32 + n * 16 + (lane & 15);
      const float ba_v = bias[col];
      const float bg_v = bias[col + DMODEL];
#pragma unroll
      for (int j = 0; j < 4; ++j) {
        const float av = aa[m][n][j] + ba_v;
        const float gv = ag[m][n][j] + bg_v;
        Cout[(size_t)(row_b + j) * N + col] = f2bf(av * sigf(gv));
      }
    }
  }
}

// ---------------- V transpose per head: QKV[b][s][1024+h*64+d] -> [bh][d][s] -
__global__ __launch_bounds__(256) void vtrans(const ushort_t* __restrict__ QKV,
                                              ushort_t* __restrict__ Vt) {
  __shared__ ushort_t tl[64][72];
  const int st = blockIdx.x;
  const int bh = blockIdx.y;
  const int b = bh >> 3, h = bh & 7;
  const int t = threadIdx.x;
#pragma unroll
  for (int i = 0; i < 2; ++i) {
    const int chunk = i * 256 + t;
    const int sr = chunk >> 3, c8 = (chunk & 7) * 8;
    *(uint4*)&tl[sr][c8] =
        *(const uint4*)(QKV + ((size_t)(b * SEQ + st * 64 + sr) * (3 * DMODEL)) + 2 * DMODEL + h * DKH + c8);
  }
  __syncthreads();
#pragma unroll
  for (int i = 0; i < 2; ++i) {
    const int chunk = i * 256 + t;
    const int dr = chunk >> 3, c8 = (chunk & 7) * 8;
    ushort_t tmp[8];
#pragma unroll
    for (int e = 0; e < 8; ++e) tmp[e] = tl[c8 + e][dr];
    *(uint4*)(Vt + ((size_t)(bh * DKH + dr) * SEQ) + st * 64 + c8) = *(uint4*)tmp;
  }
}

// ---------------- MFMA flash attention, QBLK=64, KVBLK=128, 4 waves ---------
// (round-8 proven structure; base-2 softmax, log2e folded into Q epilogue)
__global__ __launch_bounds__(256) void attn_mfma(const ushort_t* __restrict__ QKV,
                                                 const ushort_t* __restrict__ Vt,
                                                 ushort_t* __restrict__ Om) {
  __shared__ ushort_t Ks[128 * 64];
  __shared__ ushort_t Vs[64 * 128];
  __shared__ ushort_t Ps[64 * 128];
  const int t = threadIdx.x;
  const int l = t & 63;
  const int w = t >> 6;
  const int qb = blockIdx.x, h = blockIdx.y, b = blockIdx.z;
  const size_t rowstr = 3 * DMODEL;
  const size_t baseQ = ((size_t)b * SEQ) * rowstr + (size_t)h * DKH;
  const size_t baseK = baseQ + DMODEL;
  const size_t baseV = (size_t)(b * NH + h) * DKH * SEQ;
  const size_t baseO = ((size_t)b * SEQ) * DMODEL + (size_t)h * DKH;

  bf16x8 qf[2];
  {
    const int qrow = qb * 64 + w * 16 + (l & 15);
    const ushort_t* qp = QKV + baseQ + (size_t)qrow * rowstr + ((l >> 4) * 8);
    qf[0] = *(const bf16x8*)(qp);
    qf[1] = *(const bf16x8*)(qp + 32);
  }

  const int krr = t >> 3, kch = t & 7;
  const int vrr = t >> 4, vch = t & 15;

  float mrun[4], lrun[4];
  f32x4 o[4];
#pragma unroll
  for (int j = 0; j < 4; ++j) { mrun[j] = -1e30f; lrun[j] = 0.f; }
#pragma unroll
  for (int n = 0; n < 4; ++n) o[n] = (f32x4){0.f, 0.f, 0.f, 0.f};

  for (int kt = 0; kt < SEQ / 128; ++kt) {
    __syncthreads();
#pragma unroll
    for (int i = 0; i < 4; ++i) {
      const int r = i * 32 + krr;
      __builtin_amdgcn_global_load_lds(
          (const AS1 unsigned*)
              (QKV + baseK + (size_t)(kt * 128 + r) * rowstr + ((kch ^ (r & 7)) * 8)),
          (AS3 unsigned*)(Ks + ((size_t)i * 256 + t) * 8),
          16, 0, 0);
    }
#pragma unroll
    for (int i = 0; i < 4; ++i) {
      const int r = i * 16 + vrr;
      __builtin_amdgcn_global_load_lds(
          (const AS1 unsigned*)
              (Vt + baseV + (size_t)r * SEQ + kt * 128 + ((vch ^ (r & 15)) * 8)),
          (AS3 unsigned*)(Vs + ((size_t)i * 256 + t) * 8),
          16, 0, 0);
    }
    __syncthreads();

    f32x4 s[8];
#pragma unroll
    for (int n = 0; n < 8; ++n) s[n] = (f32x4){0.f, 0.f, 0.f, 0.f};
    __builtin_amdgcn_s_setprio(1);
#pragma unroll
    for (int ks = 0; ks < 2; ++ks) {
      const int kk = ks * 64 + (l >> 4) * 16;
#pragma unroll
      for (int n = 0; n < 8; ++n) {
        const int krow = n * 16 + (l & 15);
        const bf16x8 kf = *(const bf16x8*)((char*)Ks + krow * 128 + (kk ^ ((krow & 7) << 4)));
        s[n] = __builtin_amdgcn_mfma_f32_16x16x32_bf16(qf[ks], kf, s[n], 0, 0, 0);
      }
    }
    __builtin_amdgcn_s_setprio(0);

#pragma unroll
    for (int j = 0; j < 4; ++j) {
      float r0 = fmaxf(fmaxf(fmaxf(s[0][j], s[1][j]), fmaxf(s[2][j], s[3][j])),
                       fmaxf(fmaxf(s[4][j], s[5][j]), fmaxf(s[6][j], s[7][j])));
      r0 = fmaxf(r0, __shfl_xor(r0, 1));
      r0 = fmaxf(r0, __shfl_xor(r0, 2));
      r0 = fmaxf(r0, __shfl_xor(r0, 4));
      r0 = fmaxf(r0, __shfl_xor(r0, 8));
      const float mn = fmaxf(mrun[j], r0);
      const float cs = exp2f(mrun[j] - mn);
      const int prow = w * 16 + (l >> 4) * 4 + j;
      const int pswz = (prow & 15) << 4;
      float psum = 0.f;
#pragma unroll
      for (int n = 0; n < 8; ++n) {
        const float p = exp2f(s[n][j] - mn);
        psum += p;
        const int col2 = (n * 16 + (l & 15)) * 2;
        *(ushort_t*)((char*)Ps + prow * 256 + (col2 ^ pswz)) = f2bf(p);
      }
      psum += __shfl_xor(psum, 1);
      psum += __shfl_xor(psum, 2);
      psum += __shfl_xor(psum, 4);
      psum += __shfl_xor(psum, 8);
      lrun[j] = lrun[j] * cs + psum;
      mrun[j] = mn;
      o[0][j] *= cs; o[1][j] *= cs; o[2][j] *= cs; o[3][j] *= cs;
    }

    __builtin_amdgcn_s_setprio(1);
#pragma unroll
    for (int ks = 0; ks < 4; ++ks) {
      const int kk = ks * 64 + (l >> 4) * 16;
      const int arow = w * 16 + (l & 15);
      const bf16x8 pf = *(const bf16x8*)((char*)Ps + arow * 256 + (kk ^ ((arow & 15) << 4)));
#pragma unroll
      for (int n = 0; n < 4; ++n) {
        const int vrow = n * 16 + (l & 15);
        const bf16x8 vf = *(const bf16x8*)((char*)Vs + vrow * 256 + (kk ^ ((vrow & 15) << 4)));
        o[n] = __builtin_amdgcn_mfma_f32_16x16x32_bf16(pf, vf, o[n], 0, 0, 0);
      }
    }
    __builtin_amdgcn_s_setprio(0);
  }

  float inv[4];
#pragma unroll
  for (int j = 0; j < 4; ++j) inv[j] = 1.0f / lrun[j];
#pragma unroll
  for (int j = 0; j < 4; ++j) {
    const int prow = w * 16 + (l >> 4) * 4 + j;
    const int pswz = (prow & 15) << 4;
#pragma unroll
    for (int n = 0; n < 4; ++n) {
      const int col2 = (n * 16 + (l & 15)) * 2;
      *(ushort_t*)((char*)Ps + prow * 256 + (col2 ^ pswz)) = f2bf(o[n][j] * inv[j]);
    }
  }
  __syncthreads();
#pragma unroll
  for (int i = 0; i < 2; ++i) {
    const int chunk = i * 256 + t;
    const int qr = chunk >> 3, c8 = (chunk & 7) * 8;
    const uint4 ov = *(const uint4*)((char*)Ps + qr * 256 + ((c8 * 2) ^ ((qr & 15) << 4)));
    *(uint4*)(Om + baseO + (size_t)(qb * 64 + qr) * DMODEL + c8) = ov;
  }
}

// -------- depthwise conv + bias + BN + SiLU, 8 channels/thread --------------
__global__ __launch_bounds__(256) void dwconv_bn_silu(const ushort_t* __restrict__ in,
                                                      const float* __restrict__ wT,
                                                      const float* __restrict__ dwb,
                                                      const float* __restrict__ bng,
                                                      const float* __restrict__ bnb,
                                                      const float* __restrict__ bnm,
                                                      const float* __restrict__ bnv,
                                                      ushort_t* __restrict__ out) {
  const size_t gid = (size_t)blockIdx.x * 256 + threadIdx.x;   // TOK*64
  const int dc = (int)(gid & 63) * 8;
  const int s = (int)((gid >> 6) & (SEQ - 1));
  const int b = (int)(gid >> 16);
  const ushort_t* bp = in + (size_t)b * SEQ * DMODEL;
  float a[8];
#pragma unroll
  for (int e = 0; e < 8; ++e) a[e] = 0.f;
#pragma unroll
  for (int k = 0; k < KCONV; ++k) {
    const int ssi = s + k - (KCONV / 2);
    if (ssi < 0 || ssi >= SEQ) continue;
    ushort_t xv[8];
    *(uint4*)xv = *(const uint4*)(bp + (size_t)ssi * DMODEL + dc);
    const float4 w0 = *(const float4*)(wT + k * DMODEL + dc);
    const float4 w1 = *(const float4*)(wT + k * DMODEL + dc + 4);
    a[0] = fmaf(bf2f(xv[0]), w0.x, a[0]); a[1] = fmaf(bf2f(xv[1]), w0.y, a[1]);
    a[2] = fmaf(bf2f(xv[2]), w0.z, a[2]); a[3] = fmaf(bf2f(xv[3]), w0.w, a[3]);
    a[4] = fmaf(bf2f(xv[4]), w1.x, a[4]); a[5] = fmaf(bf2f(xv[5]), w1.y, a[5]);
    a[6] = fmaf(bf2f(xv[6]), w1.z, a[6]); a[7] = fmaf(bf2f(xv[7]), w1.w, a[7]);
  }
  float v[8];
#pragma unroll
  for (int half = 0; half < 2; ++half) {
    const int d4 = dc + half * 4;
    const float4 bi = *(const float4*)(dwb + d4);
    const float4 mm = *(const float4*)(bnm + d4);
    const float4 vv = *(const float4*)(bnv + d4);
    const float4 gg = *(const float4*)(bng + d4);
    const float4 b2 = *(const float4*)(bnb + d4);
    const float bia[4] = {bi.x, bi.y, bi.z, bi.w};
    const float mma[4] = {mm.x, mm.y, mm.z, mm.w};
    const float vva[4] = {vv.x, vv.y, vv.z, vv.w};
    const float gga[4] = {gg.x, gg.y, gg.z, gg.w};
    const float b2a[4] = {b2.x, b2.y, b2.z, b2.w};
#pragma unroll
    for (int e = 0; e < 4; ++e) {
      float t0 = a[half * 4 + e] + bia[e];
      t0 = (t0 - mma[e]) * rsqrtf(vva[e] + LN_EPS) * gga[e] + b2a[e];
      v[half * 4 + e] = t0 * sigf(t0);
    }
  }
  uint4 o;
  o.x = pk2(v[0], v[1]); o.y = pk2(v[2], v[3]);
  o.z = pk2(v[4], v[5]); o.w = pk2(v[6], v[7]);
  *(uint4*)&out[(((size_t)b * SEQ + s) * DMODEL) + dc] = o;
}

extern "C" void kernel_launch(void* const* d_in, const int* in_sizes, int n_in,
                              void* d_out, int out_size, void* d_ws, size_t ws_size,
                              hipStream_t stream) {
  const float* x    = (const float*)d_in[0];
  const float* n1g  = (const float*)d_in[1];
  const float* n1b  = (const float*)d_in[2];
  const float* n2g  = (const float*)d_in[3];
  const float* n2b  = (const float*)d_in[4];
  const float* n3g  = (const float*)d_in[5];
  const float* n3b  = (const float*)d_in[6];
  const float* n4g  = (const float*)d_in[7];
  const float* n4b  = (const float*)d_in[8];
  const float* clg  = (const float*)d_in[9];
  const float* clb  = (const float*)d_in[10];
  const float* f1w1 = (const float*)d_in[11];
  const float* f1b1 = (const float*)d_in[12];
  const float* f1w2 = (const float*)d_in[13];
  const float* f1b2 = (const float*)d_in[14];
  const float* f2w1 = (const float*)d_in[15];
  const float* f2b1 = (const float*)d_in[16];
  const float* f2w2 = (const float*)d_in[17];
  const float* f2b2 = (const float*)d_in[18];
  const float* wq   = (const float*)d_in[19];
  const float* bq   = (const float*)d_in[20];
  const float* wk   = (const float*)d_in[21];
  const float* bk   = (const float*)d_in[22];
  const float* wv   = (const float*)d_in[23];
  const float* bv   = (const float*)d_in[24];
  const float* wo   = (const float*)d_in[25];
  const float* bo   = (const float*)d_in[26];
  const float* pw1w = (const float*)d_in[27];
  const float* pw1b = (const float*)d_in[28];
  const float* dww  = (const float*)d_in[29];
  const float* dwb  = (const float*)d_in[30];
  const float* bng  = (const float*)d_in[31];
  const float* bnb  = (const float*)d_in[32];
  const float* bnm  = (const float*)d_in[33];
  const float* bnv  = (const float*)d_in[34];
  const float* pw2w = (const float*)d_in[35];
  const float* pw2b = (const float*)d_in[36];

  char* wsb = (char*)d_ws;
  const size_t MB = 1ull << 20;
  ushort_t* Wbf    = (ushort_t*)(wsb + 0);
  ushort_t* f1w1T  = Wbf + 0;
  ushort_t* f1w2T  = Wbf + (1ull << 20);
  ushort_t* f2w1T  = Wbf + (2ull << 20);
  ushort_t* f2w2T  = Wbf + (3ull << 20);
  ushort_t* wqkvT  = Wbf + (4ull << 20);
  ushort_t* wkT    = wqkvT + (256ull << 10);
  ushort_t* wvT    = wqkvT + (512ull << 10);
  ushort_t* woT    = wqkvT + (768ull << 10);
  ushort_t* pw1T   = Wbf + (5ull << 20);
  ushort_t* pw2T   = Wbf + (5ull << 20) + (512ull << 10);
  float*    WTc    = (float*)(wsb + 12 * MB);
  float*    bcat   = (float*)(wsb + 12 * MB + 128 * 1024);
  ushort_t* Lbf    = (ushort_t*)(wsb + 13 * MB);
  ushort_t* Hbf    = (ushort_t*)(wsb + 21 * MB);
  ushort_t* QKVb   = (ushort_t*)(wsb + 53 * MB);
  ushort_t* Vtb    = (ushort_t*)(wsb + 77 * MB);
  ushort_t* Gbf    = (ushort_t*)(wsb + 53 * MB);
  ushort_t* Obf    = (ushort_t*)(wsb + 85 * MB);
  ushort_t* Cbf    = Obf;
  float* out = (float*)d_out;

  const dim3 blk(256);
  const dim3 blk512(512);
  const dim3 blkT(32, 8);
  const dim3 gLN(TOK / 4);
  const dim3 gFFa256(FDIM / 256, TOK / 256);       // 256 blocks
  const dim3 gQKV256(3 * DMODEL / 256, TOK / 256); // 192 blocks
  const dim3 gFFb(DMODEL / 64, TOK / 128);         // 512 blocks
  const dim3 gGLU(DMODEL / 64, TOK / 128);         // 512 blocks
  const dim3 gAttn(SEQ / 64, NH, BATCH);           // 1024 blocks
  const dim3 gVt(SEQ / 64, BATCH * NH);
  const dim3 gConv(TOK * 64 / 256);                // 2048 blocks

  // ---- weight preprocessing (single dispatch) ----
  {
    WJobs jobs;
    const float* srcs[10] = {f1w1, f1w2, f2w1, f2w2, wq, wk, wv, wo, pw1w, pw2w};
    ushort_t* dsts[10] = {f1w1T, f1w2T, f2w1T, f2w2T, wqkvT, wkT, wvT, woT, pw1T, pw2T};
    const int Ks[10] = {512, 2048, 512, 2048, 512, 512, 512, 512, 512, 512};
    const int Ns[10] = {2048, 512, 2048, 512, 512, 512, 512, 512, 1024, 512};
    int t0 = 0;
    for (int i = 0; i < 10; ++i) {
      jobs.j[i].src = srcs[i]; jobs.j[i].dst = dsts[i];
      jobs.j[i].K = Ks[i]; jobs.j[i].N = Ns[i]; jobs.j[i].t0 = t0;
      t0 += (Ks[i] / 32) * (Ns[i] / 32);
    }
    jobs.misc_t0 = t0;
    jobs.dww = dww; jobs.bq = bq; jobs.bk = bk; jobs.bv = bv;
    jobs.wTc = WTc; jobs.bcat = bcat;
    const int nmisc = (DMODEL * KCONV + 3 * DMODEL + 255) / 256;
    wcast_all<<<t0 + nmisc, blkT, 0, stream>>>(jobs);
  }

  // ---- FF1 half-step ----
  ln_kernel<true><<<gLN, blk, 0, stream>>>(x, n1g, n1b, Lbf);
  gemm256<1, false><<<gFFa256, blk512, 0, stream>>>(Lbf, f1w1T, f1b1, Hbf, FDIM);
  gemm_bf16<64,  0, true,  false, false><<<gFFb, blk, 0, stream>>>(Hbf, f1w2T, f1b2, x, 0.5f, out, TOK, DMODEL, FDIM);

  // ---- MHSA ----
  ln_kernel<true><<<gLN, blk, 0, stream>>>(out, n2g, n2b, Lbf);
  gemm256<0, true><<<gQKV256, blk512, 0, stream>>>(Lbf, wqkvT, bcat, QKVb, 3 * DMODEL);
  vtrans<<<gVt, blk, 0, stream>>>(QKVb, Vtb);
  attn_mfma<<<gAttn, blk, 0, stream>>>(QKVb, Vtb, Obf);
  gemm_bf16<64,  0, true,  false, false><<<gFFb, blk, 0, stream>>>(Obf, woT, bo, out, 1.0f, out, TOK, DMODEL, DMODEL);

  // ---- conv module ----
  ln2_kernel<<<gLN, blk, 0, stream>>>(out, n3g, n3b, clg, clb, Lbf);
  gemm_glu<<<gGLU, blk, 0, stream>>>(Lbf, pw1T, pw1b, Gbf);
  dwconv_bn_silu<<<gConv, blk, 0, stream>>>(Gbf, WTc, dwb, bng, bnb, bnm, bnv, Cbf);
  gemm_bf16<64,  0, true,  false, false><<<gFFb, blk, 0, stream>>>(Cbf, pw2T, pw2b, out, 1.0f, out, TOK, DMODEL, DMODEL);

  // ---- FF2 half-step ----
  ln_kernel<true><<<gLN, blk, 0, stream>>>(out, n4g, n4b, Lbf);
  gemm256<1, false><<<gFFa256, blk512, 0, stream>>>(Lbf, f2w1T, f2b1, Hbf, FDIM);
  gemm_bf16<64,  0, true,  false, false><<<gFFb, blk, 0, stream>>>(Hbf, f2w2T, f2b2, out, 0.5f, out, TOK, DMODEL, FDIM);
}

// Round 11
// 307.574 us; speedup vs baseline: 1.3050x; 1.0113x over previous
//
#include <hip/hip_runtime.h>
#include <math.h>

#define TOK    8192
#define DMODEL 512
#define FDIM   2048
#define NH     8
#define DKH    64
#define SEQ    1024
#define BATCH  8
#define KCONV  31
#define LN_EPS 1e-5f

typedef __attribute__((ext_vector_type(8))) short bf16x8;
typedef __attribute__((ext_vector_type(4))) float f32x4;
typedef unsigned short ushort_t;

#define AS1 __attribute__((address_space(1)))
#define AS3 __attribute__((address_space(3)))

// 0.125 (1/sqrt(64)) * log2(e): QK scores land in base-2 domain
#define QSCALE 0.1803368801111204f

__device__ __forceinline__ float sigf(float x) { return 1.0f / (1.0f + __expf(-x)); }
__device__ __forceinline__ float exp2n(float x) { return __builtin_amdgcn_exp2f(x); }

__device__ __forceinline__ unsigned short f2bf(float f) {
  unsigned u = __float_as_uint(f);
  u = u + 0x7fffu + ((u >> 16) & 1u);   // RNE
  return (unsigned short)(u >> 16);
}
__device__ __forceinline__ unsigned pk2(float a, float b) {
  return (unsigned)f2bf(a) | ((unsigned)f2bf(b) << 16);
}
__device__ __forceinline__ float bf2f(ushort_t u) {
  return __uint_as_float((unsigned)u << 16);
}

// XCD-aware bijective block swizzle (grids here are multiples of 8).
__device__ __forceinline__ void xcd_swizzle(int gx, int* bx, int* by) {
  const int nwg = gx * (int)gridDim.y;
  const int cpx = nwg >> 3;
  const int bid = (*by) * gx + (*bx);
  const int wg = (bid & 7) * cpx + (bid >> 3);
  *bx = wg % gx;
  *by = wg / gx;
}

// ---------------- all weight prep in ONE dispatch ---------------------------
struct WJob { const float* src; ushort_t* dst; int K, N, t0; };
struct WJobs {
  WJob j[10];
  int misc_t0;
  const float* dww; const float* bq; const float* bk; const float* bv;
  float* wTc; float* bcat;
};

__global__ __launch_bounds__(256) void wcast_all(WJobs jobs) {
  __shared__ float tile[32][33];
  const int t = blockIdx.x;
  const int tx = threadIdx.x, ty = threadIdx.y;  // 32 x 8
  if (t >= jobs.misc_t0) {
    const int idx = (t - jobs.misc_t0) * 256 + ty * 32 + tx;
    if (idx < DMODEL * KCONV) {
      const int d = idx / KCONV, k = idx % KCONV;
      jobs.wTc[k * DMODEL + d] = jobs.dww[idx];
    } else if (idx < DMODEL * KCONV + 3 * DMODEL) {
      const int c = idx - DMODEL * KCONV;
      jobs.bcat[c] = (c < DMODEL) ? jobs.bq[c]
                    : (c < 2 * DMODEL ? jobs.bk[c - DMODEL] : jobs.bv[c - 2 * DMODEL]);
    }
    return;
  }
  int i = 0;
#pragma unroll
  for (int k = 1; k < 10; ++k) if (t >= jobs.j[k].t0) i = k;
  const WJob jb = jobs.j[i];
  const int local = t - jb.t0;
  const int ntx = jb.N >> 5;
  const int bx = (local % ntx) * 32, by = (local / ntx) * 32;
#pragma unroll
  for (int r = 0; r < 32; r += 8)
    tile[ty + r][tx] = jb.src[(size_t)(by + ty + r) * jb.N + bx + tx];
  __syncthreads();
#pragma unroll
  for (int r = 0; r < 32; r += 8)
    jb.dst[(size_t)(bx + ty + r) * jb.K + by + tx] = f2bf(tile[tx][ty + r]);
}

// ---------------- LayerNorm: one wave per 512-wide row ----------------------
template <bool OBF>
__global__ __launch_bounds__(256) void ln_kernel(const float* __restrict__ in,
                                                 const float* __restrict__ g,
                                                 const float* __restrict__ b,
                                                 void* __restrict__ outp) {
  const int wave = threadIdx.x >> 6, lane = threadIdx.x & 63;
  const size_t row = (size_t)blockIdx.x * 4 + wave;
  const float* p = in + row * DMODEL + lane * 8;
  const float4 v0 = *(const float4*)p;
  const float4 v1 = *(const float4*)(p + 4);
  float s  = v0.x + v0.y + v0.z + v0.w + v1.x + v1.y + v1.z + v1.w;
  float ss = v0.x*v0.x + v0.y*v0.y + v0.z*v0.z + v0.w*v0.w
           + v1.x*v1.x + v1.y*v1.y + v1.z*v1.z + v1.w*v1.w;
#pragma unroll
  for (int m = 1; m < 64; m <<= 1) { s += __shfl_xor(s, m); ss += __shfl_xor(ss, m); }
  const float mean = s * (1.0f / DMODEL);
  const float var  = ss * (1.0f / DMODEL) - mean * mean;
  const float rstd = rsqrtf(var + LN_EPS);
  const float4 g0 = *(const float4*)(g + lane * 8);
  const float4 g1 = *(const float4*)(g + lane * 8 + 4);
  const float4 bb0 = *(const float4*)(b + lane * 8);
  const float4 bb1 = *(const float4*)(b + lane * 8 + 4);
  float o[8];
  o[0] = (v0.x - mean) * rstd * g0.x + bb0.x;
  o[1] = (v0.y - mean) * rstd * g0.y + bb0.y;
  o[2] = (v0.z - mean) * rstd * g0.z + bb0.z;
  o[3] = (v0.w - mean) * rstd * g0.w + bb0.w;
  o[4] = (v1.x - mean) * rstd * g1.x + bb1.x;
  o[5] = (v1.y - mean) * rstd * g1.y + bb1.y;
  o[6] = (v1.z - mean) * rstd * g1.z + bb1.z;
  o[7] = (v1.w - mean) * rstd * g1.w + bb1.w;
  if (OBF) {
    uint4 pkv;
    pkv.x = pk2(o[0], o[1]); pkv.y = pk2(o[2], o[3]);
    pkv.z = pk2(o[4], o[5]); pkv.w = pk2(o[6], o[7]);
    *(uint4*)((ushort_t*)outp + row * DMODEL + lane * 8) = pkv;
  } else {
    float4 a, c;
    a.x = o[0]; a.y = o[1]; a.z = o[2]; a.w = o[3];
    c.x = o[4]; c.y = o[5]; c.z = o[6]; c.w = o[7];
    float* q = (float*)outp + row * DMODEL + lane * 8;
    *(float4*)q = a;
    *(float4*)(q + 4) = c;
  }
}

// ---------------- fused double LayerNorm (norm3 then conv_ln), bf16 out -----
__global__ __launch_bounds__(256) void ln2_kernel(const float* __restrict__ in,
                                                  const float* __restrict__ g1,
                                                  const float* __restrict__ b1,
                                                  const float* __restrict__ g2,
                                                  const float* __restrict__ b2,
                                                  ushort_t* __restrict__ outp) {
  const int wave = threadIdx.x >> 6, lane = threadIdx.x & 63;
  const size_t row = (size_t)blockIdx.x * 4 + wave;
  const float* p = in + row * DMODEL + lane * 8;
  float v[8];
  {
    const float4 v0 = *(const float4*)p;
    const float4 v1 = *(const float4*)(p + 4);
    v[0]=v0.x; v[1]=v0.y; v[2]=v0.z; v[3]=v0.w;
    v[4]=v1.x; v[5]=v1.y; v[6]=v1.z; v[7]=v1.w;
  }
  float s = 0.f, ss = 0.f;
#pragma unroll
  for (int e = 0; e < 8; ++e) { s += v[e]; ss += v[e]*v[e]; }
#pragma unroll
  for (int m = 1; m < 64; m <<= 1) { s += __shfl_xor(s, m); ss += __shfl_xor(ss, m); }
  float mean = s * (1.0f / DMODEL);
  float rstd = rsqrtf(ss * (1.0f / DMODEL) - mean * mean + LN_EPS);
  const float4 ga = *(const float4*)(g1 + lane * 8);
  const float4 gb = *(const float4*)(g1 + lane * 8 + 4);
  const float4 ba = *(const float4*)(b1 + lane * 8);
  const float4 bb = *(const float4*)(b1 + lane * 8 + 4);
  const float gg1[8] = {ga.x,ga.y,ga.z,ga.w,gb.x,gb.y,gb.z,gb.w};
  const float bb1[8] = {ba.x,ba.y,ba.z,ba.w,bb.x,bb.y,bb.z,bb.w};
#pragma unroll
  for (int e = 0; e < 8; ++e) v[e] = (v[e] - mean) * rstd * gg1[e] + bb1[e];
  s = 0.f; ss = 0.f;
#pragma unroll
  for (int e = 0; e < 8; ++e) { s += v[e]; ss += v[e]*v[e]; }
#pragma unroll
  for (int m = 1; m < 64; m <<= 1) { s += __shfl_xor(s, m); ss += __shfl_xor(ss, m); }
  mean = s * (1.0f / DMODEL);
  rstd = rsqrtf(ss * (1.0f / DMODEL) - mean * mean + LN_EPS);
  const float4 gc = *(const float4*)(g2 + lane * 8);
  const float4 gd = *(const float4*)(g2 + lane * 8 + 4);
  const float4 bc = *(const float4*)(b2 + lane * 8);
  const float4 bd = *(const float4*)(b2 + lane * 8 + 4);
  const float gg2[8] = {gc.x,gc.y,gc.z,gc.w,gd.x,gd.y,gd.z,gd.w};
  const float bb2[8] = {bc.x,bc.y,bc.z,bc.w,bd.x,bd.y,bd.z,bd.w};
  float o[8];
#pragma unroll
  for (int e = 0; e < 8; ++e) o[e] = (v[e] - mean) * rstd * gg2[e] + bb2[e];
  uint4 pkv;
  pkv.x = pk2(o[0], o[1]); pkv.y = pk2(o[2], o[3]);
  pkv.z = pk2(o[4], o[5]); pkv.w = pk2(o[6], o[7]);
  *(uint4*)(outp + row * DMODEL + lane * 8) = pkv;
}

// ================= 8-phase 256x256 GEMM (T2+T3+T4+T5), K=512 ================
template <int ACT, bool QSC>
__global__ __launch_bounds__(512, 2) void gemm256(const ushort_t* __restrict__ A,
                                                  const ushort_t* __restrict__ Bt,
                                                  const float* __restrict__ bias,
                                                  ushort_t* __restrict__ Cout,
                                                  int N) {
  __shared__ ushort_t lds[65536];   // 128 KB
  const int t = threadIdx.x;
  const int l = t & 63;
  const int wid = t >> 6;
  const int wm = wid >> 2, wn = wid & 3;
  int bx = blockIdx.x, by = blockIdx.y;
  xcd_swizzle(gridDim.x, &bx, &by);
  const int m0 = by * 256, n0 = bx * 256;
  const int K = 512;

  f32x4 acc[8][4];
#pragma unroll
  for (int m = 0; m < 8; ++m)
#pragma unroll
    for (int n = 0; n < 4; ++n) acc[m][n] = (f32x4){0.f, 0.f, 0.f, 0.f};

  const int srow = t >> 3;
  const int schunk = (t & 7) ^ ((t >> 3) & 7);

#define STAGE_A(TAU, C_, I_)                                                    \
  __builtin_amdgcn_global_load_lds(                                             \
      (const AS1 unsigned*)(A + (size_t)(m0 + (I_) * 64 + srow) * K +           \
                            (TAU) * 64 + schunk * 8),                           \
      (AS3 unsigned*)(lds + (C_) * 16384 + ((I_) * 512 + t) * 8), 16, 0, 0)
#define STAGE_B(TAU, C_, I_)                                                    \
  __builtin_amdgcn_global_load_lds(                                             \
      (const AS1 unsigned*)(Bt + (size_t)(n0 + (I_) * 64 + srow) * K +          \
                            (TAU) * 64 + schunk * 8),                           \
      (AS3 unsigned*)(lds + 32768 + (C_) * 16384 + ((I_) * 512 + t) * 8), 16, 0, 0)

#pragma unroll
  for (int i = 0; i < 4; ++i) STAGE_B(0, 0, i);
#pragma unroll
  for (int i = 0; i < 4; ++i) STAGE_A(0, 0, i);
#pragma unroll
  for (int i = 0; i < 4; ++i) STAGE_B(1, 1, i);
  STAGE_A(1, 1, 0);
  STAGE_A(1, 1, 2);
  asm volatile("s_waitcnt vmcnt(6)" ::: "memory");
  __builtin_amdgcn_s_barrier();

  const int arow = (l & 15);
  const int kch0 = (l >> 4);
  bf16x8 bfr[2][4];

  for (int it = 0; it < 4; ++it) {
    const bool stg = (it < 3);
#pragma unroll
    for (int h = 0; h < 2; ++h) {
      const int c = h;
#pragma unroll
      for (int p = 0; p < 4; ++p) {
        bf16x8 afr[2][2];
#pragma unroll
        for (int m2 = 0; m2 < 2; ++m2)
#pragma unroll
          for (int ks = 0; ks < 2; ++ks) {
            const int row = wm * 128 + (2 * p + m2) * 16 + arow;
            const int ch = (ks * 4 + kch0) ^ (row & 7);
            afr[m2][ks] = *(const bf16x8*)(lds + c * 16384 + row * 64 + ch * 8);
          }
        if (p == 0) {
#pragma unroll
          for (int nr = 0; nr < 4; ++nr)
#pragma unroll
            for (int ks = 0; ks < 2; ++ks) {
              const int row = wn * 64 + nr * 16 + arow;
              const int ch = (ks * 4 + kch0) ^ (row & 7);
              bfr[ks][nr] = *(const bf16x8*)(lds + 32768 + c * 16384 + row * 64 + ch * 8);
            }
        }
        if (p == 0) {
          if (h == 0 || stg) {
            STAGE_A(2 * it + h + 1, c ^ 1, 1);
            STAGE_A(2 * it + h + 1, c ^ 1, 3);
          }
        } else if (p == 1) {
          if (stg) {
#pragma unroll
            for (int i = 0; i < 4; ++i) STAGE_B(2 * it + h + 2, c, i);
          }
        } else if (p == 2) {
          if (stg) {
            STAGE_A(2 * it + h + 2, c, 0);
            STAGE_A(2 * it + h + 2, c, 2);
          }
        }
        __builtin_amdgcn_s_barrier();
        __builtin_amdgcn_s_setprio(1);
#pragma unroll
        for (int ks = 0; ks < 2; ++ks)
#pragma unroll
          for (int m2 = 0; m2 < 2; ++m2)
#pragma unroll
            for (int nr = 0; nr < 4; ++nr)
              acc[2 * p + m2][nr] = __builtin_amdgcn_mfma_f32_16x16x32_bf16(
                  afr[m2][ks], bfr[ks][nr], acc[2 * p + m2][nr], 0, 0, 0);
        __builtin_amdgcn_s_setprio(0);
        if (p == 3) {
          if (h == 0) {
            if (stg) asm volatile("s_waitcnt vmcnt(6)" ::: "memory");
            else     asm volatile("s_waitcnt vmcnt(0)" ::: "memory");
          } else if (stg) {
            asm volatile("s_waitcnt vmcnt(6)" ::: "memory");
          }
        }
        __builtin_amdgcn_s_barrier();
      }
    }
  }
#undef STAGE_A
#undef STAGE_B

#pragma unroll
  for (int m = 0; m < 8; ++m) {
    const int row_b = m0 + wm * 128 + m * 16 + (l >> 4) * 4;
#pragma unroll
    for (int n = 0; n < 4; ++n) {
      const int col = n0 + wn * 64 + n * 16 + (l & 15);
      const float bv = bias[col];
      const float sc = QSC ? (col < DMODEL ? QSCALE : 1.0f) : 1.0f;
#pragma unroll
      for (int j = 0; j < 4; ++j) {
        float v = acc[m][n][j] + bv;
        if (ACT == 1) v = fmaxf(v, 0.f);
        v *= sc;
        Cout[(size_t)(row_b + j) * N + col] = f2bf(v);
      }
    }
  }
}

// ---------------- bf16 MFMA GEMM (m97 structure), TN = 128 or 64 ------------
template <int TN, int ACT, bool RES, bool OBF, bool QSC>
__global__ __launch_bounds__(256) void gemm_bf16(const ushort_t* __restrict__ A,
                                                 const ushort_t* __restrict__ Bt,
                                                 const float* __restrict__ bias,
                                                 const float* __restrict__ Rp,
                                                 float alpha,
                                                 void* __restrict__ Cout,
                                                 int M, int N, int K) {
  constexpr int NF = TN / 32;
  constexpr int NB = TN / 32;
  __shared__ ushort_t Al[128 * 64];
  __shared__ ushort_t Bl[TN * 64];
  const int t = threadIdx.x;
  const int lane = t & 63;
  const int wid = t >> 6;
  const int wr = wid >> 1, wc = wid & 1;
  int bx = blockIdx.x, by = blockIdx.y;
  xcd_swizzle(gridDim.x, &bx, &by);
  const int m0 = by * 128, n0 = bx * TN;

  f32x4 acc[4][NF];
#pragma unroll
  for (int m = 0; m < 4; ++m)
#pragma unroll
    for (int n = 0; n < NF; ++n) acc[m][n] = (f32x4){0.f, 0.f, 0.f, 0.f};

  const int srow = t >> 3;
  const int scol = (t & 7) * 8;
  const ushort_t* Ag = A + (size_t)(m0 + srow) * K + scol;
  const ushort_t* Bg = Bt + (size_t)(n0 + srow) * K + scol;

  for (int k0 = 0; k0 < K; k0 += 64) {
    __syncthreads();
#pragma unroll
    for (int i = 0; i < 4; ++i) {
      __builtin_amdgcn_global_load_lds(
          (const AS1 unsigned*)(Ag + (size_t)i * 32 * K + k0),
          (AS3 unsigned*)(Al + ((size_t)i * 256 + t) * 8),
          16, 0, 0);
    }
#pragma unroll
    for (int i = 0; i < NB; ++i) {
      __builtin_amdgcn_global_load_lds(
          (const AS1 unsigned*)(Bg + (size_t)i * 32 * K + k0),
          (AS3 unsigned*)(Bl + ((size_t)i * 256 + t) * 8),
          16, 0, 0);
    }
    __syncthreads();

#pragma unroll
    for (int ks = 0; ks < 2; ++ks) {
      const int kk = ks * 32 + (lane >> 4) * 8;
      bf16x8 af[4], bfv[NF];
#pragma unroll
      for (int m = 0; m < 4; ++m)
        af[m] = *(const bf16x8*)(Al + (wr * 64 + m * 16 + (lane & 15)) * 64 + kk);
#pragma unroll
      for (int n = 0; n < NF; ++n)
        bfv[n] = *(const bf16x8*)(Bl + (wc * (TN / 2) + n * 16 + (lane & 15)) * 64 + kk);
#pragma unroll
      for (int m = 0; m < 4; ++m)
#pragma unroll
        for (int n = 0; n < NF; ++n)
          acc[m][n] = __builtin_amdgcn_mfma_f32_16x16x32_bf16(af[m], bfv[n], acc[m][n], 0, 0, 0);
    }
  }

#pragma unroll
  for (int m = 0; m < 4; ++m) {
    const int row_b = m0 + wr * 64 + m * 16 + (lane >> 4) * 4;
#pragma unroll
    for (int n = 0; n < NF; ++n) {
      const int col = n0 + wc * (TN / 2) + n * 16 + (lane & 15);
      const float bv = bias[col];
#pragma unroll
      for (int j = 0; j < 4; ++j) {
        float v = acc[m][n][j] + bv;
        if (ACT == 1) v = fmaxf(v, 0.f);
        if (QSC) v *= (col < DMODEL ? QSCALE : 1.0f);
        const size_t idx = (size_t)(row_b + j) * N + col;
        if (RES) v = Rp[idx] + alpha * v;
        if (OBF) ((ushort_t*)Cout)[idx] = f2bf(v);
        else     ((float*)Cout)[idx] = v;
      }
    }
  }
}

// ---------------- fused pw1 + GLU GEMM --------------------------------------
__global__ __launch_bounds__(256) void gemm_glu(const ushort_t* __restrict__ A,
                                                const ushort_t* __restrict__ Bt,
                                                const float* __restrict__ bias,
                                                ushort_t* __restrict__ Cout) {
  __shared__ ushort_t Al[128 * 64];
  __shared__ ushort_t Bl[128 * 64];
  const int t = threadIdx.x;
  const int lane = t & 63;
  const int wid = t >> 6;
  const int wr = wid >> 1, wc = wid & 1;
  int bx = blockIdx.x, by = blockIdx.y;
  xcd_swizzle(gridDim.x, &bx, &by);
  const int m0 = by * 128, n0 = bx * 64;
  const int K = DMODEL, N = DMODEL;

  f32x4 aa[4][2], ag[4][2];
#pragma unroll
  for (int m = 0; m < 4; ++m)
#pragma unroll
    for (int n = 0; n < 2; ++n) {
      aa[m][n] = (f32x4){0.f, 0.f, 0.f, 0.f};
      ag[m][n] = (f32x4){0.f, 0.f, 0.f, 0.f};
    }

  const int srow = t >> 3;
  const int scol = (t & 7) * 8;
  const ushort_t* Ag_ = A + (size_t)(m0 + srow) * K + scol;
  const ushort_t* Ba_ = Bt + (size_t)(n0 + srow) * K + scol;
  const ushort_t* Bg_ = Bt + (size_t)(512 + n0 + srow) * K + scol;

  for (int k0 = 0; k0 < K; k0 += 64) {
    __syncthreads();
#pragma unroll
    for (int i = 0; i < 4; ++i) {
      __builtin_amdgcn_global_load_lds(
          (const AS1 unsigned*)(Ag_ + (size_t)i * 32 * K + k0),
          (AS3 unsigned*)(Al + ((size_t)i * 256 + t) * 8),
          16, 0, 0);
    }
#pragma unroll
    for (int i = 0; i < 2; ++i) {
      __builtin_amdgcn_global_load_lds(
          (const AS1 unsigned*)(Ba_ + (size_t)i * 32 * K + k0),
          (AS3 unsigned*)(Bl + ((size_t)i * 256 + t) * 8),
          16, 0, 0);
      __builtin_amdgcn_global_load_lds(
          (const AS1 unsigned*)(Bg_ + (size_t)i * 32 * K + k0),
          (AS3 unsigned*)(Bl + 64 * 64 + ((size_t)i * 256 + t) * 8),
          16, 0, 0);
    }
    __syncthreads();

#pragma unroll
    for (int ks = 0; ks < 2; ++ks) {
      const int kk = ks * 32 + (lane >> 4) * 8;
      bf16x8 af[4], bfa[2], bfg[2];
#pragma unroll
      for (int m = 0; m < 4; ++m)
        af[m] = *(const bf16x8*)(Al + (wr * 64 + m * 16 + (lane & 15)) * 64 + kk);
#pragma unroll
      for (int n = 0; n < 2; ++n) {
        bfa[n] = *(const bf16x8*)(Bl + (wc * 32 + n * 16 + (lane & 15)) * 64 + kk);
        bfg[n] = *(const bf16x8*)(Bl + (64 + wc * 32 + n * 16 + (lane & 15)) * 64 + kk);
      }
#pragma unroll
      for (int m = 0; m < 4; ++m)
#pragma unroll
        for (int n = 0; n < 2; ++n) {
          aa[m][n] = __builtin_amdgcn_mfma_f32_16x16x32_bf16(af[m], bfa[n], aa[m][n], 0, 0, 0);
          ag[m][n] = __builtin_amdgcn_mfma_f32_16x16x32_bf16(af[m], bfg[n], ag[m][n], 0, 0, 0);
        }
    }
  }

#pragma unroll
  for (int m = 0; m < 4; ++m) {
    const int row_b = m0 + wr * 64 + m * 16 + (lane >> 4) * 4;
#pragma unroll
    for (int n = 0; n < 2; ++n) {
      const int col = n0 + wc * 32 + n * 16 + (lane & 15);
      const float ba_v = bias[col];
      const float bg_v = bias[col + DMODEL];
#pragma unroll
      for (int j = 0; j < 4; ++j) {
        const float av = aa[m][n][j] + ba_v;
        const float gv = ag[m][n][j] + bg_v;
        Cout[(size_t)(row_b + j) * N + col] = f2bf(av * sigf(gv));
      }
    }
  }
}

// ---------------- V transpose per head: QKV[b][s][1024+h*64+d] -> [bh][d][s] -
__global__ __launch_bounds__(256) void vtrans(const ushort_t* __restrict__ QKV,
                                              ushort_t* __restrict__ Vt) {
  __shared__ ushort_t tl[64][72];
  const int st = blockIdx.x;
  const int bh = blockIdx.y;
  const int b = bh >> 3, h = bh & 7;
  const int t = threadIdx.x;
#pragma unroll
  for (int i = 0; i < 2; ++i) {
    const int chunk = i * 256 + t;
    const int sr = chunk >> 3, c8 = (chunk & 7) * 8;
    *(uint4*)&tl[sr][c8] =
        *(const uint4*)(QKV + ((size_t)(b * SEQ + st * 64 + sr) * (3 * DMODEL)) + 2 * DMODEL + h * DKH + c8);
  }
  __syncthreads();
#pragma unroll
  for (int i = 0; i < 2; ++i) {
    const int chunk = i * 256 + t;
    const int dr = chunk >> 3, c8 = (chunk & 7) * 8;
    ushort_t tmp[8];
#pragma unroll
    for (int e = 0; e < 8; ++e) tmp[e] = tl[c8 + e][dr];
    *(uint4*)(Vt + ((size_t)(bh * DKH + dr) * SEQ) + st * 64 + c8) = *(uint4*)tmp;
  }
}

// ---------------- MFMA flash attention, QBLK=64, KVBLK=128, 4 waves ---------
// T3 minimal 2-phase pipeline: K/V double-buffered in LDS; next tile's
// global_load_lds issued BEFORE current tile's compute; ONE __syncthreads per
// tile at the end (its vmcnt(0) drain lands after loads flew under compute).
__global__ __launch_bounds__(256) void attn_mfma(const ushort_t* __restrict__ QKV,
                                                 const ushort_t* __restrict__ Vt,
                                                 ushort_t* __restrict__ Om) {
  __shared__ ushort_t Ks[2][128 * 64];
  __shared__ ushort_t Vs[2][64 * 128];
  __shared__ ushort_t Ps[64 * 128];
  const int t = threadIdx.x;
  const int l = t & 63;
  const int w = t >> 6;
  const int qb = blockIdx.x, h = blockIdx.y, b = blockIdx.z;
  const size_t rowstr = 3 * DMODEL;
  const size_t baseQ = ((size_t)b * SEQ) * rowstr + (size_t)h * DKH;
  const size_t baseK = baseQ + DMODEL;
  const size_t baseV = (size_t)(b * NH + h) * DKH * SEQ;
  const size_t baseO = ((size_t)b * SEQ) * DMODEL + (size_t)h * DKH;

  bf16x8 qf[2];
  {
    const int qrow = qb * 64 + w * 16 + (l & 15);
    const ushort_t* qp = QKV + baseQ + (size_t)qrow * rowstr + ((l >> 4) * 8);
    qf[0] = *(const bf16x8*)(qp);
    qf[1] = *(const bf16x8*)(qp + 32);
  }

  const int krr = t >> 3, kch = t & 7;
  const int vrr = t >> 4, vch = t & 15;

#define STAGE_KV(KT, BUF)                                                       \
  {                                                                             \
    _Pragma("unroll")                                                           \
    for (int i = 0; i < 4; ++i) {                                               \
      const int r = i * 32 + krr;                                               \
      __builtin_amdgcn_global_load_lds(                                         \
          (const AS1 unsigned*)(QKV + baseK +                                   \
              (size_t)((KT) * 128 + r) * rowstr + ((kch ^ (r & 7)) * 8)),       \
          (AS3 unsigned*)(Ks[BUF] + ((size_t)i * 256 + t) * 8), 16, 0, 0);      \
    }                                                                           \
    _Pragma("unroll")                                                           \
    for (int i = 0; i < 4; ++i) {                                               \
      const int r = i * 16 + vrr;                                               \
      __builtin_amdgcn_global_load_lds(                                         \
          (const AS1 unsigned*)(Vt + baseV +                                    \
              (size_t)r * SEQ + (KT) * 128 + ((vch ^ (r & 15)) * 8)),           \
          (AS3 unsigned*)(Vs[BUF] + ((size_t)i * 256 + t) * 8), 16, 0, 0);      \
    }                                                                           \
  }

  float mrun[4], lrun[4];
  f32x4 o[4];
#pragma unroll
  for (int j = 0; j < 4; ++j) { mrun[j] = -1e30f; lrun[j] = 0.f; }
#pragma unroll
  for (int n = 0; n < 4; ++n) o[n] = (f32x4){0.f, 0.f, 0.f, 0.f};

  STAGE_KV(0, 0);
  __syncthreads();

  int cur = 0;
  for (int kt = 0; kt < SEQ / 128; ++kt) {
    // issue next tile's loads into the other buffer; they fly under compute
    if (kt + 1 < SEQ / 128) STAGE_KV(kt + 1, cur ^ 1);

    const ushort_t* Kc = Ks[cur];
    const ushort_t* Vc = Vs[cur];

    f32x4 s[8];
#pragma unroll
    for (int n = 0; n < 8; ++n) s[n] = (f32x4){0.f, 0.f, 0.f, 0.f};
    __builtin_amdgcn_s_setprio(1);
#pragma unroll
    for (int ks = 0; ks < 2; ++ks) {
      const int kk = ks * 64 + (l >> 4) * 16;
#pragma unroll
      for (int n = 0; n < 8; ++n) {
        const int krow = n * 16 + (l & 15);
        const bf16x8 kf = *(const bf16x8*)((const char*)Kc + krow * 128 + (kk ^ ((krow & 7) << 4)));
        s[n] = __builtin_amdgcn_mfma_f32_16x16x32_bf16(qf[ks], kf, s[n], 0, 0, 0);
      }
    }
    __builtin_amdgcn_s_setprio(0);

#pragma unroll
    for (int j = 0; j < 4; ++j) {
      float r0 = fmaxf(fmaxf(fmaxf(s[0][j], s[1][j]), fmaxf(s[2][j], s[3][j])),
                       fmaxf(fmaxf(s[4][j], s[5][j]), fmaxf(s[6][j], s[7][j])));
      r0 = fmaxf(r0, __shfl_xor(r0, 1));
      r0 = fmaxf(r0, __shfl_xor(r0, 2));
      r0 = fmaxf(r0, __shfl_xor(r0, 4));
      r0 = fmaxf(r0, __shfl_xor(r0, 8));
      const float mn = fmaxf(mrun[j], r0);
      const float cs = exp2n(mrun[j] - mn);
      const int prow = w * 16 + (l >> 4) * 4 + j;
      const int pswz = (prow & 15) << 4;
      float psum = 0.f;
#pragma unroll
      for (int n = 0; n < 8; ++n) {
        const float p = exp2n(s[n][j] - mn);
        psum += p;
        const int col2 = (n * 16 + (l & 15)) * 2;
        *(ushort_t*)((char*)Ps + prow * 256 + (col2 ^ pswz)) = f2bf(p);
      }
      psum += __shfl_xor(psum, 1);
      psum += __shfl_xor(psum, 2);
      psum += __shfl_xor(psum, 4);
      psum += __shfl_xor(psum, 8);
      lrun[j] = lrun[j] * cs + psum;
      mrun[j] = mn;
      o[0][j] *= cs; o[1][j] *= cs; o[2][j] *= cs; o[3][j] *= cs;
    }

    __builtin_amdgcn_s_setprio(1);
#pragma unroll
    for (int ks = 0; ks < 4; ++ks) {
      const int kk = ks * 64 + (l >> 4) * 16;
      const int arow = w * 16 + (l & 15);
      const bf16x8 pf = *(const bf16x8*)((char*)Ps + arow * 256 + (kk ^ ((arow & 15) << 4)));
#pragma unroll
      for (int n = 0; n < 4; ++n) {
        const int vrow = n * 16 + (l & 15);
        const bf16x8 vf = *(const bf16x8*)((const char*)Vc + vrow * 256 + (kk ^ ((vrow & 15) << 4)));
        o[n] = __builtin_amdgcn_mfma_f32_16x16x32_bf16(pf, vf, o[n], 0, 0, 0);
      }
    }
    __builtin_amdgcn_s_setprio(0);

    // ONE barrier per tile: compiler's vmcnt(0) drain covers next-tile loads
    // (they had the whole compute phase in flight) and publishes buf reuse.
    __syncthreads();
    cur ^= 1;
  }
#undef STAGE_KV

  float inv[4];
#pragma unroll
  for (int j = 0; j < 4; ++j) inv[j] = 1.0f / lrun[j];
#pragma unroll
  for (int j = 0; j < 4; ++j) {
    const int prow = w * 16 + (l >> 4) * 4 + j;
    const int pswz = (prow & 15) << 4;
#pragma unroll
    for (int n = 0; n < 4; ++n) {
      const int col2 = (n * 16 + (l & 15)) * 2;
      *(ushort_t*)((char*)Ps + prow * 256 + (col2 ^ pswz)) = f2bf(o[n][j] * inv[j]);
    }
  }
  __syncthreads();
#pragma unroll
  for (int i = 0; i < 2; ++i) {
    const int chunk = i * 256 + t;
    const int qr = chunk >> 3, c8 = (chunk & 7) * 8;
    const uint4 ov = *(const uint4*)((char*)Ps + qr * 256 + ((c8 * 2) ^ ((qr & 15) << 4)));
    *(uint4*)(Om + baseO + (size_t)(qb * 64 + qr) * DMODEL + c8) = ov;
  }
}

// -------- depthwise conv + bias + BN + SiLU, 8 channels/thread --------------
__global__ __launch_bounds__(256) void dwconv_bn_silu(const ushort_t* __restrict__ in,
                                                      const float* __restrict__ wT,
                                                      const float* __restrict__ dwb,
                                                      const float* __restrict__ bng,
                                                      const float* __restrict__ bnb,
                                                      const float* __restrict__ bnm,
                                                      const float* __restrict__ bnv,
                                                      ushort_t* __restrict__ out) {
  const size_t gid = (size_t)blockIdx.x * 256 + threadIdx.x;   // TOK*64
  const int dc = (int)(gid & 63) * 8;
  const int s = (int)((gid >> 6) & (SEQ - 1));
  const int b = (int)(gid >> 16);
  const ushort_t* bp = in + (size_t)b * SEQ * DMODEL;
  float a[8];
#pragma unroll
  for (int e = 0; e < 8; ++e) a[e] = 0.f;
#pragma unroll
  for (int k = 0; k < KCONV; ++k) {
    const int ssi = s + k - (KCONV / 2);
    if (ssi < 0 || ssi >= SEQ) continue;
    ushort_t xv[8];
    *(uint4*)xv = *(const uint4*)(bp + (size_t)ssi * DMODEL + dc);
    const float4 w0 = *(const float4*)(wT + k * DMODEL + dc);
    const float4 w1 = *(const float4*)(wT + k * DMODEL + dc + 4);
    a[0] = fmaf(bf2f(xv[0]), w0.x, a[0]); a[1] = fmaf(bf2f(xv[1]), w0.y, a[1]);
    a[2] = fmaf(bf2f(xv[2]), w0.z, a[2]); a[3] = fmaf(bf2f(xv[3]), w0.w, a[3]);
    a[4] = fmaf(bf2f(xv[4]), w1.x, a[4]); a[5] = fmaf(bf2f(xv[5]), w1.y, a[5]);
    a[6] = fmaf(bf2f(xv[6]), w1.z, a[6]); a[7] = fmaf(bf2f(xv[7]), w1.w, a[7]);
  }
  float v[8];
#pragma unroll
  for (int half = 0; half < 2; ++half) {
    const int d4 = dc + half * 4;
    const float4 bi = *(const float4*)(dwb + d4);
    const float4 mm = *(const float4*)(bnm + d4);
    const float4 vv = *(const float4*)(bnv + d4);
    const float4 gg = *(const float4*)(bng + d4);
    const float4 b2 = *(const float4*)(bnb + d4);
    const float bia[4] = {bi.x, bi.y, bi.z, bi.w};
    const float mma[4] = {mm.x, mm.y, mm.z, mm.w};
    const float vva[4] = {vv.x, vv.y, vv.z, vv.w};
    const float gga[4] = {gg.x, gg.y, gg.z, gg.w};
    const float b2a[4] = {b2.x, b2.y, b2.z, b2.w};
#pragma unroll
    for (int e = 0; e < 4; ++e) {
      float t0 = a[half * 4 + e] + bia[e];
      t0 = (t0 - mma[e]) * rsqrtf(vva[e] + LN_EPS) * gga[e] + b2a[e];
      v[half * 4 + e] = t0 * sigf(t0);
    }
  }
  uint4 o;
  o.x = pk2(v[0], v[1]); o.y = pk2(v[2], v[3]);
  o.z = pk2(v[4], v[5]); o.w = pk2(v[6], v[7]);
  *(uint4*)&out[(((size_t)b * SEQ + s) * DMODEL) + dc] = o;
}

extern "C" void kernel_launch(void* const* d_in, const int* in_sizes, int n_in,
                              void* d_out, int out_size, void* d_ws, size_t ws_size,
                              hipStream_t stream) {
  const float* x    = (const float*)d_in[0];
  const float* n1g  = (const float*)d_in[1];
  const float* n1b  = (const float*)d_in[2];
  const float* n2g  = (const float*)d_in[3];
  const float* n2b  = (const float*)d_in[4];
  const float* n3g  = (const float*)d_in[5];
  const float* n3b  = (const float*)d_in[6];
  const float* n4g  = (const float*)d_in[7];
  const float* n4b  = (const float*)d_in[8];
  const float* clg  = (const float*)d_in[9];
  const float* clb  = (const float*)d_in[10];
  const float* f1w1 = (const float*)d_in[11];
  const float* f1b1 = (const float*)d_in[12];
  const float* f1w2 = (const float*)d_in[13];
  const float* f1b2 = (const float*)d_in[14];
  const float* f2w1 = (const float*)d_in[15];
  const float* f2b1 = (const float*)d_in[16];
  const float* f2w2 = (const float*)d_in[17];
  const float* f2b2 = (const float*)d_in[18];
  const float* wq   = (const float*)d_in[19];
  const float* bq   = (const float*)d_in[20];
  const float* wk   = (const float*)d_in[21];
  const float* bk   = (const float*)d_in[22];
  const float* wv   = (const float*)d_in[23];
  const float* bv   = (const float*)d_in[24];
  const float* wo   = (const float*)d_in[25];
  const float* bo   = (const float*)d_in[26];
  const float* pw1w = (const float*)d_in[27];
  const float* pw1b = (const float*)d_in[28];
  const float* dww  = (const float*)d_in[29];
  const float* dwb  = (const float*)d_in[30];
  const float* bng  = (const float*)d_in[31];
  const float* bnb  = (const float*)d_in[32];
  const float* bnm  = (const float*)d_in[33];
  const float* bnv  = (const float*)d_in[34];
  const float* pw2w = (const float*)d_in[35];
  const float* pw2b = (const float*)d_in[36];

  char* wsb = (char*)d_ws;
  const size_t MB = 1ull << 20;
  ushort_t* Wbf    = (ushort_t*)(wsb + 0);
  ushort_t* f1w1T  = Wbf + 0;
  ushort_t* f1w2T  = Wbf + (1ull << 20);
  ushort_t* f2w1T  = Wbf + (2ull << 20);
  ushort_t* f2w2T  = Wbf + (3ull << 20);
  ushort_t* wqkvT  = Wbf + (4ull << 20);
  ushort_t* wkT    = wqkvT + (256ull << 10);
  ushort_t* wvT    = wqkvT + (512ull << 10);
  ushort_t* woT    = wqkvT + (768ull << 10);
  ushort_t* pw1T   = Wbf + (5ull << 20);
  ushort_t* pw2T   = Wbf + (5ull << 20) + (512ull << 10);
  float*    WTc    = (float*)(wsb + 12 * MB);
  float*    bcat   = (float*)(wsb + 12 * MB + 128 * 1024);
  ushort_t* Lbf    = (ushort_t*)(wsb + 13 * MB);
  ushort_t* Hbf    = (ushort_t*)(wsb + 21 * MB);
  ushort_t* QKVb   = (ushort_t*)(wsb + 53 * MB);
  ushort_t* Vtb    = (ushort_t*)(wsb + 77 * MB);
  ushort_t* Gbf    = (ushort_t*)(wsb + 53 * MB);
  ushort_t* Obf    = (ushort_t*)(wsb + 85 * MB);
  ushort_t* Cbf    = Obf;
  float* out = (float*)d_out;

  const dim3 blk(256);
  const dim3 blk512(512);
  const dim3 blkT(32, 8);
  const dim3 gLN(TOK / 4);
  const dim3 gFFa256(FDIM / 256, TOK / 256);       // 256 blocks
  const dim3 gQKV256(3 * DMODEL / 256, TOK / 256); // 192 blocks
  const dim3 gFFb(DMODEL / 64, TOK / 128);         // 512 blocks
  const dim3 gGLU(DMODEL / 64, TOK / 128);         // 512 blocks
  const dim3 gAttn(SEQ / 64, NH, BATCH);           // 1024 blocks
  const dim3 gVt(SEQ / 64, BATCH * NH);
  const dim3 gConv(TOK * 64 / 256);                // 2048 blocks

  // ---- weight preprocessing (single dispatch) ----
  {
    WJobs jobs;
    const float* srcs[10] = {f1w1, f1w2, f2w1, f2w2, wq, wk, wv, wo, pw1w, pw2w};
    ushort_t* dsts[10] = {f1w1T, f1w2T, f2w1T, f2w2T, wqkvT, wkT, wvT, woT, pw1T, pw2T};
    const int Ks[10] = {512, 2048, 512, 2048, 512, 512, 512, 512, 512, 512};
    const int Ns[10] = {2048, 512, 2048, 512, 512, 512, 512, 512, 1024, 512};
    int t0 = 0;
    for (int i = 0; i < 10; ++i) {
      jobs.j[i].src = srcs[i]; jobs.j[i].dst = dsts[i];
      jobs.j[i].K = Ks[i]; jobs.j[i].N = Ns[i]; jobs.j[i].t0 = t0;
      t0 += (Ks[i] / 32) * (Ns[i] / 32);
    }
    jobs.misc_t0 = t0;
    jobs.dww = dww; jobs.bq = bq; jobs.bk = bk; jobs.bv = bv;
    jobs.wTc = WTc; jobs.bcat = bcat;
    const int nmisc = (DMODEL * KCONV + 3 * DMODEL + 255) / 256;
    wcast_all<<<t0 + nmisc, blkT, 0, stream>>>(jobs);
  }

  // ---- FF1 half-step ----
  ln_kernel<true><<<gLN, blk, 0, stream>>>(x, n1g, n1b, Lbf);
  gemm256<1, false><<<gFFa256, blk512, 0, stream>>>(Lbf, f1w1T, f1b1, Hbf, FDIM);
  gemm_bf16<64,  0, true,  false, false><<<gFFb, blk, 0, stream>>>(Hbf, f1w2T, f1b2, x, 0.5f, out, TOK, DMODEL, FDIM);

  // ---- MHSA ----
  ln_kernel<true><<<gLN, blk, 0, stream>>>(out, n2g, n2b, Lbf);
  gemm256<0, true><<<gQKV256, blk512, 0, stream>>>(Lbf, wqkvT, bcat, QKVb, 3 * DMODEL);
  vtrans<<<gVt, blk, 0, stream>>>(QKVb, Vtb);
  attn_mfma<<<gAttn, blk, 0, stream>>>(QKVb, Vtb, Obf);
  gemm_bf16<64,  0, true,  false, false><<<gFFb, blk, 0, stream>>>(Obf, woT, bo, out, 1.0f, out, TOK, DMODEL, DMODEL);

  // ---- conv module ----
  ln2_kernel<<<gLN, blk, 0, stream>>>(out, n3g, n3b, clg, clb, Lbf);
  gemm_glu<<<gGLU, blk, 0, stream>>>(Lbf, pw1T, pw1b, Gbf);
  dwconv_bn_silu<<<gConv, blk, 0, stream>>>(Gbf, WTc, dwb, bng, bnb, bnm, bnv, Cbf);
  gemm_bf16<64,  0, true,  false, false><<<gFFb, blk, 0, stream>>>(Cbf, pw2T, pw2b, out, 1.0f, out, TOK, DMODEL, DMODEL);

  // ---- FF2 half-step ----
  ln_kernel<true><<<gLN, blk, 0, stream>>>(out, n4g, n4b, Lbf);
  gemm256<1, false><<<gFFa256, blk512, 0, stream>>>(Lbf, f2w1T, f2b1, Hbf, FDIM);
  gemm_bf16<64,  0, true,  false, false><<<gFFb, blk, 0, stream>>>(Hbf, f2w2T, f2b2, out, 0.5f, out, TOK, DMODEL, FDIM);
}

// Round 12
// 296.233 us; speedup vs baseline: 1.3550x; 1.0383x over previous
//
#include <hip/hip_runtime.h>
#include <math.h>

#define TOK    8192
#define DMODEL 512
#define FDIM   2048
#define NH     8
#define DKH    64
#define SEQ    1024
#define BATCH  8
#define KCONV  31
#define LN_EPS 1e-5f

typedef __attribute__((ext_vector_type(8))) short bf16x8;
typedef __attribute__((ext_vector_type(4))) float f32x4;
typedef unsigned short ushort_t;

#define AS1 __attribute__((address_space(1)))
#define AS3 __attribute__((address_space(3)))

// 0.125 (1/sqrt(64)) * log2(e): QK scores land in base-2 domain
#define QSCALE 0.1803368801111204f

__device__ __forceinline__ float sigf(float x) { return 1.0f / (1.0f + __expf(-x)); }
__device__ __forceinline__ float exp2n(float x) { return __builtin_amdgcn_exp2f(x); }

__device__ __forceinline__ unsigned short f2bf(float f) {
  unsigned u = __float_as_uint(f);
  u = u + 0x7fffu + ((u >> 16) & 1u);   // RNE
  return (unsigned short)(u >> 16);
}
__device__ __forceinline__ unsigned pk2(float a, float b) {
  return (unsigned)f2bf(a) | ((unsigned)f2bf(b) << 16);
}
__device__ __forceinline__ float bf2f(ushort_t u) {
  return __uint_as_float((unsigned)u << 16);
}

// XCD-aware bijective block swizzle (grids here are multiples of 8).
__device__ __forceinline__ void xcd_swizzle(int gx, int* bx, int* by) {
  const int nwg = gx * (int)gridDim.y;
  const int cpx = nwg >> 3;
  const int bid = (*by) * gx + (*bx);
  const int wg = (bid & 7) * cpx + (bid >> 3);
  *bx = wg % gx;
  *by = wg / gx;
}

// ---------------- all weight prep in ONE dispatch ---------------------------
struct WJob { const float* src; ushort_t* dst; int K, N, t0; };
struct WJobs {
  WJob j[10];
  int misc_t0;
  const float* dww; const float* bq; const float* bk; const float* bv;
  float* wTc; float* bcat;
};

__global__ __launch_bounds__(256) void wcast_all(WJobs jobs) {
  __shared__ float tile[32][33];
  const int t = blockIdx.x;
  const int tx = threadIdx.x, ty = threadIdx.y;  // 32 x 8
  if (t >= jobs.misc_t0) {
    const int idx = (t - jobs.misc_t0) * 256 + ty * 32 + tx;
    if (idx < DMODEL * KCONV) {
      const int d = idx / KCONV, k = idx % KCONV;
      jobs.wTc[k * DMODEL + d] = jobs.dww[idx];
    } else if (idx < DMODEL * KCONV + 3 * DMODEL) {
      const int c = idx - DMODEL * KCONV;
      jobs.bcat[c] = (c < DMODEL) ? jobs.bq[c]
                    : (c < 2 * DMODEL ? jobs.bk[c - DMODEL] : jobs.bv[c - 2 * DMODEL]);
    }
    return;
  }
  int i = 0;
#pragma unroll
  for (int k = 1; k < 10; ++k) if (t >= jobs.j[k].t0) i = k;
  const WJob jb = jobs.j[i];
  const int local = t - jb.t0;
  const int ntx = jb.N >> 5;
  const int bx = (local % ntx) * 32, by = (local / ntx) * 32;
#pragma unroll
  for (int r = 0; r < 32; r += 8)
    tile[ty + r][tx] = jb.src[(size_t)(by + ty + r) * jb.N + bx + tx];
  __syncthreads();
#pragma unroll
  for (int r = 0; r < 32; r += 8)
    jb.dst[(size_t)(bx + ty + r) * jb.K + by + tx] = f2bf(tile[tx][ty + r]);
}

// ---------------- LayerNorm: one wave per 512-wide row ----------------------
template <bool OBF>
__global__ __launch_bounds__(256) void ln_kernel(const float* __restrict__ in,
                                                 const float* __restrict__ g,
                                                 const float* __restrict__ b,
                                                 void* __restrict__ outp) {
  const int wave = threadIdx.x >> 6, lane = threadIdx.x & 63;
  const size_t row = (size_t)blockIdx.x * 4 + wave;
  const float* p = in + row * DMODEL + lane * 8;
  const float4 v0 = *(const float4*)p;
  const float4 v1 = *(const float4*)(p + 4);
  float s  = v0.x + v0.y + v0.z + v0.w + v1.x + v1.y + v1.z + v1.w;
  float ss = v0.x*v0.x + v0.y*v0.y + v0.z*v0.z + v0.w*v0.w
           + v1.x*v1.x + v1.y*v1.y + v1.z*v1.z + v1.w*v1.w;
#pragma unroll
  for (int m = 1; m < 64; m <<= 1) { s += __shfl_xor(s, m); ss += __shfl_xor(ss, m); }
  const float mean = s * (1.0f / DMODEL);
  const float var  = ss * (1.0f / DMODEL) - mean * mean;
  const float rstd = rsqrtf(var + LN_EPS);
  const float4 g0 = *(const float4*)(g + lane * 8);
  const float4 g1 = *(const float4*)(g + lane * 8 + 4);
  const float4 bb0 = *(const float4*)(b + lane * 8);
  const float4 bb1 = *(const float4*)(b + lane * 8 + 4);
  float o[8];
  o[0] = (v0.x - mean) * rstd * g0.x + bb0.x;
  o[1] = (v0.y - mean) * rstd * g0.y + bb0.y;
  o[2] = (v0.z - mean) * rstd * g0.z + bb0.z;
  o[3] = (v0.w - mean) * rstd * g0.w + bb0.w;
  o[4] = (v1.x - mean) * rstd * g1.x + bb1.x;
  o[5] = (v1.y - mean) * rstd * g1.y + bb1.y;
  o[6] = (v1.z - mean) * rstd * g1.z + bb1.z;
  o[7] = (v1.w - mean) * rstd * g1.w + bb1.w;
  if (OBF) {
    uint4 pkv;
    pkv.x = pk2(o[0], o[1]); pkv.y = pk2(o[2], o[3]);
    pkv.z = pk2(o[4], o[5]); pkv.w = pk2(o[6], o[7]);
    *(uint4*)((ushort_t*)outp + row * DMODEL + lane * 8) = pkv;
  } else {
    float4 a, c;
    a.x = o[0]; a.y = o[1]; a.z = o[2]; a.w = o[3];
    c.x = o[4]; c.y = o[5]; c.z = o[6]; c.w = o[7];
    float* q = (float*)outp + row * DMODEL + lane * 8;
    *(float4*)q = a;
    *(float4*)(q + 4) = c;
  }
}

// ---------------- fused double LayerNorm (norm3 then conv_ln), bf16 out -----
__global__ __launch_bounds__(256) void ln2_kernel(const float* __restrict__ in,
                                                  const float* __restrict__ g1,
                                                  const float* __restrict__ b1,
                                                  const float* __restrict__ g2,
                                                  const float* __restrict__ b2,
                                                  ushort_t* __restrict__ outp) {
  const int wave = threadIdx.x >> 6, lane = threadIdx.x & 63;
  const size_t row = (size_t)blockIdx.x * 4 + wave;
  const float* p = in + row * DMODEL + lane * 8;
  float v[8];
  {
    const float4 v0 = *(const float4*)p;
    const float4 v1 = *(const float4*)(p + 4);
    v[0]=v0.x; v[1]=v0.y; v[2]=v0.z; v[3]=v0.w;
    v[4]=v1.x; v[5]=v1.y; v[6]=v1.z; v[7]=v1.w;
  }
  float s = 0.f, ss = 0.f;
#pragma unroll
  for (int e = 0; e < 8; ++e) { s += v[e]; ss += v[e]*v[e]; }
#pragma unroll
  for (int m = 1; m < 64; m <<= 1) { s += __shfl_xor(s, m); ss += __shfl_xor(ss, m); }
  float mean = s * (1.0f / DMODEL);
  float rstd = rsqrtf(ss * (1.0f / DMODEL) - mean * mean + LN_EPS);
  const float4 ga = *(const float4*)(g1 + lane * 8);
  const float4 gb = *(const float4*)(g1 + lane * 8 + 4);
  const float4 ba = *(const float4*)(b1 + lane * 8);
  const float4 bb = *(const float4*)(b1 + lane * 8 + 4);
  const float gg1[8] = {ga.x,ga.y,ga.z,ga.w,gb.x,gb.y,gb.z,gb.w};
  const float bb1[8] = {ba.x,ba.y,ba.z,ba.w,bb.x,bb.y,bb.z,bb.w};
#pragma unroll
  for (int e = 0; e < 8; ++e) v[e] = (v[e] - mean) * rstd * gg1[e] + bb1[e];
  s = 0.f; ss = 0.f;
#pragma unroll
  for (int e = 0; e < 8; ++e) { s += v[e]; ss += v[e]*v[e]; }
#pragma unroll
  for (int m = 1; m < 64; m <<= 1) { s += __shfl_xor(s, m); ss += __shfl_xor(ss, m); }
  mean = s * (1.0f / DMODEL);
  rstd = rsqrtf(ss * (1.0f / DMODEL) - mean * mean + LN_EPS);
  const float4 gc = *(const float4*)(g2 + lane * 8);
  const float4 gd = *(const float4*)(g2 + lane * 8 + 4);
  const float4 bc = *(const float4*)(b2 + lane * 8);
  const float4 bd = *(const float4*)(b2 + lane * 8 + 4);
  const float gg2[8] = {gc.x,gc.y,gc.z,gc.w,gd.x,gd.y,gd.z,gd.w};
  const float bb2[8] = {bc.x,bc.y,bc.z,bc.w,bd.x,bd.y,bd.z,bd.w};
  float o[8];
#pragma unroll
  for (int e = 0; e < 8; ++e) o[e] = (v[e] - mean) * rstd * gg2[e] + bb2[e];
  uint4 pkv;
  pkv.x = pk2(o[0], o[1]); pkv.y = pk2(o[2], o[3]);
  pkv.z = pk2(o[4], o[5]); pkv.w = pk2(o[6], o[7]);
  *(uint4*)(outp + row * DMODEL + lane * 8) = pkv;
}

// ================= 8-phase 256x256 GEMM (T2+T3+T4+T5), K=512 ================
template <int ACT, bool QSC>
__global__ __launch_bounds__(512, 2) void gemm256(const ushort_t* __restrict__ A,
                                                  const ushort_t* __restrict__ Bt,
                                                  const float* __restrict__ bias,
                                                  ushort_t* __restrict__ Cout,
                                                  int N) {
  __shared__ ushort_t lds[65536];   // 128 KB
  const int t = threadIdx.x;
  const int l = t & 63;
  const int wid = t >> 6;
  const int wm = wid >> 2, wn = wid & 3;
  int bx = blockIdx.x, by = blockIdx.y;
  xcd_swizzle(gridDim.x, &bx, &by);
  const int m0 = by * 256, n0 = bx * 256;
  const int K = 512;

  f32x4 acc[8][4];
#pragma unroll
  for (int m = 0; m < 8; ++m)
#pragma unroll
    for (int n = 0; n < 4; ++n) acc[m][n] = (f32x4){0.f, 0.f, 0.f, 0.f};

  const int srow = t >> 3;
  const int schunk = (t & 7) ^ ((t >> 3) & 7);

#define STAGE_A(TAU, C_, I_)                                                    \
  __builtin_amdgcn_global_load_lds(                                             \
      (const AS1 unsigned*)(A + (size_t)(m0 + (I_) * 64 + srow) * K +           \
                            (TAU) * 64 + schunk * 8),                           \
      (AS3 unsigned*)(lds + (C_) * 16384 + ((I_) * 512 + t) * 8), 16, 0, 0)
#define STAGE_B(TAU, C_, I_)                                                    \
  __builtin_amdgcn_global_load_lds(                                             \
      (const AS1 unsigned*)(Bt + (size_t)(n0 + (I_) * 64 + srow) * K +          \
                            (TAU) * 64 + schunk * 8),                           \
      (AS3 unsigned*)(lds + 32768 + (C_) * 16384 + ((I_) * 512 + t) * 8), 16, 0, 0)

#pragma unroll
  for (int i = 0; i < 4; ++i) STAGE_B(0, 0, i);
#pragma unroll
  for (int i = 0; i < 4; ++i) STAGE_A(0, 0, i);
#pragma unroll
  for (int i = 0; i < 4; ++i) STAGE_B(1, 1, i);
  STAGE_A(1, 1, 0);
  STAGE_A(1, 1, 2);
  asm volatile("s_waitcnt vmcnt(6)" ::: "memory");
  __builtin_amdgcn_s_barrier();

  const int arow = (l & 15);
  const int kch0 = (l >> 4);
  bf16x8 bfr[2][4];

  for (int it = 0; it < 4; ++it) {
    const bool stg = (it < 3);
#pragma unroll
    for (int h = 0; h < 2; ++h) {
      const int c = h;
#pragma unroll
      for (int p = 0; p < 4; ++p) {
        bf16x8 afr[2][2];
#pragma unroll
        for (int m2 = 0; m2 < 2; ++m2)
#pragma unroll
          for (int ks = 0; ks < 2; ++ks) {
            const int row = wm * 128 + (2 * p + m2) * 16 + arow;
            const int ch = (ks * 4 + kch0) ^ (row & 7);
            afr[m2][ks] = *(const bf16x8*)(lds + c * 16384 + row * 64 + ch * 8);
          }
        if (p == 0) {
#pragma unroll
          for (int nr = 0; nr < 4; ++nr)
#pragma unroll
            for (int ks = 0; ks < 2; ++ks) {
              const int row = wn * 64 + nr * 16 + arow;
              const int ch = (ks * 4 + kch0) ^ (row & 7);
              bfr[ks][nr] = *(const bf16x8*)(lds + 32768 + c * 16384 + row * 64 + ch * 8);
            }
        }
        if (p == 0) {
          if (h == 0 || stg) {
            STAGE_A(2 * it + h + 1, c ^ 1, 1);
            STAGE_A(2 * it + h + 1, c ^ 1, 3);
          }
        } else if (p == 1) {
          if (stg) {
#pragma unroll
            for (int i = 0; i < 4; ++i) STAGE_B(2 * it + h + 2, c, i);
          }
        } else if (p == 2) {
          if (stg) {
            STAGE_A(2 * it + h + 2, c, 0);
            STAGE_A(2 * it + h + 2, c, 2);
          }
        }
        __builtin_amdgcn_s_barrier();
        __builtin_amdgcn_s_setprio(1);
#pragma unroll
        for (int ks = 0; ks < 2; ++ks)
#pragma unroll
          for (int m2 = 0; m2 < 2; ++m2)
#pragma unroll
            for (int nr = 0; nr < 4; ++nr)
              acc[2 * p + m2][nr] = __builtin_amdgcn_mfma_f32_16x16x32_bf16(
                  afr[m2][ks], bfr[ks][nr], acc[2 * p + m2][nr], 0, 0, 0);
        __builtin_amdgcn_s_setprio(0);
        if (p == 3) {
          if (h == 0) {
            if (stg) asm volatile("s_waitcnt vmcnt(6)" ::: "memory");
            else     asm volatile("s_waitcnt vmcnt(0)" ::: "memory");
          } else if (stg) {
            asm volatile("s_waitcnt vmcnt(6)" ::: "memory");
          }
        }
        __builtin_amdgcn_s_barrier();
      }
    }
  }
#undef STAGE_A
#undef STAGE_B

#pragma unroll
  for (int m = 0; m < 8; ++m) {
    const int row_b = m0 + wm * 128 + m * 16 + (l >> 4) * 4;
#pragma unroll
    for (int n = 0; n < 4; ++n) {
      const int col = n0 + wn * 64 + n * 16 + (l & 15);
      const float bv = bias[col];
      const float sc = QSC ? (col < DMODEL ? QSCALE : 1.0f) : 1.0f;
#pragma unroll
      for (int j = 0; j < 4; ++j) {
        float v = acc[m][n][j] + bv;
        if (ACT == 1) v = fmaxf(v, 0.f);
        v *= sc;
        Cout[(size_t)(row_b + j) * N + col] = f2bf(v);
      }
    }
  }
}

// ---------------- bf16 MFMA GEMM (m97 structure), TN = 128 or 64 ------------
template <int TN, int ACT, bool RES, bool OBF, bool QSC>
__global__ __launch_bounds__(256) void gemm_bf16(const ushort_t* __restrict__ A,
                                                 const ushort_t* __restrict__ Bt,
                                                 const float* __restrict__ bias,
                                                 const float* __restrict__ Rp,
                                                 float alpha,
                                                 void* __restrict__ Cout,
                                                 int M, int N, int K) {
  constexpr int NF = TN / 32;
  constexpr int NB = TN / 32;
  __shared__ ushort_t Al[128 * 64];
  __shared__ ushort_t Bl[TN * 64];
  const int t = threadIdx.x;
  const int lane = t & 63;
  const int wid = t >> 6;
  const int wr = wid >> 1, wc = wid & 1;
  int bx = blockIdx.x, by = blockIdx.y;
  xcd_swizzle(gridDim.x, &bx, &by);
  const int m0 = by * 128, n0 = bx * TN;

  f32x4 acc[4][NF];
#pragma unroll
  for (int m = 0; m < 4; ++m)
#pragma unroll
    for (int n = 0; n < NF; ++n) acc[m][n] = (f32x4){0.f, 0.f, 0.f, 0.f};

  const int srow = t >> 3;
  const int scol = (t & 7) * 8;
  const ushort_t* Ag = A + (size_t)(m0 + srow) * K + scol;
  const ushort_t* Bg = Bt + (size_t)(n0 + srow) * K + scol;

  for (int k0 = 0; k0 < K; k0 += 64) {
    __syncthreads();
#pragma unroll
    for (int i = 0; i < 4; ++i) {
      __builtin_amdgcn_global_load_lds(
          (const AS1 unsigned*)(Ag + (size_t)i * 32 * K + k0),
          (AS3 unsigned*)(Al + ((size_t)i * 256 + t) * 8),
          16, 0, 0);
    }
#pragma unroll
    for (int i = 0; i < NB; ++i) {
      __builtin_amdgcn_global_load_lds(
          (const AS1 unsigned*)(Bg + (size_t)i * 32 * K + k0),
          (AS3 unsigned*)(Bl + ((size_t)i * 256 + t) * 8),
          16, 0, 0);
    }
    __syncthreads();

#pragma unroll
    for (int ks = 0; ks < 2; ++ks) {
      const int kk = ks * 32 + (lane >> 4) * 8;
      bf16x8 af[4], bfv[NF];
#pragma unroll
      for (int m = 0; m < 4; ++m)
        af[m] = *(const bf16x8*)(Al + (wr * 64 + m * 16 + (lane & 15)) * 64 + kk);
#pragma unroll
      for (int n = 0; n < NF; ++n)
        bfv[n] = *(const bf16x8*)(Bl + (wc * (TN / 2) + n * 16 + (lane & 15)) * 64 + kk);
#pragma unroll
      for (int m = 0; m < 4; ++m)
#pragma unroll
        for (int n = 0; n < NF; ++n)
          acc[m][n] = __builtin_amdgcn_mfma_f32_16x16x32_bf16(af[m], bfv[n], acc[m][n], 0, 0, 0);
    }
  }

#pragma unroll
  for (int m = 0; m < 4; ++m) {
    const int row_b = m0 + wr * 64 + m * 16 + (lane >> 4) * 4;
#pragma unroll
    for (int n = 0; n < NF; ++n) {
      const int col = n0 + wc * (TN / 2) + n * 16 + (lane & 15);
      const float bv = bias[col];
#pragma unroll
      for (int j = 0; j < 4; ++j) {
        float v = acc[m][n][j] + bv;
        if (ACT == 1) v = fmaxf(v, 0.f);
        if (QSC) v *= (col < DMODEL ? QSCALE : 1.0f);
        const size_t idx = (size_t)(row_b + j) * N + col;
        if (RES) v = Rp[idx] + alpha * v;
        if (OBF) ((ushort_t*)Cout)[idx] = f2bf(v);
        else     ((float*)Cout)[idx] = v;
      }
    }
  }
}

// ---------------- fused pw1 + GLU GEMM --------------------------------------
__global__ __launch_bounds__(256) void gemm_glu(const ushort_t* __restrict__ A,
                                                const ushort_t* __restrict__ Bt,
                                                const float* __restrict__ bias,
                                                ushort_t* __restrict__ Cout) {
  __shared__ ushort_t Al[128 * 64];
  __shared__ ushort_t Bl[128 * 64];
  const int t = threadIdx.x;
  const int lane = t & 63;
  const int wid = t >> 6;
  const int wr = wid >> 1, wc = wid & 1;
  int bx = blockIdx.x, by = blockIdx.y;
  xcd_swizzle(gridDim.x, &bx, &by);
  const int m0 = by * 128, n0 = bx * 64;
  const int K = DMODEL, N = DMODEL;

  f32x4 aa[4][2], ag[4][2];
#pragma unroll
  for (int m = 0; m < 4; ++m)
#pragma unroll
    for (int n = 0; n < 2; ++n) {
      aa[m][n] = (f32x4){0.f, 0.f, 0.f, 0.f};
      ag[m][n] = (f32x4){0.f, 0.f, 0.f, 0.f};
    }

  const int srow = t >> 3;
  const int scol = (t & 7) * 8;
  const ushort_t* Ag_ = A + (size_t)(m0 + srow) * K + scol;
  const ushort_t* Ba_ = Bt + (size_t)(n0 + srow) * K + scol;
  const ushort_t* Bg_ = Bt + (size_t)(512 + n0 + srow) * K + scol;

  for (int k0 = 0; k0 < K; k0 += 64) {
    __syncthreads();
#pragma unroll
    for (int i = 0; i < 4; ++i) {
      __builtin_amdgcn_global_load_lds(
          (const AS1 unsigned*)(Ag_ + (size_t)i * 32 * K + k0),
          (AS3 unsigned*)(Al + ((size_t)i * 256 + t) * 8),
          16, 0, 0);
    }
#pragma unroll
    for (int i = 0; i < 2; ++i) {
      __builtin_amdgcn_global_load_lds(
          (const AS1 unsigned*)(Ba_ + (size_t)i * 32 * K + k0),
          (AS3 unsigned*)(Bl + ((size_t)i * 256 + t) * 8),
          16, 0, 0);
      __builtin_amdgcn_global_load_lds(
          (const AS1 unsigned*)(Bg_ + (size_t)i * 32 * K + k0),
          (AS3 unsigned*)(Bl + 64 * 64 + ((size_t)i * 256 + t) * 8),
          16, 0, 0);
    }
    __syncthreads();

#pragma unroll
    for (int ks = 0; ks < 2; ++ks) {
      const int kk = ks * 32 + (lane >> 4) * 8;
      bf16x8 af[4], bfa[2], bfg[2];
#pragma unroll
      for (int m = 0; m < 4; ++m)
        af[m] = *(const bf16x8*)(Al + (wr * 64 + m * 16 + (lane & 15)) * 64 + kk);
#pragma unroll
      for (int n = 0; n < 2; ++n) {
        bfa[n] = *(const bf16x8*)(Bl + (wc * 32 + n * 16 + (lane & 15)) * 64 + kk);
        bfg[n] = *(const bf16x8*)(Bl + (64 + wc * 32 + n * 16 + (lane & 15)) * 64 + kk);
      }
#pragma unroll
      for (int m = 0; m < 4; ++m)
#pragma unroll
        for (int n = 0; n < 2; ++n) {
          aa[m][n] = __builtin_amdgcn_mfma_f32_16x16x32_bf16(af[m], bfa[n], aa[m][n], 0, 0, 0);
          ag[m][n] = __builtin_amdgcn_mfma_f32_16x16x32_bf16(af[m], bfg[n], ag[m][n], 0, 0, 0);
        }
    }
  }

#pragma unroll
  for (int m = 0; m < 4; ++m) {
    const int row_b = m0 + wr * 64 + m * 16 + (lane >> 4) * 4;
#pragma unroll
    for (int n = 0; n < 2; ++n) {
      const int col = n0 + wc * 32 + n * 16 + (lane & 15);
      const float ba_v = bias[col];
      const float bg_v = bias[col + DMODEL];
#pragma unroll
      for (int j = 0; j < 4; ++j) {
        const float av = aa[m][n][j] + ba_v;
        const float gv = ag[m][n][j] + bg_v;
        Cout[(size_t)(row_b + j) * N + col] = f2bf(av * sigf(gv));
      }
    }
  }
}

// ---------------- V transpose per head: QKV[b][s][1024+h*64+d] -> [bh][d][s] -
__global__ __launch_bounds__(256) void vtrans(const ushort_t* __restrict__ QKV,
                                              ushort_t* __restrict__ Vt) {
  __shared__ ushort_t tl[64][72];
  const int st = blockIdx.x;
  const int bh = blockIdx.y;
  const int b = bh >> 3, h = bh & 7;
  const int t = threadIdx.x;
#pragma unroll
  for (int i = 0; i < 2; ++i) {
    const int chunk = i * 256 + t;
    const int sr = chunk >> 3, c8 = (chunk & 7) * 8;
    *(uint4*)&tl[sr][c8] =
        *(const uint4*)(QKV + ((size_t)(b * SEQ + st * 64 + sr) * (3 * DMODEL)) + 2 * DMODEL + h * DKH + c8);
  }
  __syncthreads();
#pragma unroll
  for (int i = 0; i < 2; ++i) {
    const int chunk = i * 256 + t;
    const int dr = chunk >> 3, c8 = (chunk & 7) * 8;
    ushort_t tmp[8];
#pragma unroll
    for (int e = 0; e < 8; ++e) tmp[e] = tl[c8 + e][dr];
    *(uint4*)(Vt + ((size_t)(bh * DKH + dr) * SEQ) + st * 64 + c8) = *(uint4*)tmp;
  }
}

// ---------------- MFMA flash attention, QBLK=64, KVBLK=128, 4 waves ---------
// 2-phase pipelined staging + T13 defer-max (rescale only when tile max grows
// by > 8 in base-2 domain; P bounded by 2^8, f32 accumulators absorb it).
__global__ __launch_bounds__(256) void attn_mfma(const ushort_t* __restrict__ QKV,
                                                 const ushort_t* __restrict__ Vt,
                                                 ushort_t* __restrict__ Om) {
  __shared__ ushort_t Ks[2][128 * 64];
  __shared__ ushort_t Vs[2][64 * 128];
  __shared__ ushort_t Ps[64 * 128];
  const int t = threadIdx.x;
  const int l = t & 63;
  const int w = t >> 6;
  const int qb = blockIdx.x, h = blockIdx.y, b = blockIdx.z;
  const size_t rowstr = 3 * DMODEL;
  const size_t baseQ = ((size_t)b * SEQ) * rowstr + (size_t)h * DKH;
  const size_t baseK = baseQ + DMODEL;
  const size_t baseV = (size_t)(b * NH + h) * DKH * SEQ;
  const size_t baseO = ((size_t)b * SEQ) * DMODEL + (size_t)h * DKH;

  bf16x8 qf[2];
  {
    const int qrow = qb * 64 + w * 16 + (l & 15);
    const ushort_t* qp = QKV + baseQ + (size_t)qrow * rowstr + ((l >> 4) * 8);
    qf[0] = *(const bf16x8*)(qp);
    qf[1] = *(const bf16x8*)(qp + 32);
  }

  const int krr = t >> 3, kch = t & 7;
  const int vrr = t >> 4, vch = t & 15;

#define STAGE_KV(KT, BUF)                                                       \
  {                                                                             \
    _Pragma("unroll")                                                           \
    for (int i = 0; i < 4; ++i) {                                               \
      const int r = i * 32 + krr;                                               \
      __builtin_amdgcn_global_load_lds(                                         \
          (const AS1 unsigned*)(QKV + baseK +                                   \
              (size_t)((KT) * 128 + r) * rowstr + ((kch ^ (r & 7)) * 8)),       \
          (AS3 unsigned*)(Ks[BUF] + ((size_t)i * 256 + t) * 8), 16, 0, 0);      \
    }                                                                           \
    _Pragma("unroll")                                                           \
    for (int i = 0; i < 4; ++i) {                                               \
      const int r = i * 16 + vrr;                                               \
      __builtin_amdgcn_global_load_lds(                                         \
          (const AS1 unsigned*)(Vt + baseV +                                    \
              (size_t)r * SEQ + (KT) * 128 + ((vch ^ (r & 15)) * 8)),           \
          (AS3 unsigned*)(Vs[BUF] + ((size_t)i * 256 + t) * 8), 16, 0, 0);      \
    }                                                                           \
  }

  float mrun[4], lrun[4];
  f32x4 o[4];
#pragma unroll
  for (int j = 0; j < 4; ++j) { mrun[j] = -1e30f; lrun[j] = 0.f; }
#pragma unroll
  for (int n = 0; n < 4; ++n) o[n] = (f32x4){0.f, 0.f, 0.f, 0.f};

  STAGE_KV(0, 0);
  __syncthreads();

  int cur = 0;
  for (int kt = 0; kt < SEQ / 128; ++kt) {
    if (kt + 1 < SEQ / 128) STAGE_KV(kt + 1, cur ^ 1);

    const ushort_t* Kc = Ks[cur];
    const ushort_t* Vc = Vs[cur];

    f32x4 s[8];
#pragma unroll
    for (int n = 0; n < 8; ++n) s[n] = (f32x4){0.f, 0.f, 0.f, 0.f};
    __builtin_amdgcn_s_setprio(1);
#pragma unroll
    for (int ks = 0; ks < 2; ++ks) {
      const int kk = ks * 64 + (l >> 4) * 16;
#pragma unroll
      for (int n = 0; n < 8; ++n) {
        const int krow = n * 16 + (l & 15);
        const bf16x8 kf = *(const bf16x8*)((const char*)Kc + krow * 128 + (kk ^ ((krow & 7) << 4)));
        s[n] = __builtin_amdgcn_mfma_f32_16x16x32_bf16(qf[ks], kf, s[n], 0, 0, 0);
      }
    }
    __builtin_amdgcn_s_setprio(0);

#pragma unroll
    for (int j = 0; j < 4; ++j) {
      float r0 = fmaxf(fmaxf(fmaxf(s[0][j], s[1][j]), fmaxf(s[2][j], s[3][j])),
                       fmaxf(fmaxf(s[4][j], s[5][j]), fmaxf(s[6][j], s[7][j])));
      r0 = fmaxf(r0, __shfl_xor(r0, 1));
      r0 = fmaxf(r0, __shfl_xor(r0, 2));
      r0 = fmaxf(r0, __shfl_xor(r0, 4));
      r0 = fmaxf(r0, __shfl_xor(r0, 8));
      // T13 defer-max: only rescale when tile max exceeds old max by > 8
      if (r0 > mrun[j] + 8.0f) {
        const float cs = exp2n(mrun[j] - r0);
        lrun[j] *= cs;
        o[0][j] *= cs; o[1][j] *= cs; o[2][j] *= cs; o[3][j] *= cs;
        mrun[j] = r0;
      }
      const float mn = mrun[j];
      const int prow = w * 16 + (l >> 4) * 4 + j;
      const int pswz = (prow & 15) << 4;
      float psum = 0.f;
#pragma unroll
      for (int n = 0; n < 8; ++n) {
        const float p = exp2n(s[n][j] - mn);
        psum += p;
        const int col2 = (n * 16 + (l & 15)) * 2;
        *(ushort_t*)((char*)Ps + prow * 256 + (col2 ^ pswz)) = f2bf(p);
      }
      psum += __shfl_xor(psum, 1);
      psum += __shfl_xor(psum, 2);
      psum += __shfl_xor(psum, 4);
      psum += __shfl_xor(psum, 8);
      lrun[j] += psum;
    }

    __builtin_amdgcn_s_setprio(1);
#pragma unroll
    for (int ks = 0; ks < 4; ++ks) {
      const int kk = ks * 64 + (l >> 4) * 16;
      const int arow = w * 16 + (l & 15);
      const bf16x8 pf = *(const bf16x8*)((char*)Ps + arow * 256 + (kk ^ ((arow & 15) << 4)));
#pragma unroll
      for (int n = 0; n < 4; ++n) {
        const int vrow = n * 16 + (l & 15);
        const bf16x8 vf = *(const bf16x8*)((const char*)Vc + vrow * 256 + (kk ^ ((vrow & 15) << 4)));
        o[n] = __builtin_amdgcn_mfma_f32_16x16x32_bf16(pf, vf, o[n], 0, 0, 0);
      }
    }
    __builtin_amdgcn_s_setprio(0);

    __syncthreads();
    cur ^= 1;
  }
#undef STAGE_KV

  float inv[4];
#pragma unroll
  for (int j = 0; j < 4; ++j) inv[j] = 1.0f / lrun[j];
#pragma unroll
  for (int j = 0; j < 4; ++j) {
    const int prow = w * 16 + (l >> 4) * 4 + j;
    const int pswz = (prow & 15) << 4;
#pragma unroll
    for (int n = 0; n < 4; ++n) {
      const int col2 = (n * 16 + (l & 15)) * 2;
      *(ushort_t*)((char*)Ps + prow * 256 + (col2 ^ pswz)) = f2bf(o[n][j] * inv[j]);
    }
  }
  __syncthreads();
#pragma unroll
  for (int i = 0; i < 2; ++i) {
    const int chunk = i * 256 + t;
    const int qr = chunk >> 3, c8 = (chunk & 7) * 8;
    const uint4 ov = *(const uint4*)((char*)Ps + qr * 256 + ((c8 * 2) ^ ((qr & 15) << 4)));
    *(uint4*)(Om + baseO + (size_t)(qb * 64 + qr) * DMODEL + c8) = ov;
  }
}

// -------- depthwise conv + bias + BN + SiLU, LDS-tiled (31x reuse) ----------
// Block: 64 seq x 128 ch tile; halo window (94 rows) staged once in LDS.
__global__ __launch_bounds__(256) void dwconv_bn_silu(const ushort_t* __restrict__ in,
                                                      const float* __restrict__ wT,
                                                      const float* __restrict__ dwb,
                                                      const float* __restrict__ bng,
                                                      const float* __restrict__ bnb,
                                                      const float* __restrict__ bnm,
                                                      const float* __restrict__ bnv,
                                                      ushort_t* __restrict__ out) {
  __shared__ ushort_t xs[94 * 128];   // 23.5 KB
  const int t = threadIdx.x;
  const int s0 = blockIdx.x * 64;
  const int c0 = blockIdx.y * 128;
  const int b  = blockIdx.z;
  const ushort_t* bp = in + (size_t)b * SEQ * DMODEL;

  // stage halo window [s0-15 .. s0+78] x 128 ch (zero-padded at seq edges)
#pragma unroll
  for (int i = 0; i < 6; ++i) {
    const int cid = i * 256 + t;
    if (cid < 94 * 16) {
      const int r = cid >> 4, ch = cid & 15;
      const int gs = s0 + r - 15;
      uint4 v = make_uint4(0, 0, 0, 0);
      if (gs >= 0 && gs < SEQ)
        v = *(const uint4*)(bp + (size_t)gs * DMODEL + c0 + ch * 8);
      *(uint4*)(xs + r * 128 + ch * 8) = v;
    }
  }
  __syncthreads();

  const int g = t >> 4;          // seq group: rows g*4 .. g*4+3
  const int ch8 = t & 15;        // 8-channel chunk
  const int dc = c0 + ch8 * 8;

  float a[4][8];
#pragma unroll
  for (int j = 0; j < 4; ++j)
#pragma unroll
    for (int e = 0; e < 8; ++e) a[j][e] = 0.f;

  for (int k = 0; k < KCONV; ++k) {
    const float4 w0 = *(const float4*)(wT + k * DMODEL + dc);
    const float4 w1 = *(const float4*)(wT + k * DMODEL + dc + 4);
    const float wv[8] = {w0.x, w0.y, w0.z, w0.w, w1.x, w1.y, w1.z, w1.w};
#pragma unroll
    for (int j = 0; j < 4; ++j) {
      ushort_t xv[8];
      *(uint4*)xv = *(const uint4*)(xs + (g * 4 + j + k) * 128 + ch8 * 8);
#pragma unroll
      for (int e = 0; e < 8; ++e) a[j][e] = fmaf(bf2f(xv[e]), wv[e], a[j][e]);
    }
  }

  // bias + BN + SiLU epilogue (8-wide params loaded once)
  const float4 bi0 = *(const float4*)(dwb + dc);
  const float4 bi1 = *(const float4*)(dwb + dc + 4);
  const float4 mm0 = *(const float4*)(bnm + dc);
  const float4 mm1 = *(const float4*)(bnm + dc + 4);
  const float4 vv0 = *(const float4*)(bnv + dc);
  const float4 vv1 = *(const float4*)(bnv + dc + 4);
  const float4 gg0 = *(const float4*)(bng + dc);
  const float4 gg1 = *(const float4*)(bng + dc + 4);
  const float4 b20 = *(const float4*)(bnb + dc);
  const float4 b21 = *(const float4*)(bnb + dc + 4);
  const float bia[8] = {bi0.x,bi0.y,bi0.z,bi0.w,bi1.x,bi1.y,bi1.z,bi1.w};
  const float mma[8] = {mm0.x,mm0.y,mm0.z,mm0.w,mm1.x,mm1.y,mm1.z,mm1.w};
  const float vva[8] = {vv0.x,vv0.y,vv0.z,vv0.w,vv1.x,vv1.y,vv1.z,vv1.w};
  const float gga[8] = {gg0.x,gg0.y,gg0.z,gg0.w,gg1.x,gg1.y,gg1.z,gg1.w};
  const float b2a[8] = {b20.x,b20.y,b20.z,b20.w,b21.x,b21.y,b21.z,b21.w};
  float rsd[8];
#pragma unroll
  for (int e = 0; e < 8; ++e) rsd[e] = rsqrtf(vva[e] + LN_EPS) * gga[e];

#pragma unroll
  for (int j = 0; j < 4; ++j) {
    float v[8];
#pragma unroll
    for (int e = 0; e < 8; ++e) {
      float t0 = a[j][e] + bia[e];
      t0 = (t0 - mma[e]) * rsd[e] + b2a[e];
      v[e] = t0 * sigf(t0);
    }
    uint4 ov;
    ov.x = pk2(v[0], v[1]); ov.y = pk2(v[2], v[3]);
    ov.z = pk2(v[4], v[5]); ov.w = pk2(v[6], v[7]);
    *(uint4*)&out[(((size_t)b * SEQ + s0 + g * 4 + j) * DMODEL) + dc] = ov;
  }
}

extern "C" void kernel_launch(void* const* d_in, const int* in_sizes, int n_in,
                              void* d_out, int out_size, void* d_ws, size_t ws_size,
                              hipStream_t stream) {
  const float* x    = (const float*)d_in[0];
  const float* n1g  = (const float*)d_in[1];
  const float* n1b  = (const float*)d_in[2];
  const float* n2g  = (const float*)d_in[3];
  const float* n2b  = (const float*)d_in[4];
  const float* n3g  = (const float*)d_in[5];
  const float* n3b  = (const float*)d_in[6];
  const float* n4g  = (const float*)d_in[7];
  const float* n4b  = (const float*)d_in[8];
  const float* clg  = (const float*)d_in[9];
  const float* clb  = (const float*)d_in[10];
  const float* f1w1 = (const float*)d_in[11];
  const float* f1b1 = (const float*)d_in[12];
  const float* f1w2 = (const float*)d_in[13];
  const float* f1b2 = (const float*)d_in[14];
  const float* f2w1 = (const float*)d_in[15];
  const float* f2b1 = (const float*)d_in[16];
  const float* f2w2 = (const float*)d_in[17];
  const float* f2b2 = (const float*)d_in[18];
  const float* wq   = (const float*)d_in[19];
  const float* bq   = (const float*)d_in[20];
  const float* wk   = (const float*)d_in[21];
  const float* bk   = (const float*)d_in[22];
  const float* wv   = (const float*)d_in[23];
  const float* bv   = (const float*)d_in[24];
  const float* wo   = (const float*)d_in[25];
  const float* bo   = (const float*)d_in[26];
  const float* pw1w = (const float*)d_in[27];
  const float* pw1b = (const float*)d_in[28];
  const float* dww  = (const float*)d_in[29];
  const float* dwb  = (const float*)d_in[30];
  const float* bng  = (const float*)d_in[31];
  const float* bnb  = (const float*)d_in[32];
  const float* bnm  = (const float*)d_in[33];
  const float* bnv  = (const float*)d_in[34];
  const float* pw2w = (const float*)d_in[35];
  const float* pw2b = (const float*)d_in[36];

  char* wsb = (char*)d_ws;
  const size_t MB = 1ull << 20;
  ushort_t* Wbf    = (ushort_t*)(wsb + 0);
  ushort_t* f1w1T  = Wbf + 0;
  ushort_t* f1w2T  = Wbf + (1ull << 20);
  ushort_t* f2w1T  = Wbf + (2ull << 20);
  ushort_t* f2w2T  = Wbf + (3ull << 20);
  ushort_t* wqkvT  = Wbf + (4ull << 20);
  ushort_t* wkT    = wqkvT + (256ull << 10);
  ushort_t* wvT    = wqkvT + (512ull << 10);
  ushort_t* woT    = wqkvT + (768ull << 10);
  ushort_t* pw1T   = Wbf + (5ull << 20);
  ushort_t* pw2T   = Wbf + (5ull << 20) + (512ull << 10);
  float*    WTc    = (float*)(wsb + 12 * MB);
  float*    bcat   = (float*)(wsb + 12 * MB + 128 * 1024);
  ushort_t* Lbf    = (ushort_t*)(wsb + 13 * MB);
  ushort_t* Hbf    = (ushort_t*)(wsb + 21 * MB);
  ushort_t* QKVb   = (ushort_t*)(wsb + 53 * MB);
  ushort_t* Vtb    = (ushort_t*)(wsb + 77 * MB);
  ushort_t* Gbf    = (ushort_t*)(wsb + 53 * MB);
  ushort_t* Obf    = (ushort_t*)(wsb + 85 * MB);
  ushort_t* Cbf    = Obf;
  float* out = (float*)d_out;

  const dim3 blk(256);
  const dim3 blk512(512);
  const dim3 blkT(32, 8);
  const dim3 gLN(TOK / 4);
  const dim3 gFFa256(FDIM / 256, TOK / 256);       // 256 blocks
  const dim3 gQKV256(3 * DMODEL / 256, TOK / 256); // 192 blocks
  const dim3 gFFb(DMODEL / 64, TOK / 128);         // 512 blocks
  const dim3 gGLU(DMODEL / 64, TOK / 128);         // 512 blocks
  const dim3 gAttn(SEQ / 64, NH, BATCH);           // 1024 blocks
  const dim3 gVt(SEQ / 64, BATCH * NH);
  const dim3 gConv(SEQ / 64, DMODEL / 128, BATCH); // 512 blocks

  // ---- weight preprocessing (single dispatch) ----
  {
    WJobs jobs;
    const float* srcs[10] = {f1w1, f1w2, f2w1, f2w2, wq, wk, wv, wo, pw1w, pw2w};
    ushort_t* dsts[10] = {f1w1T, f1w2T, f2w1T, f2w2T, wqkvT, wkT, wvT, woT, pw1T, pw2T};
    const int Ks[10] = {512, 2048, 512, 2048, 512, 512, 512, 512, 512, 512};
    const int Ns[10] = {2048, 512, 2048, 512, 512, 512, 512, 512, 1024, 512};
    int t0 = 0;
    for (int i = 0; i < 10; ++i) {
      jobs.j[i].src = srcs[i]; jobs.j[i].dst = dsts[i];
      jobs.j[i].K = Ks[i]; jobs.j[i].N = Ns[i]; jobs.j[i].t0 = t0;
      t0 += (Ks[i] / 32) * (Ns[i] / 32);
    }
    jobs.misc_t0 = t0;
    jobs.dww = dww; jobs.bq = bq; jobs.bk = bk; jobs.bv = bv;
    jobs.wTc = WTc; jobs.bcat = bcat;
    const int nmisc = (DMODEL * KCONV + 3 * DMODEL + 255) / 256;
    wcast_all<<<t0 + nmisc, blkT, 0, stream>>>(jobs);
  }

  // ---- FF1 half-step ----
  ln_kernel<true><<<gLN, blk, 0, stream>>>(x, n1g, n1b, Lbf);
  gemm256<1, false><<<gFFa256, blk512, 0, stream>>>(Lbf, f1w1T, f1b1, Hbf, FDIM);
  gemm_bf16<64,  0, true,  false, false><<<gFFb, blk, 0, stream>>>(Hbf, f1w2T, f1b2, x, 0.5f, out, TOK, DMODEL, FDIM);

  // ---- MHSA ----
  ln_kernel<true><<<gLN, blk, 0, stream>>>(out, n2g, n2b, Lbf);
  gemm256<0, true><<<gQKV256, blk512, 0, stream>>>(Lbf, wqkvT, bcat, QKVb, 3 * DMODEL);
  vtrans<<<gVt, blk, 0, stream>>>(QKVb, Vtb);
  attn_mfma<<<gAttn, blk, 0, stream>>>(QKVb, Vtb, Obf);
  gemm_bf16<64,  0, true,  false, false><<<gFFb, blk, 0, stream>>>(Obf, woT, bo, out, 1.0f, out, TOK, DMODEL, DMODEL);

  // ---- conv module ----
  ln2_kernel<<<gLN, blk, 0, stream>>>(out, n3g, n3b, clg, clb, Lbf);
  gemm_glu<<<gGLU, blk, 0, stream>>>(Lbf, pw1T, pw1b, Gbf);
  dwconv_bn_silu<<<gConv, blk, 0, stream>>>(Gbf, WTc, dwb, bng, bnb, bnm, bnv, Cbf);
  gemm_bf16<64,  0, true,  false, false><<<gFFb, blk, 0, stream>>>(Cbf, pw2T, pw2b, out, 1.0f, out, TOK, DMODEL, DMODEL);

  // ---- FF2 half-step ----
  ln_kernel<true><<<gLN, blk, 0, stream>>>(out, n4g, n4b, Lbf);
  gemm256<1, false><<<gFFa256, blk512, 0, stream>>>(Lbf, f2w1T, f2b1, Hbf, FDIM);
  gemm_bf16<64,  0, true,  false, false><<<gFFb, blk, 0, stream>>>(Hbf, f2w2T, f2b2, out, 0.5f, out, TOK, DMODEL, FDIM);
}

// Round 13
// 291.652 us; speedup vs baseline: 1.3763x; 1.0157x over previous
//
#include <hip/hip_runtime.h>
#include <math.h>

#define TOK    8192
#define DMODEL 512
#define FDIM   2048
#define NH     8
#define DKH    64
#define SEQ    1024
#define BATCH  8
#define KCONV  31
#define LN_EPS 1e-5f

typedef __attribute__((ext_vector_type(8))) short bf16x8;
typedef __attribute__((ext_vector_type(4))) float f32x4;
typedef unsigned short ushort_t;

#define AS1 __attribute__((address_space(1)))
#define AS3 __attribute__((address_space(3)))

// 0.125 (1/sqrt(64)) * log2(e): QK scores land in base-2 domain
#define QSCALE 0.1803368801111204f

__device__ __forceinline__ float sigf(float x) { return 1.0f / (1.0f + __expf(-x)); }
__device__ __forceinline__ float exp2n(float x) { return __builtin_amdgcn_exp2f(x); }

__device__ __forceinline__ unsigned short f2bf(float f) {
  unsigned u = __float_as_uint(f);
  u = u + 0x7fffu + ((u >> 16) & 1u);   // RNE
  return (unsigned short)(u >> 16);
}
__device__ __forceinline__ unsigned pk2(float a, float b) {
  return (unsigned)f2bf(a) | ((unsigned)f2bf(b) << 16);
}
__device__ __forceinline__ float bf2f(ushort_t u) {
  return __uint_as_float((unsigned)u << 16);
}

// XCD-aware bijective block swizzle (grids here are multiples of 8).
__device__ __forceinline__ void xcd_swizzle(int gx, int* bx, int* by) {
  const int nwg = gx * (int)gridDim.y;
  const int cpx = nwg >> 3;
  const int bid = (*by) * gx + (*bx);
  const int wg = (bid & 7) * cpx + (bid >> 3);
  *bx = wg % gx;
  *by = wg / gx;
}

// ---------------- all weight prep in ONE dispatch ---------------------------
struct WJob { const float* src; ushort_t* dst; int K, N, t0; };
struct WJobs {
  WJob j[10];
  int misc_t0;
  const float* dww; const float* bq; const float* bk; const float* bv;
  float* wTc; float* bcat;
};

__global__ __launch_bounds__(256) void wcast_all(WJobs jobs) {
  __shared__ float tile[32][33];
  const int t = blockIdx.x;
  const int tx = threadIdx.x, ty = threadIdx.y;  // 32 x 8
  if (t >= jobs.misc_t0) {
    const int idx = (t - jobs.misc_t0) * 256 + ty * 32 + tx;
    if (idx < DMODEL * KCONV) {
      const int d = idx / KCONV, k = idx % KCONV;
      jobs.wTc[k * DMODEL + d] = jobs.dww[idx];
    } else if (idx < DMODEL * KCONV + 3 * DMODEL) {
      const int c = idx - DMODEL * KCONV;
      jobs.bcat[c] = (c < DMODEL) ? jobs.bq[c]
                    : (c < 2 * DMODEL ? jobs.bk[c - DMODEL] : jobs.bv[c - 2 * DMODEL]);
    }
    return;
  }
  int i = 0;
#pragma unroll
  for (int k = 1; k < 10; ++k) if (t >= jobs.j[k].t0) i = k;
  const WJob jb = jobs.j[i];
  const int local = t - jb.t0;
  const int ntx = jb.N >> 5;
  const int bx = (local % ntx) * 32, by = (local / ntx) * 32;
#pragma unroll
  for (int r = 0; r < 32; r += 8)
    tile[ty + r][tx] = jb.src[(size_t)(by + ty + r) * jb.N + bx + tx];
  __syncthreads();
#pragma unroll
  for (int r = 0; r < 32; r += 8)
    jb.dst[(size_t)(bx + ty + r) * jb.K + by + tx] = f2bf(tile[tx][ty + r]);
}

// ---------------- LayerNorm: one wave per 512-wide row ----------------------
template <bool OBF>
__global__ __launch_bounds__(256) void ln_kernel(const float* __restrict__ in,
                                                 const float* __restrict__ g,
                                                 const float* __restrict__ b,
                                                 void* __restrict__ outp) {
  const int wave = threadIdx.x >> 6, lane = threadIdx.x & 63;
  const size_t row = (size_t)blockIdx.x * 4 + wave;
  const float* p = in + row * DMODEL + lane * 8;
  const float4 v0 = *(const float4*)p;
  const float4 v1 = *(const float4*)(p + 4);
  float s  = v0.x + v0.y + v0.z + v0.w + v1.x + v1.y + v1.z + v1.w;
  float ss = v0.x*v0.x + v0.y*v0.y + v0.z*v0.z + v0.w*v0.w
           + v1.x*v1.x + v1.y*v1.y + v1.z*v1.z + v1.w*v1.w;
#pragma unroll
  for (int m = 1; m < 64; m <<= 1) { s += __shfl_xor(s, m); ss += __shfl_xor(ss, m); }
  const float mean = s * (1.0f / DMODEL);
  const float var  = ss * (1.0f / DMODEL) - mean * mean;
  const float rstd = rsqrtf(var + LN_EPS);
  const float4 g0 = *(const float4*)(g + lane * 8);
  const float4 g1 = *(const float4*)(g + lane * 8 + 4);
  const float4 bb0 = *(const float4*)(b + lane * 8);
  const float4 bb1 = *(const float4*)(b + lane * 8 + 4);
  float o[8];
  o[0] = (v0.x - mean) * rstd * g0.x + bb0.x;
  o[1] = (v0.y - mean) * rstd * g0.y + bb0.y;
  o[2] = (v0.z - mean) * rstd * g0.z + bb0.z;
  o[3] = (v0.w - mean) * rstd * g0.w + bb0.w;
  o[4] = (v1.x - mean) * rstd * g1.x + bb1.x;
  o[5] = (v1.y - mean) * rstd * g1.y + bb1.y;
  o[6] = (v1.z - mean) * rstd * g1.z + bb1.z;
  o[7] = (v1.w - mean) * rstd * g1.w + bb1.w;
  if (OBF) {
    uint4 pkv;
    pkv.x = pk2(o[0], o[1]); pkv.y = pk2(o[2], o[3]);
    pkv.z = pk2(o[4], o[5]); pkv.w = pk2(o[6], o[7]);
    *(uint4*)((ushort_t*)outp + row * DMODEL + lane * 8) = pkv;
  } else {
    float4 a, c;
    a.x = o[0]; a.y = o[1]; a.z = o[2]; a.w = o[3];
    c.x = o[4]; c.y = o[5]; c.z = o[6]; c.w = o[7];
    float* q = (float*)outp + row * DMODEL + lane * 8;
    *(float4*)q = a;
    *(float4*)(q + 4) = c;
  }
}

// ---------------- fused double LayerNorm (norm3 then conv_ln), bf16 out -----
__global__ __launch_bounds__(256) void ln2_kernel(const float* __restrict__ in,
                                                  const float* __restrict__ g1,
                                                  const float* __restrict__ b1,
                                                  const float* __restrict__ g2,
                                                  const float* __restrict__ b2,
                                                  ushort_t* __restrict__ outp) {
  const int wave = threadIdx.x >> 6, lane = threadIdx.x & 63;
  const size_t row = (size_t)blockIdx.x * 4 + wave;
  const float* p = in + row * DMODEL + lane * 8;
  float v[8];
  {
    const float4 v0 = *(const float4*)p;
    const float4 v1 = *(const float4*)(p + 4);
    v[0]=v0.x; v[1]=v0.y; v[2]=v0.z; v[3]=v0.w;
    v[4]=v1.x; v[5]=v1.y; v[6]=v1.z; v[7]=v1.w;
  }
  float s = 0.f, ss = 0.f;
#pragma unroll
  for (int e = 0; e < 8; ++e) { s += v[e]; ss += v[e]*v[e]; }
#pragma unroll
  for (int m = 1; m < 64; m <<= 1) { s += __shfl_xor(s, m); ss += __shfl_xor(ss, m); }
  float mean = s * (1.0f / DMODEL);
  float rstd = rsqrtf(ss * (1.0f / DMODEL) - mean * mean + LN_EPS);
  const float4 ga = *(const float4*)(g1 + lane * 8);
  const float4 gb = *(const float4*)(g1 + lane * 8 + 4);
  const float4 ba = *(const float4*)(b1 + lane * 8);
  const float4 bb = *(const float4*)(b1 + lane * 8 + 4);
  const float gg1[8] = {ga.x,ga.y,ga.z,ga.w,gb.x,gb.y,gb.z,gb.w};
  const float bb1[8] = {ba.x,ba.y,ba.z,ba.w,bb.x,bb.y,bb.z,bb.w};
#pragma unroll
  for (int e = 0; e < 8; ++e) v[e] = (v[e] - mean) * rstd * gg1[e] + bb1[e];
  s = 0.f; ss = 0.f;
#pragma unroll
  for (int e = 0; e < 8; ++e) { s += v[e]; ss += v[e]*v[e]; }
#pragma unroll
  for (int m = 1; m < 64; m <<= 1) { s += __shfl_xor(s, m); ss += __shfl_xor(ss, m); }
  mean = s * (1.0f / DMODEL);
  rstd = rsqrtf(ss * (1.0f / DMODEL) - mean * mean + LN_EPS);
  const float4 gc = *(const float4*)(g2 + lane * 8);
  const float4 gd = *(const float4*)(g2 + lane * 8 + 4);
  const float4 bc = *(const float4*)(b2 + lane * 8);
  const float4 bd = *(const float4*)(b2 + lane * 8 + 4);
  const float gg2[8] = {gc.x,gc.y,gc.z,gc.w,gd.x,gd.y,gd.z,gd.w};
  const float bb2[8] = {bc.x,bc.y,bc.z,bc.w,bd.x,bd.y,bd.z,bd.w};
  float o[8];
#pragma unroll
  for (int e = 0; e < 8; ++e) o[e] = (v[e] - mean) * rstd * gg2[e] + bb2[e];
  uint4 pkv;
  pkv.x = pk2(o[0], o[1]); pkv.y = pk2(o[2], o[3]);
  pkv.z = pk2(o[4], o[5]); pkv.w = pk2(o[6], o[7]);
  *(uint4*)(outp + row * DMODEL + lane * 8) = pkv;
}

// ================= 8-phase 256x256 GEMM (T2+T3+T4+T5), K=512 ================
// VEP: QKV mode — cols >= 1024 (V) are written transposed into Vt[bh][d][s]
// as packed 4x-bf16 stores; QKVb V-region is skipped.
template <int ACT, bool QSC, bool VEP>
__global__ __launch_bounds__(512, 2) void gemm256(const ushort_t* __restrict__ A,
                                                  const ushort_t* __restrict__ Bt,
                                                  const float* __restrict__ bias,
                                                  ushort_t* __restrict__ Cout,
                                                  int N,
                                                  ushort_t* __restrict__ Vt) {
  __shared__ ushort_t lds[65536];   // 128 KB
  const int t = threadIdx.x;
  const int l = t & 63;
  const int wid = t >> 6;
  const int wm = wid >> 2, wn = wid & 3;
  int bx = blockIdx.x, by = blockIdx.y;
  xcd_swizzle(gridDim.x, &bx, &by);
  const int m0 = by * 256, n0 = bx * 256;
  const int K = 512;

  f32x4 acc[8][4];
#pragma unroll
  for (int m = 0; m < 8; ++m)
#pragma unroll
    for (int n = 0; n < 4; ++n) acc[m][n] = (f32x4){0.f, 0.f, 0.f, 0.f};

  const int srow = t >> 3;
  const int schunk = (t & 7) ^ ((t >> 3) & 7);

#define STAGE_A(TAU, C_, I_)                                                    \
  __builtin_amdgcn_global_load_lds(                                             \
      (const AS1 unsigned*)(A + (size_t)(m0 + (I_) * 64 + srow) * K +           \
                            (TAU) * 64 + schunk * 8),                           \
      (AS3 unsigned*)(lds + (C_) * 16384 + ((I_) * 512 + t) * 8), 16, 0, 0)
#define STAGE_B(TAU, C_, I_)                                                    \
  __builtin_amdgcn_global_load_lds(                                             \
      (const AS1 unsigned*)(Bt + (size_t)(n0 + (I_) * 64 + srow) * K +          \
                            (TAU) * 64 + schunk * 8),                           \
      (AS3 unsigned*)(lds + 32768 + (C_) * 16384 + ((I_) * 512 + t) * 8), 16, 0, 0)

#pragma unroll
  for (int i = 0; i < 4; ++i) STAGE_B(0, 0, i);
#pragma unroll
  for (int i = 0; i < 4; ++i) STAGE_A(0, 0, i);
#pragma unroll
  for (int i = 0; i < 4; ++i) STAGE_B(1, 1, i);
  STAGE_A(1, 1, 0);
  STAGE_A(1, 1, 2);
  asm volatile("s_waitcnt vmcnt(6)" ::: "memory");
  __builtin_amdgcn_s_barrier();

  const int arow = (l & 15);
  const int kch0 = (l >> 4);
  bf16x8 bfr[2][4];

  for (int it = 0; it < 4; ++it) {
    const bool stg = (it < 3);
#pragma unroll
    for (int h = 0; h < 2; ++h) {
      const int c = h;
#pragma unroll
      for (int p = 0; p < 4; ++p) {
        bf16x8 afr[2][2];
#pragma unroll
        for (int m2 = 0; m2 < 2; ++m2)
#pragma unroll
          for (int ks = 0; ks < 2; ++ks) {
            const int row = wm * 128 + (2 * p + m2) * 16 + arow;
            const int ch = (ks * 4 + kch0) ^ (row & 7);
            afr[m2][ks] = *(const bf16x8*)(lds + c * 16384 + row * 64 + ch * 8);
          }
        if (p == 0) {
#pragma unroll
          for (int nr = 0; nr < 4; ++nr)
#pragma unroll
            for (int ks = 0; ks < 2; ++ks) {
              const int row = wn * 64 + nr * 16 + arow;
              const int ch = (ks * 4 + kch0) ^ (row & 7);
              bfr[ks][nr] = *(const bf16x8*)(lds + 32768 + c * 16384 + row * 64 + ch * 8);
            }
        }
        if (p == 0) {
          if (h == 0 || stg) {
            STAGE_A(2 * it + h + 1, c ^ 1, 1);
            STAGE_A(2 * it + h + 1, c ^ 1, 3);
          }
        } else if (p == 1) {
          if (stg) {
#pragma unroll
            for (int i = 0; i < 4; ++i) STAGE_B(2 * it + h + 2, c, i);
          }
        } else if (p == 2) {
          if (stg) {
            STAGE_A(2 * it + h + 2, c, 0);
            STAGE_A(2 * it + h + 2, c, 2);
          }
        }
        __builtin_amdgcn_s_barrier();
        __builtin_amdgcn_s_setprio(1);
#pragma unroll
        for (int ks = 0; ks < 2; ++ks)
#pragma unroll
          for (int m2 = 0; m2 < 2; ++m2)
#pragma unroll
            for (int nr = 0; nr < 4; ++nr)
              acc[2 * p + m2][nr] = __builtin_amdgcn_mfma_f32_16x16x32_bf16(
                  afr[m2][ks], bfr[ks][nr], acc[2 * p + m2][nr], 0, 0, 0);
        __builtin_amdgcn_s_setprio(0);
        if (p == 3) {
          if (h == 0) {
            if (stg) asm volatile("s_waitcnt vmcnt(6)" ::: "memory");
            else     asm volatile("s_waitcnt vmcnt(0)" ::: "memory");
          } else if (stg) {
            asm volatile("s_waitcnt vmcnt(6)" ::: "memory");
          }
        }
        __builtin_amdgcn_s_barrier();
      }
    }
  }
#undef STAGE_A
#undef STAGE_B

#pragma unroll
  for (int m = 0; m < 8; ++m) {
    const int row_b = m0 + wm * 128 + m * 16 + (l >> 4) * 4;
#pragma unroll
    for (int n = 0; n < 4; ++n) {
      const int col = n0 + wn * 64 + n * 16 + (l & 15);
      const float bv = bias[col];
      const float sc = QSC ? (col < DMODEL ? QSCALE : 1.0f) : 1.0f;
      if (VEP && col >= 2 * DMODEL) {
        // V column -> transposed Vt[bh][d][s], 4 consecutive s packed
        const int bb = row_b >> 10;          // batch
        const int sS = row_b & (SEQ - 1);
        const int hd = col - 2 * DMODEL;     // h*64+d
        ushort_t tmp[4];
#pragma unroll
        for (int j = 0; j < 4; ++j) tmp[j] = f2bf(acc[m][n][j] + bv);
        *(uint2*)(Vt + (((size_t)(bb * 512 + hd)) << 10) + sS) = *(uint2*)tmp;
      } else {
#pragma unroll
        for (int j = 0; j < 4; ++j) {
          float v = acc[m][n][j] + bv;
          if (ACT == 1) v = fmaxf(v, 0.f);
          v *= sc;
          Cout[(size_t)(row_b + j) * N + col] = f2bf(v);
        }
      }
    }
  }
}

// ---------------- bf16 MFMA GEMM (m97 structure), TN = 128 or 64 ------------
template <int TN, int ACT, bool RES, bool OBF, bool QSC>
__global__ __launch_bounds__(256) void gemm_bf16(const ushort_t* __restrict__ A,
                                                 const ushort_t* __restrict__ Bt,
                                                 const float* __restrict__ bias,
                                                 const float* __restrict__ Rp,
                                                 float alpha,
                                                 void* __restrict__ Cout,
                                                 int M, int N, int K) {
  constexpr int NF = TN / 32;
  constexpr int NB = TN / 32;
  __shared__ ushort_t Al[128 * 64];
  __shared__ ushort_t Bl[TN * 64];
  const int t = threadIdx.x;
  const int lane = t & 63;
  const int wid = t >> 6;
  const int wr = wid >> 1, wc = wid & 1;
  int bx = blockIdx.x, by = blockIdx.y;
  xcd_swizzle(gridDim.x, &bx, &by);
  const int m0 = by * 128, n0 = bx * TN;

  f32x4 acc[4][NF];
#pragma unroll
  for (int m = 0; m < 4; ++m)
#pragma unroll
    for (int n = 0; n < NF; ++n) acc[m][n] = (f32x4){0.f, 0.f, 0.f, 0.f};

  const int srow = t >> 3;
  const int scol = (t & 7) * 8;
  const ushort_t* Ag = A + (size_t)(m0 + srow) * K + scol;
  const ushort_t* Bg = Bt + (size_t)(n0 + srow) * K + scol;

  for (int k0 = 0; k0 < K; k0 += 64) {
    __syncthreads();
#pragma unroll
    for (int i = 0; i < 4; ++i) {
      __builtin_amdgcn_global_load_lds(
          (const AS1 unsigned*)(Ag + (size_t)i * 32 * K + k0),
          (AS3 unsigned*)(Al + ((size_t)i * 256 + t) * 8),
          16, 0, 0);
    }
#pragma unroll
    for (int i = 0; i < NB; ++i) {
      __builtin_amdgcn_global_load_lds(
          (const AS1 unsigned*)(Bg + (size_t)i * 32 * K + k0),
          (AS3 unsigned*)(Bl + ((size_t)i * 256 + t) * 8),
          16, 0, 0);
    }
    __syncthreads();

#pragma unroll
    for (int ks = 0; ks < 2; ++ks) {
      const int kk = ks * 32 + (lane >> 4) * 8;
      bf16x8 af[4], bfv[NF];
#pragma unroll
      for (int m = 0; m < 4; ++m)
        af[m] = *(const bf16x8*)(Al + (wr * 64 + m * 16 + (lane & 15)) * 64 + kk);
#pragma unroll
      for (int n = 0; n < NF; ++n)
        bfv[n] = *(const bf16x8*)(Bl + (wc * (TN / 2) + n * 16 + (lane & 15)) * 64 + kk);
#pragma unroll
      for (int m = 0; m < 4; ++m)
#pragma unroll
        for (int n = 0; n < NF; ++n)
          acc[m][n] = __builtin_amdgcn_mfma_f32_16x16x32_bf16(af[m], bfv[n], acc[m][n], 0, 0, 0);
    }
  }

#pragma unroll
  for (int m = 0; m < 4; ++m) {
    const int row_b = m0 + wr * 64 + m * 16 + (lane >> 4) * 4;
#pragma unroll
    for (int n = 0; n < NF; ++n) {
      const int col = n0 + wc * (TN / 2) + n * 16 + (lane & 15);
      const float bv = bias[col];
#pragma unroll
      for (int j = 0; j < 4; ++j) {
        float v = acc[m][n][j] + bv;
        if (ACT == 1) v = fmaxf(v, 0.f);
        if (QSC) v *= (col < DMODEL ? QSCALE : 1.0f);
        const size_t idx = (size_t)(row_b + j) * N + col;
        if (RES) v = Rp[idx] + alpha * v;
        if (OBF) ((ushort_t*)Cout)[idx] = f2bf(v);
        else     ((float*)Cout)[idx] = v;
      }
    }
  }
}

// ---------------- fused pw1 + GLU GEMM --------------------------------------
__global__ __launch_bounds__(256) void gemm_glu(const ushort_t* __restrict__ A,
                                                const ushort_t* __restrict__ Bt,
                                                const float* __restrict__ bias,
                                                ushort_t* __restrict__ Cout) {
  __shared__ ushort_t Al[128 * 64];
  __shared__ ushort_t Bl[128 * 64];
  const int t = threadIdx.x;
  const int lane = t & 63;
  const int wid = t >> 6;
  const int wr = wid >> 1, wc = wid & 1;
  int bx = blockIdx.x, by = blockIdx.y;
  xcd_swizzle(gridDim.x, &bx, &by);
  const int m0 = by * 128, n0 = bx * 64;
  const int K = DMODEL, N = DMODEL;

  f32x4 aa[4][2], ag[4][2];
#pragma unroll
  for (int m = 0; m < 4; ++m)
#pragma unroll
    for (int n = 0; n < 2; ++n) {
      aa[m][n] = (f32x4){0.f, 0.f, 0.f, 0.f};
      ag[m][n] = (f32x4){0.f, 0.f, 0.f, 0.f};
    }

  const int srow = t >> 3;
  const int scol = (t & 7) * 8;
  const ushort_t* Ag_ = A + (size_t)(m0 + srow) * K + scol;
  const ushort_t* Ba_ = Bt + (size_t)(n0 + srow) * K + scol;
  const ushort_t* Bg_ = Bt + (size_t)(512 + n0 + srow) * K + scol;

  for (int k0 = 0; k0 < K; k0 += 64) {
    __syncthreads();
#pragma unroll
    for (int i = 0; i < 4; ++i) {
      __builtin_amdgcn_global_load_lds(
          (const AS1 unsigned*)(Ag_ + (size_t)i * 32 * K + k0),
          (AS3 unsigned*)(Al + ((size_t)i * 256 + t) * 8),
          16, 0, 0);
    }
#pragma unroll
    for (int i = 0; i < 2; ++i) {
      __builtin_amdgcn_global_load_lds(
          (const AS1 unsigned*)(Ba_ + (size_t)i * 32 * K + k0),
          (AS3 unsigned*)(Bl + ((size_t)i * 256 + t) * 8),
          16, 0, 0);
      __builtin_amdgcn_global_load_lds(
          (const AS1 unsigned*)(Bg_ + (size_t)i * 32 * K + k0),
          (AS3 unsigned*)(Bl + 64 * 64 + ((size_t)i * 256 + t) * 8),
          16, 0, 0);
    }
    __syncthreads();

#pragma unroll
    for (int ks = 0; ks < 2; ++ks) {
      const int kk = ks * 32 + (lane >> 4) * 8;
      bf16x8 af[4], bfa[2], bfg[2];
#pragma unroll
      for (int m = 0; m < 4; ++m)
        af[m] = *(const bf16x8*)(Al + (wr * 64 + m * 16 + (lane & 15)) * 64 + kk);
#pragma unroll
      for (int n = 0; n < 2; ++n) {
        bfa[n] = *(const bf16x8*)(Bl + (wc * 32 + n * 16 + (lane & 15)) * 64 + kk);
        bfg[n] = *(const bf16x8*)(Bl + (64 + wc * 32 + n * 16 + (lane & 15)) * 64 + kk);
      }
#pragma unroll
      for (int m = 0; m < 4; ++m)
#pragma unroll
        for (int n = 0; n < 2; ++n) {
          aa[m][n] = __builtin_amdgcn_mfma_f32_16x16x32_bf16(af[m], bfa[n], aa[m][n], 0, 0, 0);
          ag[m][n] = __builtin_amdgcn_mfma_f32_16x16x32_bf16(af[m], bfg[n], ag[m][n], 0, 0, 0);
        }
    }
  }

#pragma unroll
  for (int m = 0; m < 4; ++m) {
    const int row_b = m0 + wr * 64 + m * 16 + (lane >> 4) * 4;
#pragma unroll
    for (int n = 0; n < 2; ++n) {
      const int col = n0 + wc * 32 + n * 16 + (lane & 15);
      const float ba_v = bias[col];
      const float bg_v = bias[col + DMODEL];
#pragma unroll
      for (int j = 0; j < 4; ++j) {
        const float av = aa[m][n][j] + ba_v;
        const float gv = ag[m][n][j] + bg_v;
        Cout[(size_t)(row_b + j) * N + col] = f2bf(av * sigf(gv));
      }
    }
  }
}

// ---------------- MFMA flash attention, QBLK=64, KVBLK=128, 4 waves ---------
// 2-phase pipelined staging; base-2 softmax (log2e folded into Q epilogue).
__global__ __launch_bounds__(256) void attn_mfma(const ushort_t* __restrict__ QKV,
                                                 const ushort_t* __restrict__ Vt,
                                                 ushort_t* __restrict__ Om) {
  __shared__ ushort_t Ks[2][128 * 64];
  __shared__ ushort_t Vs[2][64 * 128];
  __shared__ ushort_t Ps[64 * 128];
  const int t = threadIdx.x;
  const int l = t & 63;
  const int w = t >> 6;
  const int qb = blockIdx.x, h = blockIdx.y, b = blockIdx.z;
  const size_t rowstr = 3 * DMODEL;
  const size_t baseQ = ((size_t)b * SEQ) * rowstr + (size_t)h * DKH;
  const size_t baseK = baseQ + DMODEL;
  const size_t baseV = (size_t)(b * NH + h) * DKH * SEQ;
  const size_t baseO = ((size_t)b * SEQ) * DMODEL + (size_t)h * DKH;

  bf16x8 qf[2];
  {
    const int qrow = qb * 64 + w * 16 + (l & 15);
    const ushort_t* qp = QKV + baseQ + (size_t)qrow * rowstr + ((l >> 4) * 8);
    qf[0] = *(const bf16x8*)(qp);
    qf[1] = *(const bf16x8*)(qp + 32);
  }

  const int krr = t >> 3, kch = t & 7;
  const int vrr = t >> 4, vch = t & 15;

#define STAGE_KV(KT, BUF)                                                       \
  {                                                                             \
    _Pragma("unroll")                                                           \
    for (int i = 0; i < 4; ++i) {                                               \
      const int r = i * 32 + krr;                                               \
      __builtin_amdgcn_global_load_lds(                                         \
          (const AS1 unsigned*)(QKV + baseK +                                   \
              (size_t)((KT) * 128 + r) * rowstr + ((kch ^ (r & 7)) * 8)),       \
          (AS3 unsigned*)(Ks[BUF] + ((size_t)i * 256 + t) * 8), 16, 0, 0);      \
    }                                                                           \
    _Pragma("unroll")                                                           \
    for (int i = 0; i < 4; ++i) {                                               \
      const int r = i * 16 + vrr;                                               \
      __builtin_amdgcn_global_load_lds(                                         \
          (const AS1 unsigned*)(Vt + baseV +                                    \
              (size_t)r * SEQ + (KT) * 128 + ((vch ^ (r & 15)) * 8)),           \
          (AS3 unsigned*)(Vs[BUF] + ((size_t)i * 256 + t) * 8), 16, 0, 0);      \
    }                                                                           \
  }

  float mrun[4], lrun[4];
  f32x4 o[4];
#pragma unroll
  for (int j = 0; j < 4; ++j) { mrun[j] = -1e30f; lrun[j] = 0.f; }
#pragma unroll
  for (int n = 0; n < 4; ++n) o[n] = (f32x4){0.f, 0.f, 0.f, 0.f};

  STAGE_KV(0, 0);
  __syncthreads();

  int cur = 0;
  for (int kt = 0; kt < SEQ / 128; ++kt) {
    if (kt + 1 < SEQ / 128) STAGE_KV(kt + 1, cur ^ 1);

    const ushort_t* Kc = Ks[cur];
    const ushort_t* Vc = Vs[cur];

    f32x4 s[8];
#pragma unroll
    for (int n = 0; n < 8; ++n) s[n] = (f32x4){0.f, 0.f, 0.f, 0.f};
    __builtin_amdgcn_s_setprio(1);
#pragma unroll
    for (int ks = 0; ks < 2; ++ks) {
      const int kk = ks * 64 + (l >> 4) * 16;
#pragma unroll
      for (int n = 0; n < 8; ++n) {
        const int krow = n * 16 + (l & 15);
        const bf16x8 kf = *(const bf16x8*)((const char*)Kc + krow * 128 + (kk ^ ((krow & 7) << 4)));
        s[n] = __builtin_amdgcn_mfma_f32_16x16x32_bf16(qf[ks], kf, s[n], 0, 0, 0);
      }
    }
    __builtin_amdgcn_s_setprio(0);

#pragma unroll
    for (int j = 0; j < 4; ++j) {
      float r0 = fmaxf(fmaxf(fmaxf(s[0][j], s[1][j]), fmaxf(s[2][j], s[3][j])),
                       fmaxf(fmaxf(s[4][j], s[5][j]), fmaxf(s[6][j], s[7][j])));
      r0 = fmaxf(r0, __shfl_xor(r0, 1));
      r0 = fmaxf(r0, __shfl_xor(r0, 2));
      r0 = fmaxf(r0, __shfl_xor(r0, 4));
      r0 = fmaxf(r0, __shfl_xor(r0, 8));
      const float mn = fmaxf(mrun[j], r0);
      const float cs = exp2n(mrun[j] - mn);
      const int prow = w * 16 + (l >> 4) * 4 + j;
      const int pswz = (prow & 15) << 4;
      float psum = 0.f;
#pragma unroll
      for (int n = 0; n < 8; ++n) {
        const float p = exp2n(s[n][j] - mn);
        psum += p;
        const int col2 = (n * 16 + (l & 15)) * 2;
        *(ushort_t*)((char*)Ps + prow * 256 + (col2 ^ pswz)) = f2bf(p);
      }
      psum += __shfl_xor(psum, 1);
      psum += __shfl_xor(psum, 2);
      psum += __shfl_xor(psum, 4);
      psum += __shfl_xor(psum, 8);
      lrun[j] = lrun[j] * cs + psum;
      mrun[j] = mn;
      o[0][j] *= cs; o[1][j] *= cs; o[2][j] *= cs; o[3][j] *= cs;
    }

    __builtin_amdgcn_s_setprio(1);
#pragma unroll
    for (int ks = 0; ks < 4; ++ks) {
      const int kk = ks * 64 + (l >> 4) * 16;
      const int arow = w * 16 + (l & 15);
      const bf16x8 pf = *(const bf16x8*)((char*)Ps + arow * 256 + (kk ^ ((arow & 15) << 4)));
#pragma unroll
      for (int n = 0; n < 4; ++n) {
        const int vrow = n * 16 + (l & 15);
        const bf16x8 vf = *(const bf16x8*)((const char*)Vc + vrow * 256 + (kk ^ ((vrow & 15) << 4)));
        o[n] = __builtin_amdgcn_mfma_f32_16x16x32_bf16(pf, vf, o[n], 0, 0, 0);
      }
    }
    __builtin_amdgcn_s_setprio(0);

    __syncthreads();
    cur ^= 1;
  }
#undef STAGE_KV

  float inv[4];
#pragma unroll
  for (int j = 0; j < 4; ++j) inv[j] = 1.0f / lrun[j];
#pragma unroll
  for (int j = 0; j < 4; ++j) {
    const int prow = w * 16 + (l >> 4) * 4 + j;
    const int pswz = (prow & 15) << 4;
#pragma unroll
    for (int n = 0; n < 4; ++n) {
      const int col2 = (n * 16 + (l & 15)) * 2;
      *(ushort_t*)((char*)Ps + prow * 256 + (col2 ^ pswz)) = f2bf(o[n][j] * inv[j]);
    }
  }
  __syncthreads();
#pragma unroll
  for (int i = 0; i < 2; ++i) {
    const int chunk = i * 256 + t;
    const int qr = chunk >> 3, c8 = (chunk & 7) * 8;
    const uint4 ov = *(const uint4*)((char*)Ps + qr * 256 + ((c8 * 2) ^ ((qr & 15) << 4)));
    *(uint4*)(Om + baseO + (size_t)(qb * 64 + qr) * DMODEL + c8) = ov;
  }
}

// -------- depthwise conv + bias + BN + SiLU, LDS-tiled (31x reuse) ----------
__global__ __launch_bounds__(256) void dwconv_bn_silu(const ushort_t* __restrict__ in,
                                                      const float* __restrict__ wT,
                                                      const float* __restrict__ dwb,
                                                      const float* __restrict__ bng,
                                                      const float* __restrict__ bnb,
                                                      const float* __restrict__ bnm,
                                                      const float* __restrict__ bnv,
                                                      ushort_t* __restrict__ out) {
  __shared__ ushort_t xs[94 * 128];   // 23.5 KB
  const int t = threadIdx.x;
  const int s0 = blockIdx.x * 64;
  const int c0 = blockIdx.y * 128;
  const int b  = blockIdx.z;
  const ushort_t* bp = in + (size_t)b * SEQ * DMODEL;

#pragma unroll
  for (int i = 0; i < 6; ++i) {
    const int cid = i * 256 + t;
    if (cid < 94 * 16) {
      const int r = cid >> 4, ch = cid & 15;
      const int gs = s0 + r - 15;
      uint4 v = make_uint4(0, 0, 0, 0);
      if (gs >= 0 && gs < SEQ)
        v = *(const uint4*)(bp + (size_t)gs * DMODEL + c0 + ch * 8);
      *(uint4*)(xs + r * 128 + ch * 8) = v;
    }
  }
  __syncthreads();

  const int g = t >> 4;
  const int ch8 = t & 15;
  const int dc = c0 + ch8 * 8;

  float a[4][8];
#pragma unroll
  for (int j = 0; j < 4; ++j)
#pragma unroll
    for (int e = 0; e < 8; ++e) a[j][e] = 0.f;

  for (int k = 0; k < KCONV; ++k) {
    const float4 w0 = *(const float4*)(wT + k * DMODEL + dc);
    const float4 w1 = *(const float4*)(wT + k * DMODEL + dc + 4);
    const float wv[8] = {w0.x, w0.y, w0.z, w0.w, w1.x, w1.y, w1.z, w1.w};
#pragma unroll
    for (int j = 0; j < 4; ++j) {
      ushort_t xv[8];
      *(uint4*)xv = *(const uint4*)(xs + (g * 4 + j + k) * 128 + ch8 * 8);
#pragma unroll
      for (int e = 0; e < 8; ++e) a[j][e] = fmaf(bf2f(xv[e]), wv[e], a[j][e]);
    }
  }

  const float4 bi0 = *(const float4*)(dwb + dc);
  const float4 bi1 = *(const float4*)(dwb + dc + 4);
  const float4 mm0 = *(const float4*)(bnm + dc);
  const float4 mm1 = *(const float4*)(bnm + dc + 4);
  const float4 vv0 = *(const float4*)(bnv + dc);
  const float4 vv1 = *(const float4*)(bnv + dc + 4);
  const float4 gg0 = *(const float4*)(bng + dc);
  const float4 gg1 = *(const float4*)(bng + dc + 4);
  const float4 b20 = *(const float4*)(bnb + dc);
  const float4 b21 = *(const float4*)(bnb + dc + 4);
  const float bia[8] = {bi0.x,bi0.y,bi0.z,bi0.w,bi1.x,bi1.y,bi1.z,bi1.w};
  const float mma[8] = {mm0.x,mm0.y,mm0.z,mm0.w,mm1.x,mm1.y,mm1.z,mm1.w};
  const float vva[8] = {vv0.x,vv0.y,vv0.z,vv0.w,vv1.x,vv1.y,vv1.z,vv1.w};
  const float gga[8] = {gg0.x,gg0.y,gg0.z,gg0.w,gg1.x,gg1.y,gg1.z,gg1.w};
  const float b2a[8] = {b20.x,b20.y,b20.z,b20.w,b21.x,b21.y,b21.z,b21.w};
  float rsd[8];
#pragma unroll
  for (int e = 0; e < 8; ++e) rsd[e] = rsqrtf(vva[e] + LN_EPS) * gga[e];

#pragma unroll
  for (int j = 0; j < 4; ++j) {
    float v[8];
#pragma unroll
    for (int e = 0; e < 8; ++e) {
      float t0 = a[j][e] + bia[e];
      t0 = (t0 - mma[e]) * rsd[e] + b2a[e];
      v[e] = t0 * sigf(t0);
    }
    uint4 ov;
    ov.x = pk2(v[0], v[1]); ov.y = pk2(v[2], v[3]);
    ov.z = pk2(v[4], v[5]); ov.w = pk2(v[6], v[7]);
    *(uint4*)&out[(((size_t)b * SEQ + s0 + g * 4 + j) * DMODEL) + dc] = ov;
  }
}

extern "C" void kernel_launch(void* const* d_in, const int* in_sizes, int n_in,
                              void* d_out, int out_size, void* d_ws, size_t ws_size,
                              hipStream_t stream) {
  const float* x    = (const float*)d_in[0];
  const float* n1g  = (const float*)d_in[1];
  const float* n1b  = (const float*)d_in[2];
  const float* n2g  = (const float*)d_in[3];
  const float* n2b  = (const float*)d_in[4];
  const float* n3g  = (const float*)d_in[5];
  const float* n3b  = (const float*)d_in[6];
  const float* n4g  = (const float*)d_in[7];
  const float* n4b  = (const float*)d_in[8];
  const float* clg  = (const float*)d_in[9];
  const float* clb  = (const float*)d_in[10];
  const float* f1w1 = (const float*)d_in[11];
  const float* f1b1 = (const float*)d_in[12];
  const float* f1w2 = (const float*)d_in[13];
  const float* f1b2 = (const float*)d_in[14];
  const float* f2w1 = (const float*)d_in[15];
  const float* f2b1 = (const float*)d_in[16];
  const float* f2w2 = (const float*)d_in[17];
  const float* f2b2 = (const float*)d_in[18];
  const float* wq   = (const float*)d_in[19];
  const float* bq   = (const float*)d_in[20];
  const float* wk   = (const float*)d_in[21];
  const float* bk   = (const float*)d_in[22];
  const float* wv   = (const float*)d_in[23];
  const float* bv   = (const float*)d_in[24];
  const float* wo   = (const float*)d_in[25];
  const float* bo   = (const float*)d_in[26];
  const float* pw1w = (const float*)d_in[27];
  const float* pw1b = (const float*)d_in[28];
  const float* dww  = (const float*)d_in[29];
  const float* dwb  = (const float*)d_in[30];
  const float* bng  = (const float*)d_in[31];
  const float* bnb  = (const float*)d_in[32];
  const float* bnm  = (const float*)d_in[33];
  const float* bnv  = (const float*)d_in[34];
  const float* pw2w = (const float*)d_in[35];
  const float* pw2b = (const float*)d_in[36];

  char* wsb = (char*)d_ws;
  const size_t MB = 1ull << 20;
  ushort_t* Wbf    = (ushort_t*)(wsb + 0);
  ushort_t* f1w1T  = Wbf + 0;
  ushort_t* f1w2T  = Wbf + (1ull << 20);
  ushort_t* f2w1T  = Wbf + (2ull << 20);
  ushort_t* f2w2T  = Wbf + (3ull << 20);
  ushort_t* wqkvT  = Wbf + (4ull << 20);
  ushort_t* wkT    = wqkvT + (256ull << 10);
  ushort_t* wvT    = wqkvT + (512ull << 10);
  ushort_t* woT    = wqkvT + (768ull << 10);
  ushort_t* pw1T   = Wbf + (5ull << 20);
  ushort_t* pw2T   = Wbf + (5ull << 20) + (512ull << 10);
  float*    WTc    = (float*)(wsb + 12 * MB);
  float*    bcat   = (float*)(wsb + 12 * MB + 128 * 1024);
  ushort_t* Lbf    = (ushort_t*)(wsb + 13 * MB);
  ushort_t* Hbf    = (ushort_t*)(wsb + 21 * MB);
  ushort_t* QKVb   = (ushort_t*)(wsb + 53 * MB);
  ushort_t* Vtb    = (ushort_t*)(wsb + 77 * MB);
  ushort_t* Gbf    = (ushort_t*)(wsb + 53 * MB);
  ushort_t* Obf    = (ushort_t*)(wsb + 85 * MB);
  ushort_t* Cbf    = Obf;
  float* out = (float*)d_out;

  const dim3 blk(256);
  const dim3 blk512(512);
  const dim3 blkT(32, 8);
  const dim3 gLN(TOK / 4);
  const dim3 gFFa256(FDIM / 256, TOK / 256);       // 256 blocks
  const dim3 gQKV256(3 * DMODEL / 256, TOK / 256); // 192 blocks
  const dim3 gFFb(DMODEL / 64, TOK / 128);         // 512 blocks
  const dim3 gGLU(DMODEL / 64, TOK / 128);         // 512 blocks
  const dim3 gAttn(SEQ / 64, NH, BATCH);           // 1024 blocks
  const dim3 gConv(SEQ / 64, DMODEL / 128, BATCH); // 512 blocks

  // ---- weight preprocessing (single dispatch) ----
  {
    WJobs jobs;
    const float* srcs[10] = {f1w1, f1w2, f2w1, f2w2, wq, wk, wv, wo, pw1w, pw2w};
    ushort_t* dsts[10] = {f1w1T, f1w2T, f2w1T, f2w2T, wqkvT, wkT, wvT, woT, pw1T, pw2T};
    const int Ks[10] = {512, 2048, 512, 2048, 512, 512, 512, 512, 512, 512};
    const int Ns[10] = {2048, 512, 2048, 512, 512, 512, 512, 512, 1024, 512};
    int t0 = 0;
    for (int i = 0; i < 10; ++i) {
      jobs.j[i].src = srcs[i]; jobs.j[i].dst = dsts[i];
      jobs.j[i].K = Ks[i]; jobs.j[i].N = Ns[i]; jobs.j[i].t0 = t0;
      t0 += (Ks[i] / 32) * (Ns[i] / 32);
    }
    jobs.misc_t0 = t0;
    jobs.dww = dww; jobs.bq = bq; jobs.bk = bk; jobs.bv = bv;
    jobs.wTc = WTc; jobs.bcat = bcat;
    const int nmisc = (DMODEL * KCONV + 3 * DMODEL + 255) / 256;
    wcast_all<<<t0 + nmisc, blkT, 0, stream>>>(jobs);
  }

  // ---- FF1 half-step ----
  ln_kernel<true><<<gLN, blk, 0, stream>>>(x, n1g, n1b, Lbf);
  gemm256<1, false, false><<<gFFa256, blk512, 0, stream>>>(Lbf, f1w1T, f1b1, Hbf, FDIM, nullptr);
  gemm_bf16<64,  0, true,  false, false><<<gFFb, blk, 0, stream>>>(Hbf, f1w2T, f1b2, x, 0.5f, out, TOK, DMODEL, FDIM);

  // ---- MHSA ----
  ln_kernel<true><<<gLN, blk, 0, stream>>>(out, n2g, n2b, Lbf);
  gemm256<0, true, true><<<gQKV256, blk512, 0, stream>>>(Lbf, wqkvT, bcat, QKVb, 3 * DMODEL, Vtb);
  attn_mfma<<<gAttn, blk, 0, stream>>>(QKVb, Vtb, Obf);
  gemm_bf16<64,  0, true,  false, false><<<gFFb, blk, 0, stream>>>(Obf, woT, bo, out, 1.0f, out, TOK, DMODEL, DMODEL);

  // ---- conv module ----
  ln2_kernel<<<gLN, blk, 0, stream>>>(out, n3g, n3b, clg, clb, Lbf);
  gemm_glu<<<gGLU, blk, 0, stream>>>(Lbf, pw1T, pw1b, Gbf);
  dwconv_bn_silu<<<gConv, blk, 0, stream>>>(Gbf, WTc, dwb, bng, bnb, bnm, bnv, Cbf);
  gemm_bf16<64,  0, true,  false, false><<<gFFb, blk, 0, stream>>>(Cbf, pw2T, pw2b, out, 1.0f, out, TOK, DMODEL, DMODEL);

  // ---- FF2 half-step ----
  ln_kernel<true><<<gLN, blk, 0, stream>>>(out, n4g, n4b, Lbf);
  gemm256<1, false, false><<<gFFa256, blk512, 0, stream>>>(Lbf, f2w1T, f2b1, Hbf, FDIM, nullptr);
  gemm_bf16<64,  0, true,  false, false><<<gFFb, blk, 0, stream>>>(Hbf, f2w2T, f2b2, out, 0.5f, out, TOK, DMODEL, FDIM);
}